// Round 11
// baseline (222.609 us; speedup 1.0000x reference)
//
#include <hip/hip_runtime.h>
#include <math.h>

#define BB 4
#define CC 128
#define NN 4096
#define HH 64
#define WW 64
#define YTP 4356   // 66*66 padded pixel count

typedef __attribute__((ext_vector_type(8))) short bf16x8;
typedef __attribute__((ext_vector_type(4))) float f32x4;

__device__ inline unsigned short f2bf(float f) {
  unsigned int u = __float_as_uint(f);
  unsigned int r = (u + 0x7FFFu + ((u >> 16) & 1u)) >> 16;
  return (unsigned short)r;
}
__device__ inline float bf2f(short s) {
  union { unsigned u; float f; } x;
  x.u = ((unsigned)(unsigned short)s) << 16;
  return x.f;
}

// ---------------- xt: transpose x -> xtb bf16 [b][n][c] ----------------
__global__ __launch_bounds__(256) void xt_kernel(
    const float* __restrict__ x, unsigned short* __restrict__ xtb) {
  int b = blockIdx.y;
  int n0 = blockIdx.x * 64;
  int t = threadIdx.x;
  __shared__ float xs[CC][65];
  for (int l = 0; l < 32; l++) {
    int idx = t + 256 * l;
    int px = idx & 63, c = idx >> 6;
    xs[c][px] = x[((size_t)b * CC + c) * NN + n0 + px];
  }
  __syncthreads();
  int n = t & 63, ch = t >> 6;
  unsigned o[16];
#pragma unroll
  for (int i = 0; i < 32; i += 2) {
    o[i >> 1] = (unsigned)f2bf(xs[32 * ch + i][n]) |
                ((unsigned)f2bf(xs[32 * ch + i + 1][n]) << 16);
  }
  unsigned short* dst = xtb + ((size_t)b * NN + n0 + n) * CC + 32 * ch;
#pragma unroll
  for (int k = 0; k < 4; k++) {
    uint4 v; v.x = o[4 * k]; v.y = o[4 * k + 1]; v.z = o[4 * k + 2]; v.w = o[4 * k + 3];
    *(uint4*)(dst + 8 * k) = v;
  }
}

// ---------------- wrepack: all weights -> bf16 packed ----------------
__global__ __launch_bounds__(256) void wrepack_kernel(
    const float* __restrict__ qw, const float* __restrict__ vw,
    const float* __restrict__ lw1w, const float* __restrict__ bw1w,
    const float* __restrict__ lw, unsigned short* __restrict__ qwb,
    unsigned short* __restrict__ vwb, unsigned short* __restrict__ hwb,
    unsigned short* __restrict__ Wt) {
  int idx = blockIdx.x * 256 + threadIdx.x;
  if (idx < 16384) { qwb[idx] = f2bf(qw[idx]); return; }
  idx -= 16384;
  if (idx < 16384) { vwb[idx] = f2bf(vw[idx]); return; }
  idx -= 16384;
  if (idx < 4096) { hwb[idx] = f2bf(lw1w[idx]); return; }
  idx -= 4096;
  if (idx < 4096) { hwb[4096 + idx] = f2bf(bw1w[idx]); return; }
  idx -= 4096;
  if (idx < CC * 1152) {
    int co = idx / 1152, rem = idx % 1152;
    int tap = rem >> 7, ci = rem & 127;
    Wt[idx] = f2bf(lw[(size_t)(co * CC + ci) * 9 + tap]);
  }
}

// ------- qv_mfma: q[n][c] + v[c][n] + nrm + qt/qtn + partial Skey/SumV + heads
__global__ __launch_bounds__(256) void qv_mfma(
    const unsigned short* __restrict__ xtb, const unsigned short* __restrict__ qwb,
    const unsigned short* __restrict__ vwb, const unsigned short* __restrict__ hwb,
    const float* __restrict__ qb, const float* __restrict__ vb,
    const float* __restrict__ lw1b, const float* __restrict__ lw2w,
    const float* __restrict__ lw2b, const float* __restrict__ bw1b,
    const float* __restrict__ bw2w, const float* __restrict__ bw2b,
    unsigned short* __restrict__ qt, unsigned short* __restrict__ qtn,
    float* __restrict__ nrm, float* __restrict__ pSkey,
    unsigned short* __restrict__ vbuf, float* __restrict__ pSumV,
    float* __restrict__ wmap, float* __restrict__ bmap) {
  int b = blockIdx.y;
  int nb = blockIdx.x;
  int n0 = nb * 64;
  int t = threadIdx.x, w = t >> 6, lane = t & 63;
  int col = lane & 15, oct = lane >> 4;
  __shared__ float qs[4][16][132];
  __shared__ float partK[4][128];
  __shared__ float partV[4][128];
  const unsigned short* xb = xtb + (size_t)b * NN * CC;

  f32x4 aq[8], av[8];
#pragma unroll
  for (int i = 0; i < 8; i++) { aq[i] = (f32x4)0.f; av[i] = (f32x4)0.f; }
#pragma unroll
  for (int kc = 0; kc < 4; kc++) {
    bf16x8 Xf = *(const bf16x8*)(xb + (size_t)(n0 + 16 * w + col) * CC + kc * 32 + oct * 8);
#pragma unroll
    for (int ct = 0; ct < 8; ct++) {
      bf16x8 Qf = *(const bf16x8*)(qwb + (16 * ct + col) * CC + kc * 32 + oct * 8);
      aq[ct] = __builtin_amdgcn_mfma_f32_16x16x32_bf16(Xf, Qf, aq[ct], 0, 0, 0);
      bf16x8 Vf = *(const bf16x8*)(vwb + (16 * ct + col) * CC + kc * 32 + oct * 8);
      av[ct] = __builtin_amdgcn_mfma_f32_16x16x32_bf16(Vf, Xf, av[ct], 0, 0, 0);
    }
  }

  // ---- v epilogue: v[c][n] bf16 + per-wave SumV partial into LDS ----
  unsigned short* vbb = vbuf + (size_t)b * CC * NN;
#pragma unroll
  for (int ct = 0; ct < 8; ct++) {
#pragma unroll
    for (int r = 0; r < 4; r++) {
      int c = 16 * ct + 4 * oct + r;
      float val = av[ct][r] + vb[c];
      vbb[(size_t)c * NN + n0 + 16 * w + col] = f2bf(val);
      float sv = val;
      sv += __shfl_xor(sv, 1); sv += __shfl_xor(sv, 2);
      sv += __shfl_xor(sv, 4); sv += __shfl_xor(sv, 8);
      if (col == 0) partV[w][c] = sv;
    }
  }

  // ---- q -> LDS (fp32, biased) ----
#pragma unroll
  for (int ct = 0; ct < 8; ct++) {
#pragma unroll
    for (int r = 0; r < 4; r++) {
      int c = 16 * ct + col;
      qs[w][4 * oct + r][c] = aq[ct][r] + qb[c];
    }
  }
  int row = lane >> 2, cq = (lane & 3) * 32;
  float vals[32];
  float ssq = 0.f;
#pragma unroll
  for (int i = 0; i < 32; i += 4) {
    float4 v4 = *(const float4*)&qs[w][row][cq + i];
    vals[i] = v4.x; vals[i + 1] = v4.y; vals[i + 2] = v4.z; vals[i + 3] = v4.w;
    ssq += v4.x * v4.x + v4.y * v4.y + v4.z * v4.z + v4.w * v4.w;
  }
  ssq += __shfl_xor(ssq, 1); ssq += __shfl_xor(ssq, 2);
  float nm = fmaxf(sqrtf(ssq), 1e-4f), sc = 1.0f / nm;
  int gp = b * NN + n0 + 16 * w + row;
  if ((lane & 3) == 0) nrm[gp] = nm;
  unsigned outq[16], outn[16];
  float sk[32];
#pragma unroll
  for (int i = 0; i < 32; i += 2) {
    unsigned short u0 = f2bf(vals[i]), u1 = f2bf(vals[i + 1]);
    unsigned short m0 = f2bf(vals[i] * sc), m1 = f2bf(vals[i + 1] * sc);
    outq[i >> 1] = (unsigned)u0 | ((unsigned)u1 << 16);
    outn[i >> 1] = (unsigned)m0 | ((unsigned)m1 << 16);
    sk[i] = bf2f((short)m0); sk[i + 1] = bf2f((short)m1);
  }
  unsigned short* qtp = qt + (size_t)gp * CC + cq;
  unsigned short* qnp = qtn + (size_t)gp * CC + cq;
#pragma unroll
  for (int k = 0; k < 4; k++) {
    uint4 v; v.x = outq[4 * k]; v.y = outq[4 * k + 1]; v.z = outq[4 * k + 2]; v.w = outq[4 * k + 3];
    *(uint4*)(qtp + 8 * k) = v;
    uint4 u; u.x = outn[4 * k]; u.y = outn[4 * k + 1]; u.z = outn[4 * k + 2]; u.w = outn[4 * k + 3];
    *(uint4*)(qnp + 8 * k) = u;
  }
#pragma unroll
  for (int i = 0; i < 32; i++) {
    float v = sk[i];
    v += __shfl_xor(v, 4); v += __shfl_xor(v, 8);
    v += __shfl_xor(v, 16); v += __shfl_xor(v, 32);
    if ((lane >> 2) == 0) partK[w][cq + i] = v;
  }

  // ---- heads ----
  f32x4 ah[4];
#pragma unroll
  for (int i = 0; i < 4; i++) ah[i] = (f32x4)0.f;
#pragma unroll
  for (int kc = 0; kc < 4; kc++) {
    float4 a0 = *(const float4*)&qs[w][col][kc * 32 + oct * 8];
    float4 a1 = *(const float4*)&qs[w][col][kc * 32 + oct * 8 + 4];
    union { unsigned short s[8]; bf16x8 v; } af;
    af.s[0] = f2bf(a0.x); af.s[1] = f2bf(a0.y); af.s[2] = f2bf(a0.z); af.s[3] = f2bf(a0.w);
    af.s[4] = f2bf(a1.x); af.s[5] = f2bf(a1.y); af.s[6] = f2bf(a1.z); af.s[7] = f2bf(a1.w);
#pragma unroll
    for (int ct = 0; ct < 4; ct++) {
      bf16x8 Bf = *(const bf16x8*)(hwb + (16 * ct + col) * CC + kc * 32 + oct * 8);
      ah[ct] = __builtin_amdgcn_mfma_f32_16x16x32_bf16(af.v, Bf, ah[ct], 0, 0, 0);
    }
  }
  float b1l[2], b1b[2], w2l[2], w2b[2];
#pragma unroll
  for (int ct = 0; ct < 2; ct++) {
    int mid = 16 * ct + col;
    b1l[ct] = lw1b[mid]; w2l[ct] = lw2w[mid];
    b1b[ct] = bw1b[mid]; w2b[ct] = bw2w[mid];
  }
#pragma unroll
  for (int r = 0; r < 4; r++) {
    float wp = 0.f, bp = 0.f;
#pragma unroll
    for (int ct = 0; ct < 2; ct++) {
      float zl = ah[ct][r] + b1l[ct];
      zl = (zl >= 0.f) ? zl : 0.2f * zl;
      wp += w2l[ct] * zl;
      float zb = ah[ct + 2][r] + b1b[ct];
      zb = (zb >= 0.f) ? zb : 0.2f * zb;
      bp += w2b[ct] * zb;
    }
    wp += __shfl_xor(wp, 1); wp += __shfl_xor(wp, 2);
    wp += __shfl_xor(wp, 4); wp += __shfl_xor(wp, 8);
    bp += __shfl_xor(bp, 1); bp += __shfl_xor(bp, 2);
    bp += __shfl_xor(bp, 4); bp += __shfl_xor(bp, 8);
    if (col == 0) {
      int g = b * NN + n0 + 16 * w + 4 * oct + r;
      wmap[g] = wp + lw2b[0];
      bmap[g] = bp + bw2b[0];
    }
  }

  // ---- block reduction of partials -> coalesced global partial vectors ----
  __syncthreads();
  int blk = b * 64 + nb;
  if (t < 128) {
    float s = (partK[0][t] + partK[1][t]) + (partK[2][t] + partK[3][t]);
    pSkey[(size_t)blk * 128 + t] = s;
  } else {
    int c = t - 128;
    float s = (partV[0][c] + partV[1][c]) + (partV[2][c] + partV[3][c]);
    pSumV[(size_t)blk * 128 + c] = s;
  }
}

// ---------------- reduce: partials -> Skey / SumV ----------------
__global__ __launch_bounds__(256) void reduce_kernel(
    const float* __restrict__ pSkey, const float* __restrict__ pSumV,
    float* __restrict__ Skey, float* __restrict__ SumV) {
  int b = blockIdx.x;
  int t = threadIdx.x;
  const float* src = (t < 128) ? pSkey : pSumV;
  int c = t & 127;
  float s = 0.f;
#pragma unroll 8
  for (int nb = 0; nb < 64; nb++)
    s += src[((size_t)b * 64 + nb) * 128 + c];
  if (t < 128) Skey[b * CC + c] = s;
  else SumV[b * CC + c] = s;
}

// -------- qk_sparse v7: fused PV, async global_load_lds staging -------------
// (Resubmission: round-10 bench was an infra failure -- "container failed
// twice", no pytest/profile output; same signature as round 5 which passed
// unchanged on resubmit.  Audit found no defect: LDS dst is wave-uniform
// base + lane*16B, global src per-lane, size literal 16, __syncthreads
// drains vmcnt before any Bt read.)
// Theory: the 16 uint4 staging copies were load->vmcnt->ds_write chains
// serialized under VGPR pressure; global_load_lds removes the VGPR
// round-trip, all 16 DMAs issue first, A/stats compute hides their latency.
// grid 2048: lin = mtile*64 + b*16 + ks; 128 m x 256 keys (8 iters).
__global__ __launch_bounds__(256, 2) void qk_sparse(
    const unsigned short* __restrict__ qt, const unsigned short* __restrict__ qtn,
    const float* __restrict__ nrm, const float* __restrict__ wmap,
    const float* __restrict__ bmap, const float* __restrict__ Skey,
    float* __restrict__ Zacc, const unsigned short* __restrict__ vb16,
    float* __restrict__ Ypart, int* __restrict__ flags) {
  int lin = blockIdx.x;
  int mtile = lin >> 6;
  int bks = lin & 63;
  int b = bks >> 4, ks = bks & 15;
  int t = threadIdx.x, wave = t >> 6, lane = t & 63;
  int col = lane & 15, oct = lane >> 4;
  int m0 = mtile * 128 + 32 * wave;
  int bucket = b * 128 + (m0 >> 5);

  __shared__ unsigned short Bt[8][4096];                 // full 256-key slab, 64 KB
  __shared__ __align__(16) unsigned short tS[4][32][40]; // per-wave P tile

  const unsigned short* qtb  = qt  + (size_t)b * NN * CC;
  const unsigned short* qtnb = qtn + (size_t)b * NN * CC;
  const unsigned short* vbb  = vb16 + (size_t)b * CC * NN;

  int n0base = ks * 256;
  // ---- issue all 16 async global->LDS DMAs first (no VGPR round-trip) ----
  {
    int f0 = wave, f1 = wave + 4;
    size_t off0 = (size_t)(16 * (f0 >> 2) + col) * CC + (4 * (f0 & 3) + oct) * 8;
    size_t off1 = (size_t)(16 * (f1 >> 2) + col) * CC + (4 * (f1 & 3) + oct) * 8;
#pragma unroll
    for (int it = 0; it < 8; it++) {
      size_t nb0 = (size_t)(n0base + it * 32) * CC;
      __builtin_amdgcn_global_load_lds(
          (const __attribute__((address_space(1))) unsigned int*)(qtnb + nb0 + off0),
          (__attribute__((address_space(3))) unsigned int*)&Bt[it][f0 * 512],
          16, 0, 0);
      __builtin_amdgcn_global_load_lds(
          (const __attribute__((address_space(1))) unsigned int*)(qtnb + nb0 + off1),
          (__attribute__((address_space(3))) unsigned int*)&Bt[it][f1 * 512],
          16, 0, 0);
    }
  }

  // ---- A fragments + analytic stats compute under the DMA latency ----
  bf16x8 A[2][4];
#pragma unroll
  for (int mt = 0; mt < 2; mt++)
#pragma unroll
    for (int kc = 0; kc < 4; kc++)
      A[mt][kc] = *(const bf16x8*)(qtb + (size_t)(m0 + 16 * mt + col) * CC + 32 * kc + 8 * oct);

  float stc1[2][4], stzd[2][4];
#pragma unroll
  for (int mt = 0; mt < 2; mt++) {
    float dot = 0.f;
#pragma unroll
    for (int kc = 0; kc < 4; kc++) {
      const float* skp = Skey + b * CC + 32 * kc + 8 * oct;
      float4 s0 = *(const float4*)skp;
      float4 s1 = *(const float4*)(skp + 4);
      bf16x8 a = A[mt][kc];
      dot += bf2f(a[0]) * s0.x + bf2f(a[1]) * s0.y + bf2f(a[2]) * s0.z + bf2f(a[3]) * s0.w;
      dot += bf2f(a[4]) * s1.x + bf2f(a[5]) * s1.y + bf2f(a[6]) * s1.z + bf2f(a[7]) * s1.w;
    }
    dot += __shfl_xor(dot, 16);
    dot += __shfl_xor(dot, 32);
    int m = m0 + 16 * mt + col;
    float c1 = dot * (1.0f / NN) * wmap[(size_t)b * NN + m] - bmap[(size_t)b * NN + m];
    float nm = nrm[(size_t)b * NN + m];
    float zd = nm * fmaxf(nm - c1, 0.f);
#pragma unroll
    for (int r = 0; r < 4; r++) {
      stc1[mt][r] = __shfl(c1, 4 * oct + r);
      stzd[mt][r] = __shfl(zd, 4 * oct + r);
    }
  }

  __syncthreads();   // the ONLY block-wide barrier (drains the DMAs)

  float zp[2][4];
#pragma unroll
  for (int mt = 0; mt < 2; mt++)
#pragma unroll
    for (int r = 0; r < 4; r++) zp[mt][r] = 0.f;
  // persistent PV accumulators: pvacc[mt][ct] covers (c = 16ct+4oct+r, m = 16mt+col)
  f32x4 pvacc[2][8];
#pragma unroll
  for (int mt = 0; mt < 2; mt++)
#pragma unroll
    for (int ct = 0; ct < 8; ct++) pvacc[mt][ct] = (f32x4)0.f;
  bool didwork = false;

  for (int it = 0; it < 8; it++) {
    f32x4 acc[2][2];
    acc[0][0] = (f32x4)0.f; acc[0][1] = (f32x4)0.f;
    acc[1][0] = (f32x4)0.f; acc[1][1] = (f32x4)0.f;
#pragma unroll
    for (int nt = 0; nt < 2; nt++)
#pragma unroll
      for (int kc = 0; kc < 4; kc++) {
        bf16x8 Bf = *(const bf16x8*)&Bt[it][(nt * 4 + kc) * 512 + lane * 8];
        acc[0][nt] = __builtin_amdgcn_mfma_f32_16x16x32_bf16(A[0][kc], Bf, acc[0][nt], 0, 0, 0);
        acc[1][nt] = __builtin_amdgcn_mfma_f32_16x16x32_bf16(A[1][kc], Bf, acc[1][nt], 0, 0, 0);
      }
    // cheap row-max screen: max_z_row <= max(lmax*relu(lmax-c1), 0)
    float fm = -1e30f;
#pragma unroll
    for (int mt = 0; mt < 2; mt++)
#pragma unroll
      for (int r = 0; r < 4; r++) {
        float lm = fmaxf(acc[mt][0][r], acc[mt][1][r]);
        float ub = fmaxf(lm * fmaxf(lm - stc1[mt][r], 0.f), 0.f);
        fm = fmaxf(fm, ub - stzd[mt][r]);
      }
    if (__any(fm > -18.4207f)) {
      didwork = true;
      int n0 = n0base + it * 32;
#pragma unroll
      for (int mt = 0; mt < 2; mt++)
#pragma unroll
        for (int nt = 0; nt < 2; nt++)
#pragma unroll
          for (int r = 0; r < 4; r++) {
            float l = acc[mt][nt][r];
            float s = l - stc1[mt][r];
            float z = l * fmaxf(s, 0.f);
            float e = __expf(z - stzd[mt][r]);
            zp[mt][r] += e;
            tS[wave][16 * mt + 4 * oct + r][16 * nt + col] = f2bf((s > 0.f) ? e : 0.f);
          }
      // fused PV: P (tS) is in B-fragment layout; V fragments direct from global
      bf16x8 Pa = *(const bf16x8*)&tS[wave][col][8 * oct];
      bf16x8 Pb = *(const bf16x8*)&tS[wave][16 + col][8 * oct];
#pragma unroll
      for (int ct = 0; ct < 8; ct++) {
        bf16x8 Vf = *(const bf16x8*)(vbb + (size_t)(16 * ct + col) * NN + n0 + 8 * oct);
        pvacc[0][ct] = __builtin_amdgcn_mfma_f32_16x16x32_bf16(Vf, Pa, pvacc[0][ct], 0, 0, 0);
        pvacc[1][ct] = __builtin_amdgcn_mfma_f32_16x16x32_bf16(Vf, Pb, pvacc[1][ct], 0, 0, 0);
      }
    }
  }

  if (didwork) {
#pragma unroll
    for (int mt = 0; mt < 2; mt++)
#pragma unroll
      for (int r = 0; r < 4; r++) {
        float v = zp[mt][r];
        v += __shfl_xor(v, 1); v += __shfl_xor(v, 2);
        v += __shfl_xor(v, 4); v += __shfl_xor(v, 8);
        if (col == 0)
          atomicAdd(Zacc + (size_t)b * NN + m0 + 16 * mt + 4 * oct + r, v);
      }
    // write un-normalized PV partial: Ypart chunk [32 m][128 c], single writer
    float* yp = Ypart + ((size_t)bucket * 16 + ks) * (32 * CC);
#pragma unroll
    for (int mt = 0; mt < 2; mt++)
#pragma unroll
      for (int ct = 0; ct < 8; ct++) {
        float4 o;
        o.x = pvacc[mt][ct][0]; o.y = pvacc[mt][ct][1];
        o.z = pvacc[mt][ct][2]; o.w = pvacc[mt][ct][3];
        *(float4*)(yp + (16 * mt + col) * CC + 16 * ct + 4 * oct) = o;
      }
    if (lane == 0) flags[bucket * 16 + ks] = 1;
  }
}

// ---- yfin: sum flagged chunk partials, /Z + 1e-8*SumV -> bf16 padded Yt ----
__global__ __launch_bounds__(256) void yfin_kernel(
    const float* __restrict__ Ypart, const int* __restrict__ flags,
    const float* __restrict__ Zacc, const float* __restrict__ SumV,
    unsigned short* __restrict__ Yt) {
  int bucket = blockIdx.x;
  int b = bucket >> 7;
  int m0 = (bucket & 127) * 32;
  int t = threadIdx.x;
  int mi = t >> 3, c0 = (t & 7) * 16;
  int m = m0 + mi;
  __shared__ int fl[16];
  if (t < 16) fl[t] = flags[bucket * 16 + t];
  __syncthreads();
  float rZ = 1.0f / Zacc[(size_t)b * NN + m];
  int h = m >> 6, ww = m & 63;
  const float* yb = Ypart + (size_t)bucket * 16 * (32 * CC) + mi * CC + c0;
  const float* sv = SumV + b * CC + c0;
  unsigned short* yp = Yt + ((size_t)b * YTP + (size_t)(h + 1) * 66 + (ww + 1)) * CC + c0;
  float a[16];
#pragma unroll
  for (int j = 0; j < 16; j++) a[j] = 0.f;
  for (int ks = 0; ks < 16; ks++) {
    if (!fl[ks]) continue;
    const float* ya = yb + (size_t)ks * (32 * CC);
#pragma unroll
    for (int j = 0; j < 4; j++) {
      float4 v = *(const float4*)(ya + 4 * j);
      a[4 * j] += v.x; a[4 * j + 1] += v.y; a[4 * j + 2] += v.z; a[4 * j + 3] += v.w;
    }
  }
  unsigned ov[8];
#pragma unroll
  for (int j = 0; j < 8; j++) {
    float2 s = *(const float2*)(sv + 2 * j);
    float y0 = a[2 * j] * rZ + 1e-8f * s.x;
    float y1 = a[2 * j + 1] * rZ + 1e-8f * s.y;
    ov[j] = (unsigned)f2bf(y0) | ((unsigned)f2bf(y1) << 16);
  }
  uint4 o0; o0.x = ov[0]; o0.y = ov[1]; o0.z = ov[2]; o0.w = ov[3];
  uint4 o1; o1.x = ov[4]; o1.y = ov[5]; o1.z = ov[6]; o1.w = ov[7];
  *(uint4*)yp = o0;
  *(uint4*)(yp + 8) = o1;
}

// ---------------- MFMA 3x3 conv + bias + leaky + residual ------------------
__global__ __launch_bounds__(256, 2) void conv_mfma(
    const unsigned short* __restrict__ Yt, const unsigned short* __restrict__ Wt,
    const float* __restrict__ x, const float* __restrict__ lb,
    float* __restrict__ out) {
  int h = blockIdx.x;
  int by = blockIdx.y;
  int b = blockIdx.z;
  int t = threadIdx.x;
  int wave = t >> 6, lane = t & 63;
  int col = lane & 15, oct = lane >> 4;
  int pxt = wave & 1, cohalf = wave >> 1;
  int w0 = by * 32 + pxt * 16;
  const unsigned short* Yb = Yt + (size_t)b * YTP * CC;

  f32x4 acc[4];
#pragma unroll
  for (int ct = 0; ct < 4; ct++) acc[ct] = (f32x4)0.f;

#pragma unroll
  for (int tap = 0; tap < 9; tap++) {
    int dh = tap / 3 - 1, dw = tap % 3 - 1;
    const unsigned short* ybase =
        Yb + (size_t)((h + 1 + dh) * 66 + (w0 + 1 + dw + col)) * CC;
#pragma unroll
    for (int kc = 0; kc < 4; kc++) {
      bf16x8 Af = *(const bf16x8*)(ybase + 32 * kc + 8 * oct);
#pragma unroll
      for (int ct = 0; ct < 4; ct++) {
        bf16x8 Bf = *(const bf16x8*)(Wt +
            (size_t)(cohalf * 64 + 16 * ct + col) * 1152 + tap * 128 + 32 * kc + 8 * oct);
        acc[ct] = __builtin_amdgcn_mfma_f32_16x16x32_bf16(Af, Bf, acc[ct], 0, 0, 0);
      }
    }
  }
#pragma unroll
  for (int ct = 0; ct < 4; ct++) {
    int co = cohalf * 64 + 16 * ct + col;
    float bv = lb[co];
    int n = h * 64 + w0 + 4 * oct;
    size_t base = ((size_t)b * CC + co) * NN + n;
    float4 xi = *(const float4*)(x + base);
    float4 o;
    float z0 = acc[ct][0] + bv; o.x = ((z0 >= 0.f) ? z0 : 0.2f * z0) + xi.x;
    float z1 = acc[ct][1] + bv; o.y = ((z1 >= 0.f) ? z1 : 0.2f * z1) + xi.y;
    float z2 = acc[ct][2] + bv; o.z = ((z2 >= 0.f) ? z2 : 0.2f * z2) + xi.z;
    float z3 = acc[ct][3] + bv; o.w = ((z3 >= 0.f) ? z3 : 0.2f * z3) + xi.w;
    *(float4*)(out + base) = o;
  }
}

extern "C" void kernel_launch(void* const* d_in, const int* in_sizes, int n_in,
                              void* d_out, int out_size, void* d_ws, size_t ws_size,
                              hipStream_t stream) {
  const float* x    = (const float*)d_in[0];
  const float* q_w  = (const float*)d_in[1];
  const float* q_b  = (const float*)d_in[2];
  const float* v_w  = (const float*)d_in[3];
  const float* v_b  = (const float*)d_in[4];
  const float* lw1w = (const float*)d_in[5];
  const float* lw1b = (const float*)d_in[6];
  const float* lw2w = (const float*)d_in[7];
  const float* lw2b = (const float*)d_in[8];
  const float* bw1w = (const float*)d_in[9];
  const float* bw1b = (const float*)d_in[10];
  const float* bw2w = (const float*)d_in[11];
  const float* bw2b = (const float*)d_in[12];
  const float* linw = (const float*)d_in[13];
  const float* linb = (const float*)d_in[14];
  float* out = (float*)d_out;

  const size_t BCN = (size_t)BB * CC * NN;  // 2,097,152
  const size_t BN  = (size_t)BB * NN;       // 16,384

  unsigned short* xtb = (unsigned short*)d_ws;         // BCN bf16
  unsigned short* qt  = xtb + BCN;                     // BCN
  unsigned short* qtn = qt + BCN;                      // BCN
  unsigned short* vb16 = qtn + BCN;                    // BCN
  unsigned short* Yt  = vb16 + BCN;                    // BB*YTP*CC
  unsigned short* qwb = Yt + (size_t)BB * YTP * CC;    // CC*CC
  unsigned short* vwb = qwb + CC * CC;                 // CC*CC
  unsigned short* hwb = vwb + CC * CC;                 // 64*CC
  unsigned short* Wt  = hwb + 64 * CC;                 // CC*1152
  float* nrmb = (float*)(Wt + (size_t)CC * 1152);      // BN
  float* wmap = nrmb + BN;                             // BN
  float* bmap = wmap + BN;                             // BN
  float* SumV = bmap + BN;                             // BB*CC
  float* Skey = SumV + (size_t)BB * CC;                // BB*CC
  float* Zacc = Skey + (size_t)BB * CC;                // BN        } zero
  int*   flags = (int*)(Zacc + BN);                    // 512*16    } region
  float* pSkey = (float*)(flags + 512 * 16);           // 256*128
  float* pSumV = pSkey + 256 * 128;                    // 256*128
  float* Ypart = pSumV + 256 * 128;                    // 512*16*4096 f32 (128MB)
  // total ≈ 16 MB bf16 bufs + 4.3 Yt + ~0.6 weights + maps + 128 MB Ypart
  //       ≈ 150 MB < 256 MiB.  Ypart needs no memset (only flagged chunks read).

  size_t zbytes = BN * sizeof(float) + 512 * 16 * sizeof(int);
  hipMemsetAsync(Zacc, 0, zbytes, stream);
  hipMemsetAsync(Yt, 0, (size_t)BB * YTP * CC * sizeof(unsigned short), stream);

  hipLaunchKernelGGL(xt_kernel, dim3(NN / 64, BB), dim3(256), 0, stream, x, xtb);
  hipLaunchKernelGGL(wrepack_kernel, dim3((188416 + 255) / 256), dim3(256), 0,
                     stream, q_w, v_w, lw1w, bw1w, linw, qwb, vwb, hwb, Wt);
  hipLaunchKernelGGL(qv_mfma, dim3(NN / 64, BB), dim3(256), 0, stream,
                     xtb, qwb, vwb, hwb, q_b, v_b, lw1b, lw2w, lw2b,
                     bw1b, bw2w, bw2b, qt, qtn, nrmb, pSkey, vb16, pSumV,
                     wmap, bmap);
  hipLaunchKernelGGL(reduce_kernel, dim3(BB), dim3(256), 0, stream,
                     pSkey, pSumV, Skey, SumV);
  hipLaunchKernelGGL(qk_sparse, dim3(2048), dim3(256), 0, stream,
                     qt, qtn, nrmb, wmap, bmap, Skey, Zacc, vb16, Ypart, flags);
  hipLaunchKernelGGL(yfin_kernel, dim3(512), dim3(256), 0, stream,
                     Ypart, flags, Zacc, SumV, Yt);
  hipLaunchKernelGGL(conv_mfma, dim3(HH, 2, BB), dim3(256), 0, stream,
                     Yt, Wt, x, linb, out);
}

// Round 12
// 219.568 us; speedup vs baseline: 1.0139x; 1.0139x over previous
//
#include <hip/hip_runtime.h>
#include <math.h>

#define BB 4
#define CC 128
#define NN 4096
#define HH 64
#define WW 64
#define YTP 4356   // 66*66 padded pixel count

typedef __attribute__((ext_vector_type(8))) short bf16x8;
typedef __attribute__((ext_vector_type(4))) float f32x4;

__device__ inline unsigned short f2bf(float f) {
  unsigned int u = __float_as_uint(f);
  unsigned int r = (u + 0x7FFFu + ((u >> 16) & 1u)) >> 16;
  return (unsigned short)r;
}
__device__ inline float bf2f(short s) {
  union { unsigned u; float f; } x;
  x.u = ((unsigned)(unsigned short)s) << 16;
  return x.f;
}

// ---------------- xt: transpose x -> xtb bf16 [b][n][c] ----------------
__global__ __launch_bounds__(256) void xt_kernel(
    const float* __restrict__ x, unsigned short* __restrict__ xtb) {
  int b = blockIdx.y;
  int n0 = blockIdx.x * 64;
  int t = threadIdx.x;
  __shared__ float xs[CC][65];
  for (int l = 0; l < 32; l++) {
    int idx = t + 256 * l;
    int px = idx & 63, c = idx >> 6;
    xs[c][px] = x[((size_t)b * CC + c) * NN + n0 + px];
  }
  __syncthreads();
  int n = t & 63, ch = t >> 6;
  unsigned o[16];
#pragma unroll
  for (int i = 0; i < 32; i += 2) {
    o[i >> 1] = (unsigned)f2bf(xs[32 * ch + i][n]) |
                ((unsigned)f2bf(xs[32 * ch + i + 1][n]) << 16);
  }
  unsigned short* dst = xtb + ((size_t)b * NN + n0 + n) * CC + 32 * ch;
#pragma unroll
  for (int k = 0; k < 4; k++) {
    uint4 v; v.x = o[4 * k]; v.y = o[4 * k + 1]; v.z = o[4 * k + 2]; v.w = o[4 * k + 3];
    *(uint4*)(dst + 8 * k) = v;
  }
}

// ---------------- wrepack: all weights -> bf16 packed ----------------
__global__ __launch_bounds__(256) void wrepack_kernel(
    const float* __restrict__ qw, const float* __restrict__ vw,
    const float* __restrict__ lw1w, const float* __restrict__ bw1w,
    const float* __restrict__ lw, unsigned short* __restrict__ qwb,
    unsigned short* __restrict__ vwb, unsigned short* __restrict__ hwb,
    unsigned short* __restrict__ Wt) {
  int idx = blockIdx.x * 256 + threadIdx.x;
  if (idx < 16384) { qwb[idx] = f2bf(qw[idx]); return; }
  idx -= 16384;
  if (idx < 16384) { vwb[idx] = f2bf(vw[idx]); return; }
  idx -= 16384;
  if (idx < 4096) { hwb[idx] = f2bf(lw1w[idx]); return; }
  idx -= 4096;
  if (idx < 4096) { hwb[4096 + idx] = f2bf(bw1w[idx]); return; }
  idx -= 4096;
  if (idx < CC * 1152) {
    int co = idx / 1152, rem = idx % 1152;
    int tap = rem >> 7, ci = rem & 127;
    Wt[idx] = f2bf(lw[(size_t)(co * CC + ci) * 9 + tap]);
  }
}

// ------- qv_mfma: q[n][c] + v[c][n] + nrm + qt/qtn + partial Skey/SumV + heads
__global__ __launch_bounds__(256) void qv_mfma(
    const unsigned short* __restrict__ xtb, const unsigned short* __restrict__ qwb,
    const unsigned short* __restrict__ vwb, const unsigned short* __restrict__ hwb,
    const float* __restrict__ qb, const float* __restrict__ vb,
    const float* __restrict__ lw1b, const float* __restrict__ lw2w,
    const float* __restrict__ lw2b, const float* __restrict__ bw1b,
    const float* __restrict__ bw2w, const float* __restrict__ bw2b,
    unsigned short* __restrict__ qt, unsigned short* __restrict__ qtn,
    float* __restrict__ nrm, float* __restrict__ pSkey,
    unsigned short* __restrict__ vbuf, float* __restrict__ pSumV,
    float* __restrict__ wmap, float* __restrict__ bmap) {
  int b = blockIdx.y;
  int nb = blockIdx.x;
  int n0 = nb * 64;
  int t = threadIdx.x, w = t >> 6, lane = t & 63;
  int col = lane & 15, oct = lane >> 4;
  __shared__ float qs[4][16][132];
  __shared__ float partK[4][128];
  __shared__ float partV[4][128];
  const unsigned short* xb = xtb + (size_t)b * NN * CC;

  f32x4 aq[8], av[8];
#pragma unroll
  for (int i = 0; i < 8; i++) { aq[i] = (f32x4)0.f; av[i] = (f32x4)0.f; }
#pragma unroll
  for (int kc = 0; kc < 4; kc++) {
    bf16x8 Xf = *(const bf16x8*)(xb + (size_t)(n0 + 16 * w + col) * CC + kc * 32 + oct * 8);
#pragma unroll
    for (int ct = 0; ct < 8; ct++) {
      bf16x8 Qf = *(const bf16x8*)(qwb + (16 * ct + col) * CC + kc * 32 + oct * 8);
      aq[ct] = __builtin_amdgcn_mfma_f32_16x16x32_bf16(Xf, Qf, aq[ct], 0, 0, 0);
      bf16x8 Vf = *(const bf16x8*)(vwb + (16 * ct + col) * CC + kc * 32 + oct * 8);
      av[ct] = __builtin_amdgcn_mfma_f32_16x16x32_bf16(Vf, Xf, av[ct], 0, 0, 0);
    }
  }

  // ---- v epilogue: v[c][n] bf16 + per-wave SumV partial into LDS ----
  unsigned short* vbb = vbuf + (size_t)b * CC * NN;
#pragma unroll
  for (int ct = 0; ct < 8; ct++) {
#pragma unroll
    for (int r = 0; r < 4; r++) {
      int c = 16 * ct + 4 * oct + r;
      float val = av[ct][r] + vb[c];
      vbb[(size_t)c * NN + n0 + 16 * w + col] = f2bf(val);
      float sv = val;
      sv += __shfl_xor(sv, 1); sv += __shfl_xor(sv, 2);
      sv += __shfl_xor(sv, 4); sv += __shfl_xor(sv, 8);
      if (col == 0) partV[w][c] = sv;
    }
  }

  // ---- q -> LDS (fp32, biased) ----
#pragma unroll
  for (int ct = 0; ct < 8; ct++) {
#pragma unroll
    for (int r = 0; r < 4; r++) {
      int c = 16 * ct + col;
      qs[w][4 * oct + r][c] = aq[ct][r] + qb[c];
    }
  }
  int row = lane >> 2, cq = (lane & 3) * 32;
  float vals[32];
  float ssq = 0.f;
#pragma unroll
  for (int i = 0; i < 32; i += 4) {
    float4 v4 = *(const float4*)&qs[w][row][cq + i];
    vals[i] = v4.x; vals[i + 1] = v4.y; vals[i + 2] = v4.z; vals[i + 3] = v4.w;
    ssq += v4.x * v4.x + v4.y * v4.y + v4.z * v4.z + v4.w * v4.w;
  }
  ssq += __shfl_xor(ssq, 1); ssq += __shfl_xor(ssq, 2);
  float nm = fmaxf(sqrtf(ssq), 1e-4f), sc = 1.0f / nm;
  int gp = b * NN + n0 + 16 * w + row;
  if ((lane & 3) == 0) nrm[gp] = nm;
  unsigned outq[16], outn[16];
  float sk[32];
#pragma unroll
  for (int i = 0; i < 32; i += 2) {
    unsigned short u0 = f2bf(vals[i]), u1 = f2bf(vals[i + 1]);
    unsigned short m0 = f2bf(vals[i] * sc), m1 = f2bf(vals[i + 1] * sc);
    outq[i >> 1] = (unsigned)u0 | ((unsigned)u1 << 16);
    outn[i >> 1] = (unsigned)m0 | ((unsigned)m1 << 16);
    sk[i] = bf2f((short)m0); sk[i + 1] = bf2f((short)m1);
  }
  unsigned short* qtp = qt + (size_t)gp * CC + cq;
  unsigned short* qnp = qtn + (size_t)gp * CC + cq;
#pragma unroll
  for (int k = 0; k < 4; k++) {
    uint4 v; v.x = outq[4 * k]; v.y = outq[4 * k + 1]; v.z = outq[4 * k + 2]; v.w = outq[4 * k + 3];
    *(uint4*)(qtp + 8 * k) = v;
    uint4 u; u.x = outn[4 * k]; u.y = outn[4 * k + 1]; u.z = outn[4 * k + 2]; u.w = outn[4 * k + 3];
    *(uint4*)(qnp + 8 * k) = u;
  }
#pragma unroll
  for (int i = 0; i < 32; i++) {
    float v = sk[i];
    v += __shfl_xor(v, 4); v += __shfl_xor(v, 8);
    v += __shfl_xor(v, 16); v += __shfl_xor(v, 32);
    if ((lane >> 2) == 0) partK[w][cq + i] = v;
  }

  // ---- heads ----
  f32x4 ah[4];
#pragma unroll
  for (int i = 0; i < 4; i++) ah[i] = (f32x4)0.f;
#pragma unroll
  for (int kc = 0; kc < 4; kc++) {
    float4 a0 = *(const float4*)&qs[w][col][kc * 32 + oct * 8];
    float4 a1 = *(const float4*)&qs[w][col][kc * 32 + oct * 8 + 4];
    union { unsigned short s[8]; bf16x8 v; } af;
    af.s[0] = f2bf(a0.x); af.s[1] = f2bf(a0.y); af.s[2] = f2bf(a0.z); af.s[3] = f2bf(a0.w);
    af.s[4] = f2bf(a1.x); af.s[5] = f2bf(a1.y); af.s[6] = f2bf(a1.z); af.s[7] = f2bf(a1.w);
#pragma unroll
    for (int ct = 0; ct < 4; ct++) {
      bf16x8 Bf = *(const bf16x8*)(hwb + (16 * ct + col) * CC + kc * 32 + oct * 8);
      ah[ct] = __builtin_amdgcn_mfma_f32_16x16x32_bf16(af.v, Bf, ah[ct], 0, 0, 0);
    }
  }
  float b1l[2], b1b[2], w2l[2], w2b[2];
#pragma unroll
  for (int ct = 0; ct < 2; ct++) {
    int mid = 16 * ct + col;
    b1l[ct] = lw1b[mid]; w2l[ct] = lw2w[mid];
    b1b[ct] = bw1b[mid]; w2b[ct] = bw2w[mid];
  }
#pragma unroll
  for (int r = 0; r < 4; r++) {
    float wp = 0.f, bp = 0.f;
#pragma unroll
    for (int ct = 0; ct < 2; ct++) {
      float zl = ah[ct][r] + b1l[ct];
      zl = (zl >= 0.f) ? zl : 0.2f * zl;
      wp += w2l[ct] * zl;
      float zb = ah[ct + 2][r] + b1b[ct];
      zb = (zb >= 0.f) ? zb : 0.2f * zb;
      bp += w2b[ct] * zb;
    }
    wp += __shfl_xor(wp, 1); wp += __shfl_xor(wp, 2);
    wp += __shfl_xor(wp, 4); wp += __shfl_xor(wp, 8);
    bp += __shfl_xor(bp, 1); bp += __shfl_xor(bp, 2);
    bp += __shfl_xor(bp, 4); bp += __shfl_xor(bp, 8);
    if (col == 0) {
      int g = b * NN + n0 + 16 * w + 4 * oct + r;
      wmap[g] = wp + lw2b[0];
      bmap[g] = bp + bw2b[0];
    }
  }

  // ---- block reduction of partials -> coalesced global partial vectors ----
  __syncthreads();
  int blk = b * 64 + nb;
  if (t < 128) {
    float s = (partK[0][t] + partK[1][t]) + (partK[2][t] + partK[3][t]);
    pSkey[(size_t)blk * 128 + t] = s;
  } else {
    int c = t - 128;
    float s = (partV[0][c] + partV[1][c]) + (partV[2][c] + partV[3][c]);
    pSumV[(size_t)blk * 128 + c] = s;
  }
}

// ---------------- reduce: partials -> Skey / SumV ----------------
__global__ __launch_bounds__(256) void reduce_kernel(
    const float* __restrict__ pSkey, const float* __restrict__ pSumV,
    float* __restrict__ Skey, float* __restrict__ SumV) {
  int b = blockIdx.x;
  int t = threadIdx.x;
  const float* src = (t < 128) ? pSkey : pSumV;
  int c = t & 127;
  float s = 0.f;
#pragma unroll 8
  for (int nb = 0; nb < 64; nb++)
    s += src[((size_t)b * 64 + nb) * 128 + c];
  if (t < 128) Skey[b * CC + c] = s;
  else SumV[b * CC + c] = s;
}

// ---- stats: per-row c1/zd (dedup: was recomputed by all 16 ks-blocks) ------
// c1[m] = dot(qtn[m], Skey[b]) / NN * wmap[m] - bmap[m]
// zd[m] = nrm[m] * max(nrm[m] - c1[m], 0)
// grid 64 x 256 threads; block covers 256 consecutive m within one batch b.
__global__ __launch_bounds__(256) void stats_kernel(
    const unsigned short* __restrict__ qtn, const float* __restrict__ Skey,
    const float* __restrict__ nrm, const float* __restrict__ wmap,
    const float* __restrict__ bmap, float* __restrict__ c1a,
    float* __restrict__ zda) {
  int g = blockIdx.x * 256 + threadIdx.x;   // g in [0, BB*NN)
  int b = g >> 12;                          // NN = 4096; 16 blocks per batch
  __shared__ float sk[CC];
  if (threadIdx.x < CC) sk[threadIdx.x] = Skey[b * CC + threadIdx.x];
  __syncthreads();
  const unsigned short* qp = qtn + (size_t)g * CC;
  float dot = 0.f;
#pragma unroll
  for (int i = 0; i < CC; i += 8) {
    bf16x8 v = *(const bf16x8*)(qp + i);
    dot += bf2f(v[0]) * sk[i]     + bf2f(v[1]) * sk[i + 1]
         + bf2f(v[2]) * sk[i + 2] + bf2f(v[3]) * sk[i + 3]
         + bf2f(v[4]) * sk[i + 4] + bf2f(v[5]) * sk[i + 5]
         + bf2f(v[6]) * sk[i + 6] + bf2f(v[7]) * sk[i + 7];
  }
  float c1 = dot * (1.0f / NN) * wmap[g] - bmap[g];
  float nm = nrm[g];
  c1a[g] = c1;
  zda[g] = nm * fmaxf(nm - c1, 0.f);
}

// -------- qk_sparse v8: fused PV, sync slab staging, precomputed stats ------
// Round-11 falsified the async-DMA theory (49 vs 46.9 sync): revert to the
// round-9 staging (best measured).  qk has been invariant ~47 us across all
// scheduling variants; the one untouched redundancy is the per-row stats
// chain (64 serial FMAs + 4 load streams), recomputed by all 16 ks-blocks
// per (b,mtile).  Hoisted to stats_kernel; prologue is now 2 loads+shuffles.
// grid 2048: lin = mtile*64 + b*16 + ks; 128 m x 256 keys (8 iters).
__global__ __launch_bounds__(256, 2) void qk_sparse(
    const unsigned short* __restrict__ qt, const unsigned short* __restrict__ qtn,
    const float* __restrict__ c1a, const float* __restrict__ zda,
    float* __restrict__ Zacc, const unsigned short* __restrict__ vb16,
    float* __restrict__ Ypart, int* __restrict__ flags) {
  int lin = blockIdx.x;
  int mtile = lin >> 6;
  int bks = lin & 63;
  int b = bks >> 4, ks = bks & 15;
  int t = threadIdx.x, wave = t >> 6, lane = t & 63;
  int col = lane & 15, oct = lane >> 4;
  int m0 = mtile * 128 + 32 * wave;
  int bucket = b * 128 + (m0 >> 5);

  __shared__ unsigned short Bt[8][4096];                 // full 256-key slab, 64 KB
  __shared__ __align__(16) unsigned short tS[4][32][40]; // per-wave P tile

  const unsigned short* qtb  = qt  + (size_t)b * NN * CC;
  const unsigned short* qtnb = qtn + (size_t)b * NN * CC;
  const unsigned short* vbb  = vb16 + (size_t)b * CC * NN;

  bf16x8 A[2][4];
#pragma unroll
  for (int mt = 0; mt < 2; mt++)
#pragma unroll
    for (int kc = 0; kc < 4; kc++)
      A[mt][kc] = *(const bf16x8*)(qtb + (size_t)(m0 + 16 * mt + col) * CC + 32 * kc + 8 * oct);

  // precomputed per-row stats: 2 loads + the same broadcast shuffles
  float stc1[2][4], stzd[2][4];
#pragma unroll
  for (int mt = 0; mt < 2; mt++) {
    int m = m0 + 16 * mt + col;
    float c1 = c1a[(size_t)b * NN + m];
    float zd = zda[(size_t)b * NN + m];
#pragma unroll
    for (int r = 0; r < 4; r++) {
      stc1[mt][r] = __shfl(c1, 4 * oct + r);
      stzd[mt][r] = __shfl(zd, 4 * oct + r);
    }
  }

  int n0base = ks * 256;
  // stage the ENTIRE 256-key slab once: 16 independent uint4 loads/thread
  {
    int f0 = wave, f1 = wave + 4;
    size_t off0 = (size_t)(16 * (f0 >> 2) + col) * CC + (4 * (f0 & 3) + oct) * 8;
    size_t off1 = (size_t)(16 * (f1 >> 2) + col) * CC + (4 * (f1 & 3) + oct) * 8;
#pragma unroll
    for (int it = 0; it < 8; it++) {
      size_t nb0 = (size_t)(n0base + it * 32) * CC;
      uint4 r0 = *(const uint4*)(qtnb + nb0 + off0);
      uint4 r1 = *(const uint4*)(qtnb + nb0 + off1);
      *(uint4*)&Bt[it][f0 * 512 + lane * 8] = r0;
      *(uint4*)&Bt[it][f1 * 512 + lane * 8] = r1;
    }
  }
  __syncthreads();   // the ONLY block-wide barrier

  float zp[2][4];
#pragma unroll
  for (int mt = 0; mt < 2; mt++)
#pragma unroll
    for (int r = 0; r < 4; r++) zp[mt][r] = 0.f;
  // persistent PV accumulators: pvacc[mt][ct] covers (c = 16ct+4oct+r, m = 16mt+col)
  f32x4 pvacc[2][8];
#pragma unroll
  for (int mt = 0; mt < 2; mt++)
#pragma unroll
    for (int ct = 0; ct < 8; ct++) pvacc[mt][ct] = (f32x4)0.f;
  bool didwork = false;

  for (int it = 0; it < 8; it++) {
    f32x4 acc[2][2];
    acc[0][0] = (f32x4)0.f; acc[0][1] = (f32x4)0.f;
    acc[1][0] = (f32x4)0.f; acc[1][1] = (f32x4)0.f;
#pragma unroll
    for (int nt = 0; nt < 2; nt++)
#pragma unroll
      for (int kc = 0; kc < 4; kc++) {
        bf16x8 Bf = *(const bf16x8*)&Bt[it][(nt * 4 + kc) * 512 + lane * 8];
        acc[0][nt] = __builtin_amdgcn_mfma_f32_16x16x32_bf16(A[0][kc], Bf, acc[0][nt], 0, 0, 0);
        acc[1][nt] = __builtin_amdgcn_mfma_f32_16x16x32_bf16(A[1][kc], Bf, acc[1][nt], 0, 0, 0);
      }
    // cheap row-max screen: max_z_row <= max(lmax*relu(lmax-c1), 0)
    float fm = -1e30f;
#pragma unroll
    for (int mt = 0; mt < 2; mt++)
#pragma unroll
      for (int r = 0; r < 4; r++) {
        float lm = fmaxf(acc[mt][0][r], acc[mt][1][r]);
        float ub = fmaxf(lm * fmaxf(lm - stc1[mt][r], 0.f), 0.f);
        fm = fmaxf(fm, ub - stzd[mt][r]);
      }
    if (__any(fm > -18.4207f)) {
      didwork = true;
      int n0 = n0base + it * 32;
#pragma unroll
      for (int mt = 0; mt < 2; mt++)
#pragma unroll
        for (int nt = 0; nt < 2; nt++)
#pragma unroll
          for (int r = 0; r < 4; r++) {
            float l = acc[mt][nt][r];
            float s = l - stc1[mt][r];
            float z = l * fmaxf(s, 0.f);
            float e = __expf(z - stzd[mt][r]);
            zp[mt][r] += e;
            tS[wave][16 * mt + 4 * oct + r][16 * nt + col] = f2bf((s > 0.f) ? e : 0.f);
          }
      // fused PV: P (tS) is in B-fragment layout; V fragments direct from global
      bf16x8 Pa = *(const bf16x8*)&tS[wave][col][8 * oct];
      bf16x8 Pb = *(const bf16x8*)&tS[wave][16 + col][8 * oct];
#pragma unroll
      for (int ct = 0; ct < 8; ct++) {
        bf16x8 Vf = *(const bf16x8*)(vbb + (size_t)(16 * ct + col) * NN + n0 + 8 * oct);
        pvacc[0][ct] = __builtin_amdgcn_mfma_f32_16x16x32_bf16(Vf, Pa, pvacc[0][ct], 0, 0, 0);
        pvacc[1][ct] = __builtin_amdgcn_mfma_f32_16x16x32_bf16(Vf, Pb, pvacc[1][ct], 0, 0, 0);
      }
    }
  }

  if (didwork) {
#pragma unroll
    for (int mt = 0; mt < 2; mt++)
#pragma unroll
      for (int r = 0; r < 4; r++) {
        float v = zp[mt][r];
        v += __shfl_xor(v, 1); v += __shfl_xor(v, 2);
        v += __shfl_xor(v, 4); v += __shfl_xor(v, 8);
        if (col == 0)
          atomicAdd(Zacc + (size_t)b * NN + m0 + 16 * mt + 4 * oct + r, v);
      }
    // write un-normalized PV partial: Ypart chunk [32 m][128 c], single writer
    float* yp = Ypart + ((size_t)bucket * 16 + ks) * (32 * CC);
#pragma unroll
    for (int mt = 0; mt < 2; mt++)
#pragma unroll
      for (int ct = 0; ct < 8; ct++) {
        float4 o;
        o.x = pvacc[mt][ct][0]; o.y = pvacc[mt][ct][1];
        o.z = pvacc[mt][ct][2]; o.w = pvacc[mt][ct][3];
        *(float4*)(yp + (16 * mt + col) * CC + 16 * ct + 4 * oct) = o;
      }
    if (lane == 0) flags[bucket * 16 + ks] = 1;
  }
}

// ---- yfin: sum flagged chunk partials, /Z + 1e-8*SumV -> bf16 padded Yt ----
__global__ __launch_bounds__(256) void yfin_kernel(
    const float* __restrict__ Ypart, const int* __restrict__ flags,
    const float* __restrict__ Zacc, const float* __restrict__ SumV,
    unsigned short* __restrict__ Yt) {
  int bucket = blockIdx.x;
  int b = bucket >> 7;
  int m0 = (bucket & 127) * 32;
  int t = threadIdx.x;
  int mi = t >> 3, c0 = (t & 7) * 16;
  int m = m0 + mi;
  __shared__ int fl[16];
  if (t < 16) fl[t] = flags[bucket * 16 + t];
  __syncthreads();
  float rZ = 1.0f / Zacc[(size_t)b * NN + m];
  int h = m >> 6, ww = m & 63;
  const float* yb = Ypart + (size_t)bucket * 16 * (32 * CC) + mi * CC + c0;
  const float* sv = SumV + b * CC + c0;
  unsigned short* yp = Yt + ((size_t)b * YTP + (size_t)(h + 1) * 66 + (ww + 1)) * CC + c0;
  float a[16];
#pragma unroll
  for (int j = 0; j < 16; j++) a[j] = 0.f;
  for (int ks = 0; ks < 16; ks++) {
    if (!fl[ks]) continue;
    const float* ya = yb + (size_t)ks * (32 * CC);
#pragma unroll
    for (int j = 0; j < 4; j++) {
      float4 v = *(const float4*)(ya + 4 * j);
      a[4 * j] += v.x; a[4 * j + 1] += v.y; a[4 * j + 2] += v.z; a[4 * j + 3] += v.w;
    }
  }
  unsigned ov[8];
#pragma unroll
  for (int j = 0; j < 8; j++) {
    float2 s = *(const float2*)(sv + 2 * j);
    float y0 = a[2 * j] * rZ + 1e-8f * s.x;
    float y1 = a[2 * j + 1] * rZ + 1e-8f * s.y;
    ov[j] = (unsigned)f2bf(y0) | ((unsigned)f2bf(y1) << 16);
  }
  uint4 o0; o0.x = ov[0]; o0.y = ov[1]; o0.z = ov[2]; o0.w = ov[3];
  uint4 o1; o1.x = ov[4]; o1.y = ov[5]; o1.z = ov[6]; o1.w = ov[7];
  *(uint4*)yp = o0;
  *(uint4*)(yp + 8) = o1;
}

// ---------------- MFMA 3x3 conv + bias + leaky + residual ------------------
__global__ __launch_bounds__(256, 2) void conv_mfma(
    const unsigned short* __restrict__ Yt, const unsigned short* __restrict__ Wt,
    const float* __restrict__ x, const float* __restrict__ lb,
    float* __restrict__ out) {
  int h = blockIdx.x;
  int by = blockIdx.y;
  int b = blockIdx.z;
  int t = threadIdx.x;
  int wave = t >> 6, lane = t & 63;
  int col = lane & 15, oct = lane >> 4;
  int pxt = wave & 1, cohalf = wave >> 1;
  int w0 = by * 32 + pxt * 16;
  const unsigned short* Yb = Yt + (size_t)b * YTP * CC;

  f32x4 acc[4];
#pragma unroll
  for (int ct = 0; ct < 4; ct++) acc[ct] = (f32x4)0.f;

#pragma unroll
  for (int tap = 0; tap < 9; tap++) {
    int dh = tap / 3 - 1, dw = tap % 3 - 1;
    const unsigned short* ybase =
        Yb + (size_t)((h + 1 + dh) * 66 + (w0 + 1 + dw + col)) * CC;
#pragma unroll
    for (int kc = 0; kc < 4; kc++) {
      bf16x8 Af = *(const bf16x8*)(ybase + 32 * kc + 8 * oct);
#pragma unroll
      for (int ct = 0; ct < 4; ct++) {
        bf16x8 Bf = *(const bf16x8*)(Wt +
            (size_t)(cohalf * 64 + 16 * ct + col) * 1152 + tap * 128 + 32 * kc + 8 * oct);
        acc[ct] = __builtin_amdgcn_mfma_f32_16x16x32_bf16(Af, Bf, acc[ct], 0, 0, 0);
      }
    }
  }
#pragma unroll
  for (int ct = 0; ct < 4; ct++) {
    int co = cohalf * 64 + 16 * ct + col;
    float bv = lb[co];
    int n = h * 64 + w0 + 4 * oct;
    size_t base = ((size_t)b * CC + co) * NN + n;
    float4 xi = *(const float4*)(x + base);
    float4 o;
    float z0 = acc[ct][0] + bv; o.x = ((z0 >= 0.f) ? z0 : 0.2f * z0) + xi.x;
    float z1 = acc[ct][1] + bv; o.y = ((z1 >= 0.f) ? z1 : 0.2f * z1) + xi.y;
    float z2 = acc[ct][2] + bv; o.z = ((z2 >= 0.f) ? z2 : 0.2f * z2) + xi.z;
    float z3 = acc[ct][3] + bv; o.w = ((z3 >= 0.f) ? z3 : 0.2f * z3) + xi.w;
    *(float4*)(out + base) = o;
  }
}

extern "C" void kernel_launch(void* const* d_in, const int* in_sizes, int n_in,
                              void* d_out, int out_size, void* d_ws, size_t ws_size,
                              hipStream_t stream) {
  const float* x    = (const float*)d_in[0];
  const float* q_w  = (const float*)d_in[1];
  const float* q_b  = (const float*)d_in[2];
  const float* v_w  = (const float*)d_in[3];
  const float* v_b  = (const float*)d_in[4];
  const float* lw1w = (const float*)d_in[5];
  const float* lw1b = (const float*)d_in[6];
  const float* lw2w = (const float*)d_in[7];
  const float* lw2b = (const float*)d_in[8];
  const float* bw1w = (const float*)d_in[9];
  const float* bw1b = (const float*)d_in[10];
  const float* bw2w = (const float*)d_in[11];
  const float* bw2b = (const float*)d_in[12];
  const float* linw = (const float*)d_in[13];
  const float* linb = (const float*)d_in[14];
  float* out = (float*)d_out;

  const size_t BCN = (size_t)BB * CC * NN;  // 2,097,152
  const size_t BN  = (size_t)BB * NN;       // 16,384

  unsigned short* xtb = (unsigned short*)d_ws;         // BCN bf16
  unsigned short* qt  = xtb + BCN;                     // BCN
  unsigned short* qtn = qt + BCN;                      // BCN
  unsigned short* vb16 = qtn + BCN;                    // BCN
  unsigned short* Yt  = vb16 + BCN;                    // BB*YTP*CC
  unsigned short* qwb = Yt + (size_t)BB * YTP * CC;    // CC*CC
  unsigned short* vwb = qwb + CC * CC;                 // CC*CC
  unsigned short* hwb = vwb + CC * CC;                 // 64*CC
  unsigned short* Wt  = hwb + 64 * CC;                 // CC*1152
  float* nrmb = (float*)(Wt + (size_t)CC * 1152);      // BN
  float* wmap = nrmb + BN;                             // BN
  float* bmap = wmap + BN;                             // BN
  float* SumV = bmap + BN;                             // BB*CC
  float* Skey = SumV + (size_t)BB * CC;                // BB*CC
  float* c1a  = Skey + (size_t)BB * CC;                // BN
  float* zda  = c1a + BN;                              // BN
  float* Zacc = zda + BN;                              // BN        } zero
  int*   flags = (int*)(Zacc + BN);                    // 512*16    } region
  float* pSkey = (float*)(flags + 512 * 16);           // 256*128
  float* pSumV = pSkey + 256 * 128;                    // 256*128
  float* Ypart = pSumV + 256 * 128;                    // 512*16*4096 f32 (128MB)
  // total ≈ 16 MB bf16 bufs + 4.3 Yt + ~0.6 weights + maps + 128 MB Ypart
  //       ≈ 150 MB < 256 MiB.  Ypart needs no memset (only flagged chunks read).

  size_t zbytes = BN * sizeof(float) + 512 * 16 * sizeof(int);
  hipMemsetAsync(Zacc, 0, zbytes, stream);
  hipMemsetAsync(Yt, 0, (size_t)BB * YTP * CC * sizeof(unsigned short), stream);

  hipLaunchKernelGGL(xt_kernel, dim3(NN / 64, BB), dim3(256), 0, stream, x, xtb);
  hipLaunchKernelGGL(wrepack_kernel, dim3((188416 + 255) / 256), dim3(256), 0,
                     stream, q_w, v_w, lw1w, bw1w, linw, qwb, vwb, hwb, Wt);
  hipLaunchKernelGGL(qv_mfma, dim3(NN / 64, BB), dim3(256), 0, stream,
                     xtb, qwb, vwb, hwb, q_b, v_b, lw1b, lw2w, lw2b,
                     bw1b, bw2w, bw2b, qt, qtn, nrmb, pSkey, vb16, pSumV,
                     wmap, bmap);
  hipLaunchKernelGGL(reduce_kernel, dim3(BB), dim3(256), 0, stream,
                     pSkey, pSumV, Skey, SumV);
  hipLaunchKernelGGL(stats_kernel, dim3(BN / 256), dim3(256), 0, stream,
                     qtn, Skey, nrmb, wmap, bmap, c1a, zda);
  hipLaunchKernelGGL(qk_sparse, dim3(2048), dim3(256), 0, stream,
                     qt, qtn, c1a, zda, Zacc, vb16, Ypart, flags);
  hipLaunchKernelGGL(yfin_kernel, dim3(512), dim3(256), 0, stream,
                     Ypart, flags, Zacc, SumV, Yt);
  hipLaunchKernelGGL(conv_mfma, dim3(HH, 2, BB), dim3(256), 0, stream,
                     Yt, Wt, x, linb, out);
}

// Round 13
// 212.413 us; speedup vs baseline: 1.0480x; 1.0337x over previous
//
#include <hip/hip_runtime.h>
#include <math.h>

#define BB 4
#define CC 128
#define NN 4096
#define HH 64
#define WW 64
#define YTP 4356   // 66*66 padded pixel count

typedef __attribute__((ext_vector_type(8))) short bf16x8;
typedef __attribute__((ext_vector_type(4))) float f32x4;

__device__ inline unsigned short f2bf(float f) {
  unsigned int u = __float_as_uint(f);
  unsigned int r = (u + 0x7FFFu + ((u >> 16) & 1u)) >> 16;
  return (unsigned short)r;
}
__device__ inline float bf2f(short s) {
  union { unsigned u; float f; } x;
  x.u = ((unsigned)(unsigned short)s) << 16;
  return x.f;
}

// ---------------- xt: transpose x -> xtb bf16 [b][n][c] ----------------
__global__ __launch_bounds__(256) void xt_kernel(
    const float* __restrict__ x, unsigned short* __restrict__ xtb) {
  int b = blockIdx.y;
  int n0 = blockIdx.x * 64;
  int t = threadIdx.x;
  __shared__ float xs[CC][65];
  for (int l = 0; l < 32; l++) {
    int idx = t + 256 * l;
    int px = idx & 63, c = idx >> 6;
    xs[c][px] = x[((size_t)b * CC + c) * NN + n0 + px];
  }
  __syncthreads();
  int n = t & 63, ch = t >> 6;
  unsigned o[16];
#pragma unroll
  for (int i = 0; i < 32; i += 2) {
    o[i >> 1] = (unsigned)f2bf(xs[32 * ch + i][n]) |
                ((unsigned)f2bf(xs[32 * ch + i + 1][n]) << 16);
  }
  unsigned short* dst = xtb + ((size_t)b * NN + n0 + n) * CC + 32 * ch;
#pragma unroll
  for (int k = 0; k < 4; k++) {
    uint4 v; v.x = o[4 * k]; v.y = o[4 * k + 1]; v.z = o[4 * k + 2]; v.w = o[4 * k + 3];
    *(uint4*)(dst + 8 * k) = v;
  }
}

// ---------------- wrepack: all weights -> bf16 packed ----------------
__global__ __launch_bounds__(256) void wrepack_kernel(
    const float* __restrict__ qw, const float* __restrict__ vw,
    const float* __restrict__ lw1w, const float* __restrict__ bw1w,
    const float* __restrict__ lw, unsigned short* __restrict__ qwb,
    unsigned short* __restrict__ vwb, unsigned short* __restrict__ hwb,
    unsigned short* __restrict__ Wt) {
  int idx = blockIdx.x * 256 + threadIdx.x;
  if (idx < 16384) { qwb[idx] = f2bf(qw[idx]); return; }
  idx -= 16384;
  if (idx < 16384) { vwb[idx] = f2bf(vw[idx]); return; }
  idx -= 16384;
  if (idx < 4096) { hwb[idx] = f2bf(lw1w[idx]); return; }
  idx -= 4096;
  if (idx < 4096) { hwb[4096 + idx] = f2bf(bw1w[idx]); return; }
  idx -= 4096;
  if (idx < CC * 1152) {
    int co = idx / 1152, rem = idx % 1152;
    int tap = rem >> 7, ci = rem & 127;
    Wt[idx] = f2bf(lw[(size_t)(co * CC + ci) * 9 + tap]);
  }
}

// ------- qv_mfma: q[n][c] + v[c][n] + nrm + qt/qtn + partial Skey/SumV + heads
__global__ __launch_bounds__(256) void qv_mfma(
    const unsigned short* __restrict__ xtb, const unsigned short* __restrict__ qwb,
    const unsigned short* __restrict__ vwb, const unsigned short* __restrict__ hwb,
    const float* __restrict__ qb, const float* __restrict__ vb,
    const float* __restrict__ lw1b, const float* __restrict__ lw2w,
    const float* __restrict__ lw2b, const float* __restrict__ bw1b,
    const float* __restrict__ bw2w, const float* __restrict__ bw2b,
    unsigned short* __restrict__ qt, unsigned short* __restrict__ qtn,
    float* __restrict__ nrm, float* __restrict__ pSkey,
    unsigned short* __restrict__ vbuf, float* __restrict__ pSumV,
    float* __restrict__ wmap, float* __restrict__ bmap) {
  int b = blockIdx.y;
  int nb = blockIdx.x;
  int n0 = nb * 64;
  int t = threadIdx.x, w = t >> 6, lane = t & 63;
  int col = lane & 15, oct = lane >> 4;
  __shared__ float qs[4][16][132];
  __shared__ float partK[4][128];
  __shared__ float partV[4][128];
  const unsigned short* xb = xtb + (size_t)b * NN * CC;

  f32x4 aq[8], av[8];
#pragma unroll
  for (int i = 0; i < 8; i++) { aq[i] = (f32x4)0.f; av[i] = (f32x4)0.f; }
#pragma unroll
  for (int kc = 0; kc < 4; kc++) {
    bf16x8 Xf = *(const bf16x8*)(xb + (size_t)(n0 + 16 * w + col) * CC + kc * 32 + oct * 8);
#pragma unroll
    for (int ct = 0; ct < 8; ct++) {
      bf16x8 Qf = *(const bf16x8*)(qwb + (16 * ct + col) * CC + kc * 32 + oct * 8);
      aq[ct] = __builtin_amdgcn_mfma_f32_16x16x32_bf16(Xf, Qf, aq[ct], 0, 0, 0);
      bf16x8 Vf = *(const bf16x8*)(vwb + (16 * ct + col) * CC + kc * 32 + oct * 8);
      av[ct] = __builtin_amdgcn_mfma_f32_16x16x32_bf16(Vf, Xf, av[ct], 0, 0, 0);
    }
  }

  // ---- v epilogue: v[c][n] bf16 + per-wave SumV partial into LDS ----
  unsigned short* vbb = vbuf + (size_t)b * CC * NN;
#pragma unroll
  for (int ct = 0; ct < 8; ct++) {
#pragma unroll
    for (int r = 0; r < 4; r++) {
      int c = 16 * ct + 4 * oct + r;
      float val = av[ct][r] + vb[c];
      vbb[(size_t)c * NN + n0 + 16 * w + col] = f2bf(val);
      float sv = val;
      sv += __shfl_xor(sv, 1); sv += __shfl_xor(sv, 2);
      sv += __shfl_xor(sv, 4); sv += __shfl_xor(sv, 8);
      if (col == 0) partV[w][c] = sv;
    }
  }

  // ---- q -> LDS (fp32, biased) ----
#pragma unroll
  for (int ct = 0; ct < 8; ct++) {
#pragma unroll
    for (int r = 0; r < 4; r++) {
      int c = 16 * ct + col;
      qs[w][4 * oct + r][c] = aq[ct][r] + qb[c];
    }
  }
  int row = lane >> 2, cq = (lane & 3) * 32;
  float vals[32];
  float ssq = 0.f;
#pragma unroll
  for (int i = 0; i < 32; i += 4) {
    float4 v4 = *(const float4*)&qs[w][row][cq + i];
    vals[i] = v4.x; vals[i + 1] = v4.y; vals[i + 2] = v4.z; vals[i + 3] = v4.w;
    ssq += v4.x * v4.x + v4.y * v4.y + v4.z * v4.z + v4.w * v4.w;
  }
  ssq += __shfl_xor(ssq, 1); ssq += __shfl_xor(ssq, 2);
  float nm = fmaxf(sqrtf(ssq), 1e-4f), sc = 1.0f / nm;
  int gp = b * NN + n0 + 16 * w + row;
  if ((lane & 3) == 0) nrm[gp] = nm;
  unsigned outq[16], outn[16];
  float sk[32];
#pragma unroll
  for (int i = 0; i < 32; i += 2) {
    unsigned short u0 = f2bf(vals[i]), u1 = f2bf(vals[i + 1]);
    unsigned short m0 = f2bf(vals[i] * sc), m1 = f2bf(vals[i + 1] * sc);
    outq[i >> 1] = (unsigned)u0 | ((unsigned)u1 << 16);
    outn[i >> 1] = (unsigned)m0 | ((unsigned)m1 << 16);
    sk[i] = bf2f((short)m0); sk[i + 1] = bf2f((short)m1);
  }
  unsigned short* qtp = qt + (size_t)gp * CC + cq;
  unsigned short* qnp = qtn + (size_t)gp * CC + cq;
#pragma unroll
  for (int k = 0; k < 4; k++) {
    uint4 v; v.x = outq[4 * k]; v.y = outq[4 * k + 1]; v.z = outq[4 * k + 2]; v.w = outq[4 * k + 3];
    *(uint4*)(qtp + 8 * k) = v;
    uint4 u; u.x = outn[4 * k]; u.y = outn[4 * k + 1]; u.z = outn[4 * k + 2]; u.w = outn[4 * k + 3];
    *(uint4*)(qnp + 8 * k) = u;
  }
#pragma unroll
  for (int i = 0; i < 32; i++) {
    float v = sk[i];
    v += __shfl_xor(v, 4); v += __shfl_xor(v, 8);
    v += __shfl_xor(v, 16); v += __shfl_xor(v, 32);
    if ((lane >> 2) == 0) partK[w][cq + i] = v;
  }

  // ---- heads ----
  f32x4 ah[4];
#pragma unroll
  for (int i = 0; i < 4; i++) ah[i] = (f32x4)0.f;
#pragma unroll
  for (int kc = 0; kc < 4; kc++) {
    float4 a0 = *(const float4*)&qs[w][col][kc * 32 + oct * 8];
    float4 a1 = *(const float4*)&qs[w][col][kc * 32 + oct * 8 + 4];
    union { unsigned short s[8]; bf16x8 v; } af;
    af.s[0] = f2bf(a0.x); af.s[1] = f2bf(a0.y); af.s[2] = f2bf(a0.z); af.s[3] = f2bf(a0.w);
    af.s[4] = f2bf(a1.x); af.s[5] = f2bf(a1.y); af.s[6] = f2bf(a1.z); af.s[7] = f2bf(a1.w);
#pragma unroll
    for (int ct = 0; ct < 4; ct++) {
      bf16x8 Bf = *(const bf16x8*)(hwb + (16 * ct + col) * CC + kc * 32 + oct * 8);
      ah[ct] = __builtin_amdgcn_mfma_f32_16x16x32_bf16(af.v, Bf, ah[ct], 0, 0, 0);
    }
  }
  float b1l[2], b1b[2], w2l[2], w2b[2];
#pragma unroll
  for (int ct = 0; ct < 2; ct++) {
    int mid = 16 * ct + col;
    b1l[ct] = lw1b[mid]; w2l[ct] = lw2w[mid];
    b1b[ct] = bw1b[mid]; w2b[ct] = bw2w[mid];
  }
#pragma unroll
  for (int r = 0; r < 4; r++) {
    float wp = 0.f, bp = 0.f;
#pragma unroll
    for (int ct = 0; ct < 2; ct++) {
      float zl = ah[ct][r] + b1l[ct];
      zl = (zl >= 0.f) ? zl : 0.2f * zl;
      wp += w2l[ct] * zl;
      float zb = ah[ct + 2][r] + b1b[ct];
      zb = (zb >= 0.f) ? zb : 0.2f * zb;
      bp += w2b[ct] * zb;
    }
    wp += __shfl_xor(wp, 1); wp += __shfl_xor(wp, 2);
    wp += __shfl_xor(wp, 4); wp += __shfl_xor(wp, 8);
    bp += __shfl_xor(bp, 1); bp += __shfl_xor(bp, 2);
    bp += __shfl_xor(bp, 4); bp += __shfl_xor(bp, 8);
    if (col == 0) {
      int g = b * NN + n0 + 16 * w + 4 * oct + r;
      wmap[g] = wp + lw2b[0];
      bmap[g] = bp + bw2b[0];
    }
  }

  // ---- block reduction of partials -> coalesced global partial vectors ----
  __syncthreads();
  int blk = b * 64 + nb;
  if (t < 128) {
    float s = (partK[0][t] + partK[1][t]) + (partK[2][t] + partK[3][t]);
    pSkey[(size_t)blk * 128 + t] = s;
  } else {
    int c = t - 128;
    float s = (partV[0][c] + partV[1][c]) + (partV[2][c] + partV[3][c]);
    pSumV[(size_t)blk * 128 + c] = s;
  }
}

// ---------------- reduce: partials -> Skey / SumV ----------------
__global__ __launch_bounds__(256) void reduce_kernel(
    const float* __restrict__ pSkey, const float* __restrict__ pSumV,
    float* __restrict__ Skey, float* __restrict__ SumV) {
  int b = blockIdx.x;
  int t = threadIdx.x;
  const float* src = (t < 128) ? pSkey : pSumV;
  int c = t & 127;
  float s = 0.f;
#pragma unroll 8
  for (int nb = 0; nb < 64; nb++)
    s += src[((size_t)b * 64 + nb) * 128 + c];
  if (t < 128) Skey[b * CC + c] = s;
  else SumV[b * CC + c] = s;
}

// ---- stats: per-row c1/zd (dedup: was recomputed by all 16 ks-blocks) ------
__global__ __launch_bounds__(256) void stats_kernel(
    const unsigned short* __restrict__ qtn, const float* __restrict__ Skey,
    const float* __restrict__ nrm, const float* __restrict__ wmap,
    const float* __restrict__ bmap, float* __restrict__ c1a,
    float* __restrict__ zda) {
  int g = blockIdx.x * 256 + threadIdx.x;   // g in [0, BB*NN)
  int b = g >> 12;                          // NN = 4096; 16 blocks per batch
  __shared__ float sk[CC];
  if (threadIdx.x < CC) sk[threadIdx.x] = Skey[b * CC + threadIdx.x];
  __syncthreads();
  const unsigned short* qp = qtn + (size_t)g * CC;
  float dot = 0.f;
#pragma unroll
  for (int i = 0; i < CC; i += 8) {
    bf16x8 v = *(const bf16x8*)(qp + i);
    dot += bf2f(v[0]) * sk[i]     + bf2f(v[1]) * sk[i + 1]
         + bf2f(v[2]) * sk[i + 2] + bf2f(v[3]) * sk[i + 3]
         + bf2f(v[4]) * sk[i + 4] + bf2f(v[5]) * sk[i + 5]
         + bf2f(v[6]) * sk[i + 6] + bf2f(v[7]) * sk[i + 7];
  }
  float c1 = dot * (1.0f / NN) * wmap[g] - bmap[g];
  float nm = nrm[g];
  c1a[g] = c1;
  zda[g] = nm * fmaxf(nm - c1, 0.f);
}

// -------- qk_sparse v8: fused PV, sync slab staging, precomputed stats ------
// grid 2048: lin = mtile*64 + b*16 + ks; 128 m x 256 keys (8 iters).
__global__ __launch_bounds__(256, 2) void qk_sparse(
    const unsigned short* __restrict__ qt, const unsigned short* __restrict__ qtn,
    const float* __restrict__ c1a, const float* __restrict__ zda,
    float* __restrict__ Zacc, const unsigned short* __restrict__ vb16,
    float* __restrict__ Ypart, int* __restrict__ flags) {
  int lin = blockIdx.x;
  int mtile = lin >> 6;
  int bks = lin & 63;
  int b = bks >> 4, ks = bks & 15;
  int t = threadIdx.x, wave = t >> 6, lane = t & 63;
  int col = lane & 15, oct = lane >> 4;
  int m0 = mtile * 128 + 32 * wave;
  int bucket = b * 128 + (m0 >> 5);

  __shared__ unsigned short Bt[8][4096];                 // full 256-key slab, 64 KB
  __shared__ __align__(16) unsigned short tS[4][32][40]; // per-wave P tile

  const unsigned short* qtb  = qt  + (size_t)b * NN * CC;
  const unsigned short* qtnb = qtn + (size_t)b * NN * CC;
  const unsigned short* vbb  = vb16 + (size_t)b * CC * NN;

  bf16x8 A[2][4];
#pragma unroll
  for (int mt = 0; mt < 2; mt++)
#pragma unroll
    for (int kc = 0; kc < 4; kc++)
      A[mt][kc] = *(const bf16x8*)(qtb + (size_t)(m0 + 16 * mt + col) * CC + 32 * kc + 8 * oct);

  // precomputed per-row stats: 2 loads + the same broadcast shuffles
  float stc1[2][4], stzd[2][4];
#pragma unroll
  for (int mt = 0; mt < 2; mt++) {
    int m = m0 + 16 * mt + col;
    float c1 = c1a[(size_t)b * NN + m];
    float zd = zda[(size_t)b * NN + m];
#pragma unroll
    for (int r = 0; r < 4; r++) {
      stc1[mt][r] = __shfl(c1, 4 * oct + r);
      stzd[mt][r] = __shfl(zd, 4 * oct + r);
    }
  }

  int n0base = ks * 256;
  // stage the ENTIRE 256-key slab once: 16 independent uint4 loads/thread
  {
    int f0 = wave, f1 = wave + 4;
    size_t off0 = (size_t)(16 * (f0 >> 2) + col) * CC + (4 * (f0 & 3) + oct) * 8;
    size_t off1 = (size_t)(16 * (f1 >> 2) + col) * CC + (4 * (f1 & 3) + oct) * 8;
#pragma unroll
    for (int it = 0; it < 8; it++) {
      size_t nb0 = (size_t)(n0base + it * 32) * CC;
      uint4 r0 = *(const uint4*)(qtnb + nb0 + off0);
      uint4 r1 = *(const uint4*)(qtnb + nb0 + off1);
      *(uint4*)&Bt[it][f0 * 512 + lane * 8] = r0;
      *(uint4*)&Bt[it][f1 * 512 + lane * 8] = r1;
    }
  }
  __syncthreads();   // the ONLY block-wide barrier

  float zp[2][4];
#pragma unroll
  for (int mt = 0; mt < 2; mt++)
#pragma unroll
    for (int r = 0; r < 4; r++) zp[mt][r] = 0.f;
  // persistent PV accumulators: pvacc[mt][ct] covers (c = 16ct+4oct+r, m = 16mt+col)
  f32x4 pvacc[2][8];
#pragma unroll
  for (int mt = 0; mt < 2; mt++)
#pragma unroll
    for (int ct = 0; ct < 8; ct++) pvacc[mt][ct] = (f32x4)0.f;
  bool didwork = false;

  for (int it = 0; it < 8; it++) {
    f32x4 acc[2][2];
    acc[0][0] = (f32x4)0.f; acc[0][1] = (f32x4)0.f;
    acc[1][0] = (f32x4)0.f; acc[1][1] = (f32x4)0.f;
#pragma unroll
    for (int nt = 0; nt < 2; nt++)
#pragma unroll
      for (int kc = 0; kc < 4; kc++) {
        bf16x8 Bf = *(const bf16x8*)&Bt[it][(nt * 4 + kc) * 512 + lane * 8];
        acc[0][nt] = __builtin_amdgcn_mfma_f32_16x16x32_bf16(A[0][kc], Bf, acc[0][nt], 0, 0, 0);
        acc[1][nt] = __builtin_amdgcn_mfma_f32_16x16x32_bf16(A[1][kc], Bf, acc[1][nt], 0, 0, 0);
      }
    // cheap row-max screen: max_z_row <= max(lmax*relu(lmax-c1), 0)
    float fm = -1e30f;
#pragma unroll
    for (int mt = 0; mt < 2; mt++)
#pragma unroll
      for (int r = 0; r < 4; r++) {
        float lm = fmaxf(acc[mt][0][r], acc[mt][1][r]);
        float ub = fmaxf(lm * fmaxf(lm - stc1[mt][r], 0.f), 0.f);
        fm = fmaxf(fm, ub - stzd[mt][r]);
      }
    if (__any(fm > -18.4207f)) {
      didwork = true;
      int n0 = n0base + it * 32;
#pragma unroll
      for (int mt = 0; mt < 2; mt++)
#pragma unroll
        for (int nt = 0; nt < 2; nt++)
#pragma unroll
          for (int r = 0; r < 4; r++) {
            float l = acc[mt][nt][r];
            float s = l - stc1[mt][r];
            float z = l * fmaxf(s, 0.f);
            float e = __expf(z - stzd[mt][r]);
            zp[mt][r] += e;
            tS[wave][16 * mt + 4 * oct + r][16 * nt + col] = f2bf((s > 0.f) ? e : 0.f);
          }
      // fused PV: P (tS) is in B-fragment layout; V fragments direct from global
      bf16x8 Pa = *(const bf16x8*)&tS[wave][col][8 * oct];
      bf16x8 Pb = *(const bf16x8*)&tS[wave][16 + col][8 * oct];
#pragma unroll
      for (int ct = 0; ct < 8; ct++) {
        bf16x8 Vf = *(const bf16x8*)(vbb + (size_t)(16 * ct + col) * NN + n0 + 8 * oct);
        pvacc[0][ct] = __builtin_amdgcn_mfma_f32_16x16x32_bf16(Vf, Pa, pvacc[0][ct], 0, 0, 0);
        pvacc[1][ct] = __builtin_amdgcn_mfma_f32_16x16x32_bf16(Vf, Pb, pvacc[1][ct], 0, 0, 0);
      }
    }
  }

  if (didwork) {
#pragma unroll
    for (int mt = 0; mt < 2; mt++)
#pragma unroll
      for (int r = 0; r < 4; r++) {
        float v = zp[mt][r];
        v += __shfl_xor(v, 1); v += __shfl_xor(v, 2);
        v += __shfl_xor(v, 4); v += __shfl_xor(v, 8);
        if (col == 0)
          atomicAdd(Zacc + (size_t)b * NN + m0 + 16 * mt + 4 * oct + r, v);
      }
    // write un-normalized PV partial: Ypart chunk [32 m][128 c], single writer
    float* yp = Ypart + ((size_t)bucket * 16 + ks) * (32 * CC);
#pragma unroll
    for (int mt = 0; mt < 2; mt++)
#pragma unroll
      for (int ct = 0; ct < 8; ct++) {
        float4 o;
        o.x = pvacc[mt][ct][0]; o.y = pvacc[mt][ct][1];
        o.z = pvacc[mt][ct][2]; o.w = pvacc[mt][ct][3];
        *(float4*)(yp + (16 * mt + col) * CC + 16 * ct + 4 * oct) = o;
      }
    if (lane == 0) flags[bucket * 16 + ks] = 1;
  }
}

// ---- yfin: sum flagged chunk partials, /Z + 1e-8*SumV -> bf16 padded Yt ----
__global__ __launch_bounds__(256) void yfin_kernel(
    const float* __restrict__ Ypart, const int* __restrict__ flags,
    const float* __restrict__ Zacc, const float* __restrict__ SumV,
    unsigned short* __restrict__ Yt) {
  int bucket = blockIdx.x;
  int b = bucket >> 7;
  int m0 = (bucket & 127) * 32;
  int t = threadIdx.x;
  int mi = t >> 3, c0 = (t & 7) * 16;
  int m = m0 + mi;
  __shared__ int fl[16];
  if (t < 16) fl[t] = flags[bucket * 16 + t];
  __syncthreads();
  float rZ = 1.0f / Zacc[(size_t)b * NN + m];
  int h = m >> 6, ww = m & 63;
  const float* yb = Ypart + (size_t)bucket * 16 * (32 * CC) + mi * CC + c0;
  const float* sv = SumV + b * CC + c0;
  unsigned short* yp = Yt + ((size_t)b * YTP + (size_t)(h + 1) * 66 + (ww + 1)) * CC + c0;
  float a[16];
#pragma unroll
  for (int j = 0; j < 16; j++) a[j] = 0.f;
  for (int ks = 0; ks < 16; ks++) {
    if (!fl[ks]) continue;
    const float* ya = yb + (size_t)ks * (32 * CC);
#pragma unroll
    for (int j = 0; j < 4; j++) {
      float4 v = *(const float4*)(ya + 4 * j);
      a[4 * j] += v.x; a[4 * j + 1] += v.y; a[4 * j + 2] += v.z; a[4 * j + 3] += v.w;
    }
  }
  unsigned ov[8];
#pragma unroll
  for (int j = 0; j < 8; j++) {
    float2 s = *(const float2*)(sv + 2 * j);
    float y0 = a[2 * j] * rZ + 1e-8f * s.x;
    float y1 = a[2 * j + 1] * rZ + 1e-8f * s.y;
    ov[j] = (unsigned)f2bf(y0) | ((unsigned)f2bf(y1) << 16);
  }
  uint4 o0; o0.x = ov[0]; o0.y = ov[1]; o0.z = ov[2]; o0.w = ov[3];
  uint4 o1; o1.x = ov[4]; o1.y = ov[5]; o1.z = ov[6]; o1.w = ov[7];
  *(uint4*)yp = o0;
  *(uint4*)(yp + 8) = o1;
}

// -------- conv v2: MFMA 3x3 conv, LDS-staged halo tile, 4x finer grid -------
// Round-12 evidence: conv at 44.8 us, MfmaUtil 3.65%, occupancy 19% (grid
// 512 = 2 blocks/CU cap), A-fragments scattered per-lane global loads in
// the MFMA chain and duplicated 2x across cohalf waves.  v2: grid (64,4,4)
// = 1024 blocks (4/CU); block stages its 3x18x128 Y-halo tile into LDS once
// (coalesced, XOR-swizzled slot = c16 ^ (row&7) to kill the 256B-stride
// bank conflict, guide G4); 4 waves = 4 channel quarters over the same 16
// pixels.  A from LDS, B from L1/L2-hot Wt.  Per-wave: 72 MFMA, 36 ds_read.
__global__ __launch_bounds__(256, 4) void conv_mfma(
    const unsigned short* __restrict__ Yt, const unsigned short* __restrict__ Wt,
    const float* __restrict__ x, const float* __restrict__ lb,
    float* __restrict__ out) {
  int h = blockIdx.x;
  int by = blockIdx.y;               // 16-pixel column tile
  int b = blockIdx.z;
  int t = threadIdx.x;
  int wave = t >> 6, lane = t & 63;
  int col = lane & 15, oct = lane >> 4;
  int w0 = by * 16;
  __shared__ __align__(16) unsigned short ys[54 * 128];  // 3 x 18 x 128, swizzled

  // stage halo: padded rows h..h+2, padded cols w0..w0+17, all 128 ch
  const unsigned short* Yb = Yt + (size_t)b * YTP * CC;
  for (int e = t; e < 864; e += 256) {     // 864 = 54 rows * 16 uint4
    int row = e >> 4;                      // 0..53
    int c16 = e & 15;
    int dr = row / 18, j = row - dr * 18;
    uint4 v = *(const uint4*)(Yb + ((size_t)(h + dr) * 66 + w0 + j) * CC + c16 * 8);
    int slot = row * 16 + (c16 ^ (row & 7));
    *(uint4*)(ys + slot * 8) = v;
  }
  __syncthreads();

  f32x4 acc[2];
  acc[0] = (f32x4)0.f; acc[1] = (f32x4)0.f;

#pragma unroll
  for (int tap = 0; tap < 9; tap++) {
    int dr = tap / 3, dc = tap % 3;
    int arow = dr * 18 + dc + col;         // pixel row in tile, 0..53
#pragma unroll
    for (int kc = 0; kc < 4; kc++) {
      int slot = arow * 16 + ((kc * 4 + oct) ^ (arow & 7));
      bf16x8 Af = *(const bf16x8*)(ys + slot * 8);
#pragma unroll
      for (int ct = 0; ct < 2; ct++) {
        bf16x8 Bf = *(const bf16x8*)(Wt +
            (size_t)(32 * wave + 16 * ct + col) * 1152 + tap * 128 + 32 * kc + 8 * oct);
        acc[ct] = __builtin_amdgcn_mfma_f32_16x16x32_bf16(Af, Bf, acc[ct], 0, 0, 0);
      }
    }
  }
#pragma unroll
  for (int ct = 0; ct < 2; ct++) {
    int co = 32 * wave + 16 * ct + col;
    float bv = lb[co];
    int n = h * 64 + w0 + 4 * oct;
    size_t base = ((size_t)b * CC + co) * NN + n;
    float4 xi = *(const float4*)(x + base);
    float4 o;
    float z0 = acc[ct][0] + bv; o.x = ((z0 >= 0.f) ? z0 : 0.2f * z0) + xi.x;
    float z1 = acc[ct][1] + bv; o.y = ((z1 >= 0.f) ? z1 : 0.2f * z1) + xi.y;
    float z2 = acc[ct][2] + bv; o.z = ((z2 >= 0.f) ? z2 : 0.2f * z2) + xi.z;
    float z3 = acc[ct][3] + bv; o.w = ((z3 >= 0.f) ? z3 : 0.2f * z3) + xi.w;
    *(float4*)(out + base) = o;
  }
}

extern "C" void kernel_launch(void* const* d_in, const int* in_sizes, int n_in,
                              void* d_out, int out_size, void* d_ws, size_t ws_size,
                              hipStream_t stream) {
  const float* x    = (const float*)d_in[0];
  const float* q_w  = (const float*)d_in[1];
  const float* q_b  = (const float*)d_in[2];
  const float* v_w  = (const float*)d_in[3];
  const float* v_b  = (const float*)d_in[4];
  const float* lw1w = (const float*)d_in[5];
  const float* lw1b = (const float*)d_in[6];
  const float* lw2w = (const float*)d_in[7];
  const float* lw2b = (const float*)d_in[8];
  const float* bw1w = (const float*)d_in[9];
  const float* bw1b = (const float*)d_in[10];
  const float* bw2w = (const float*)d_in[11];
  const float* bw2b = (const float*)d_in[12];
  const float* linw = (const float*)d_in[13];
  const float* linb = (const float*)d_in[14];
  float* out = (float*)d_out;

  const size_t BCN = (size_t)BB * CC * NN;  // 2,097,152
  const size_t BN  = (size_t)BB * NN;       // 16,384

  unsigned short* xtb = (unsigned short*)d_ws;         // BCN bf16
  unsigned short* qt  = xtb + BCN;                     // BCN
  unsigned short* qtn = qt + BCN;                      // BCN
  unsigned short* vb16 = qtn + BCN;                    // BCN
  unsigned short* Yt  = vb16 + BCN;                    // BB*YTP*CC
  unsigned short* qwb = Yt + (size_t)BB * YTP * CC;    // CC*CC
  unsigned short* vwb = qwb + CC * CC;                 // CC*CC
  unsigned short* hwb = vwb + CC * CC;                 // 64*CC
  unsigned short* Wt  = hwb + 64 * CC;                 // CC*1152
  float* nrmb = (float*)(Wt + (size_t)CC * 1152);      // BN
  float* wmap = nrmb + BN;                             // BN
  float* bmap = wmap + BN;                             // BN
  float* SumV = bmap + BN;                             // BB*CC
  float* Skey = SumV + (size_t)BB * CC;                // BB*CC
  float* c1a  = Skey + (size_t)BB * CC;                // BN
  float* zda  = c1a + BN;                              // BN
  float* Zacc = zda + BN;                              // BN        } zero
  int*   flags = (int*)(Zacc + BN);                    // 512*16    } region
  float* pSkey = (float*)(flags + 512 * 16);           // 256*128
  float* pSumV = pSkey + 256 * 128;                    // 256*128
  float* Ypart = pSumV + 256 * 128;                    // 512*16*4096 f32 (128MB)
  // total ≈ 16 MB bf16 bufs + 4.3 Yt + ~0.6 weights + maps + 128 MB Ypart
  //       ≈ 150 MB < 256 MiB.  Ypart needs no memset (only flagged chunks read).

  size_t zbytes = BN * sizeof(float) + 512 * 16 * sizeof(int);
  hipMemsetAsync(Zacc, 0, zbytes, stream);
  hipMemsetAsync(Yt, 0, (size_t)BB * YTP * CC * sizeof(unsigned short), stream);

  hipLaunchKernelGGL(xt_kernel, dim3(NN / 64, BB), dim3(256), 0, stream, x, xtb);
  hipLaunchKernelGGL(wrepack_kernel, dim3((188416 + 255) / 256), dim3(256), 0,
                     stream, q_w, v_w, lw1w, bw1w, linw, qwb, vwb, hwb, Wt);
  hipLaunchKernelGGL(qv_mfma, dim3(NN / 64, BB), dim3(256), 0, stream,
                     xtb, qwb, vwb, hwb, q_b, v_b, lw1b, lw2w, lw2b,
                     bw1b, bw2w, bw2b, qt, qtn, nrmb, pSkey, vb16, pSumV,
                     wmap, bmap);
  hipLaunchKernelGGL(reduce_kernel, dim3(BB), dim3(256), 0, stream,
                     pSkey, pSumV, Skey, SumV);
  hipLaunchKernelGGL(stats_kernel, dim3(BN / 256), dim3(256), 0, stream,
                     qtn, Skey, nrmb, wmap, bmap, c1a, zda);
  hipLaunchKernelGGL(qk_sparse, dim3(2048), dim3(256), 0, stream,
                     qt, qtn, c1a, zda, Zacc, vb16, Ypart, flags);
  hipLaunchKernelGGL(yfin_kernel, dim3(512), dim3(256), 0, stream,
                     Ypart, flags, Zacc, SumV, Yt);
  hipLaunchKernelGGL(conv_mfma, dim3(HH, 4, BB), dim3(256), 0, stream,
                     Yt, Wt, x, linb, out);
}

// Round 14
// 208.587 us; speedup vs baseline: 1.0672x; 1.0183x over previous
//
#include <hip/hip_runtime.h>
#include <math.h>

#define BB 4
#define CC 128
#define NN 4096
#define HH 64
#define WW 64
#define YTP 4356   // 66*66 padded pixel count

typedef __attribute__((ext_vector_type(8))) short bf16x8;
typedef __attribute__((ext_vector_type(4))) float f32x4;

__device__ inline unsigned short f2bf(float f) {
  unsigned int u = __float_as_uint(f);
  unsigned int r = (u + 0x7FFFu + ((u >> 16) & 1u)) >> 16;
  return (unsigned short)r;
}
__device__ inline float bf2f(short s) {
  union { unsigned u; float f; } x;
  x.u = ((unsigned)(unsigned short)s) << 16;
  return x.f;
}

// ---------------- xt: transpose x -> xtb bf16 [b][n][c] ----------------
__global__ __launch_bounds__(256) void xt_kernel(
    const float* __restrict__ x, unsigned short* __restrict__ xtb) {
  int b = blockIdx.y;
  int n0 = blockIdx.x * 64;
  int t = threadIdx.x;
  __shared__ float xs[CC][65];
  for (int l = 0; l < 32; l++) {
    int idx = t + 256 * l;
    int px = idx & 63, c = idx >> 6;
    xs[c][px] = x[((size_t)b * CC + c) * NN + n0 + px];
  }
  __syncthreads();
  int n = t & 63, ch = t >> 6;
  unsigned o[16];
#pragma unroll
  for (int i = 0; i < 32; i += 2) {
    o[i >> 1] = (unsigned)f2bf(xs[32 * ch + i][n]) |
                ((unsigned)f2bf(xs[32 * ch + i + 1][n]) << 16);
  }
  unsigned short* dst = xtb + ((size_t)b * NN + n0 + n) * CC + 32 * ch;
#pragma unroll
  for (int k = 0; k < 4; k++) {
    uint4 v; v.x = o[4 * k]; v.y = o[4 * k + 1]; v.z = o[4 * k + 2]; v.w = o[4 * k + 3];
    *(uint4*)(dst + 8 * k) = v;
  }
}

// ---------------- wrepack: all weights -> bf16 packed ----------------
__global__ __launch_bounds__(256) void wrepack_kernel(
    const float* __restrict__ qw, const float* __restrict__ vw,
    const float* __restrict__ lw1w, const float* __restrict__ bw1w,
    const float* __restrict__ lw, unsigned short* __restrict__ qwb,
    unsigned short* __restrict__ vwb, unsigned short* __restrict__ hwb,
    unsigned short* __restrict__ Wt) {
  int idx = blockIdx.x * 256 + threadIdx.x;
  if (idx < 16384) { qwb[idx] = f2bf(qw[idx]); return; }
  idx -= 16384;
  if (idx < 16384) { vwb[idx] = f2bf(vw[idx]); return; }
  idx -= 16384;
  if (idx < 4096) { hwb[idx] = f2bf(lw1w[idx]); return; }
  idx -= 4096;
  if (idx < 4096) { hwb[4096 + idx] = f2bf(bw1w[idx]); return; }
  idx -= 4096;
  if (idx < CC * 1152) {
    int co = idx / 1152, rem = idx % 1152;
    int tap = rem >> 7, ci = rem & 127;
    Wt[idx] = f2bf(lw[(size_t)(co * CC + ci) * 9 + tap]);
  }
}

// ---- qv_mfma v2: ROLE-SPLIT.  Round-13 evidence: 44.5 us at MfmaUtil 1%,
// occupancy 9% -- grid 256 = 1 block/CU, 1024 waves total (one wave owns a
// 16-pixel group's MFMAs AND the whole serial epilogue).  Wave-count is the
// cap, so split each group across TWO waves: q-wave (q MFMAs, norm, qt/qtn,
// partK, heads) and v-wave (v MFMAs, vbuf, partV).  Block = 2 groups x 2
// roles; grid (128,4) -> 2048 waves = 8/CU, per-wave chain halved.
__global__ __launch_bounds__(256) void qv_mfma(
    const unsigned short* __restrict__ xtb, const unsigned short* __restrict__ qwb,
    const unsigned short* __restrict__ vwb, const unsigned short* __restrict__ hwb,
    const float* __restrict__ qb, const float* __restrict__ vb,
    const float* __restrict__ lw1b, const float* __restrict__ lw2w,
    const float* __restrict__ lw2b, const float* __restrict__ bw1b,
    const float* __restrict__ bw2w, const float* __restrict__ bw2b,
    unsigned short* __restrict__ qt, unsigned short* __restrict__ qtn,
    float* __restrict__ nrm, float* __restrict__ pSkey,
    unsigned short* __restrict__ vbuf, float* __restrict__ pSumV,
    float* __restrict__ wmap, float* __restrict__ bmap) {
  int b = blockIdx.y;
  int nb = blockIdx.x;               // 128 per batch, 32 pixels each
  int t = threadIdx.x, w = t >> 6, lane = t & 63;
  int role = w & 1, pg = w >> 1;     // role 0 = q, 1 = v; pixel group 0..1
  int n0 = nb * 32 + pg * 16;        // this wave-pair's 16 pixels
  int col = lane & 15, oct = lane >> 4;
  __shared__ float qs[2][16][132];
  __shared__ float partK[2][128];
  __shared__ float partV[2][128];
  const unsigned short* xb = xtb + (size_t)b * NN * CC;

  if (role == 1) {
    // ---------------- v path ----------------
    f32x4 av[8];
#pragma unroll
    for (int i = 0; i < 8; i++) av[i] = (f32x4)0.f;
#pragma unroll
    for (int kc = 0; kc < 4; kc++) {
      bf16x8 Xf = *(const bf16x8*)(xb + (size_t)(n0 + col) * CC + kc * 32 + oct * 8);
#pragma unroll
      for (int ct = 0; ct < 8; ct++) {
        bf16x8 Vf = *(const bf16x8*)(vwb + (16 * ct + col) * CC + kc * 32 + oct * 8);
        av[ct] = __builtin_amdgcn_mfma_f32_16x16x32_bf16(Vf, Xf, av[ct], 0, 0, 0);
      }
    }
    unsigned short* vbb = vbuf + (size_t)b * CC * NN;
#pragma unroll
    for (int ct = 0; ct < 8; ct++) {
#pragma unroll
      for (int r = 0; r < 4; r++) {
        int c = 16 * ct + 4 * oct + r;
        float val = av[ct][r] + vb[c];
        vbb[(size_t)c * NN + n0 + col] = f2bf(val);
        float sv = val;
        sv += __shfl_xor(sv, 1); sv += __shfl_xor(sv, 2);
        sv += __shfl_xor(sv, 4); sv += __shfl_xor(sv, 8);
        if (col == 0) partV[pg][c] = sv;
      }
    }
  } else {
    // ---------------- q path ----------------
    f32x4 aq[8];
#pragma unroll
    for (int i = 0; i < 8; i++) aq[i] = (f32x4)0.f;
#pragma unroll
    for (int kc = 0; kc < 4; kc++) {
      bf16x8 Xf = *(const bf16x8*)(xb + (size_t)(n0 + col) * CC + kc * 32 + oct * 8);
#pragma unroll
      for (int ct = 0; ct < 8; ct++) {
        bf16x8 Qf = *(const bf16x8*)(qwb + (16 * ct + col) * CC + kc * 32 + oct * 8);
        aq[ct] = __builtin_amdgcn_mfma_f32_16x16x32_bf16(Xf, Qf, aq[ct], 0, 0, 0);
      }
    }
    // q -> LDS (fp32, biased); same-wave write->read, no block barrier needed
#pragma unroll
    for (int ct = 0; ct < 8; ct++) {
#pragma unroll
      for (int r = 0; r < 4; r++) {
        int c = 16 * ct + col;
        qs[pg][4 * oct + r][c] = aq[ct][r] + qb[c];
      }
    }
    int row = lane >> 2, cq = (lane & 3) * 32;
    float vals[32];
    float ssq = 0.f;
#pragma unroll
    for (int i = 0; i < 32; i += 4) {
      float4 v4 = *(const float4*)&qs[pg][row][cq + i];
      vals[i] = v4.x; vals[i + 1] = v4.y; vals[i + 2] = v4.z; vals[i + 3] = v4.w;
      ssq += v4.x * v4.x + v4.y * v4.y + v4.z * v4.z + v4.w * v4.w;
    }
    ssq += __shfl_xor(ssq, 1); ssq += __shfl_xor(ssq, 2);
    float nm = fmaxf(sqrtf(ssq), 1e-4f), sc = 1.0f / nm;
    int gp = b * NN + n0 + row;
    if ((lane & 3) == 0) nrm[gp] = nm;
    unsigned outq[16], outn[16];
    float sk[32];
#pragma unroll
    for (int i = 0; i < 32; i += 2) {
      unsigned short u0 = f2bf(vals[i]), u1 = f2bf(vals[i + 1]);
      unsigned short m0 = f2bf(vals[i] * sc), m1 = f2bf(vals[i + 1] * sc);
      outq[i >> 1] = (unsigned)u0 | ((unsigned)u1 << 16);
      outn[i >> 1] = (unsigned)m0 | ((unsigned)m1 << 16);
      sk[i] = bf2f((short)m0); sk[i + 1] = bf2f((short)m1);
    }
    unsigned short* qtp = qt + (size_t)gp * CC + cq;
    unsigned short* qnp = qtn + (size_t)gp * CC + cq;
#pragma unroll
    for (int k = 0; k < 4; k++) {
      uint4 v; v.x = outq[4 * k]; v.y = outq[4 * k + 1]; v.z = outq[4 * k + 2]; v.w = outq[4 * k + 3];
      *(uint4*)(qtp + 8 * k) = v;
      uint4 u; u.x = outn[4 * k]; u.y = outn[4 * k + 1]; u.z = outn[4 * k + 2]; u.w = outn[4 * k + 3];
      *(uint4*)(qnp + 8 * k) = u;
    }
#pragma unroll
    for (int i = 0; i < 32; i++) {
      float v = sk[i];
      v += __shfl_xor(v, 4); v += __shfl_xor(v, 8);
      v += __shfl_xor(v, 16); v += __shfl_xor(v, 32);
      if ((lane >> 2) == 0) partK[pg][cq + i] = v;
    }

    // ---- heads ----
    f32x4 ah[4];
#pragma unroll
    for (int i = 0; i < 4; i++) ah[i] = (f32x4)0.f;
#pragma unroll
    for (int kc = 0; kc < 4; kc++) {
      float4 a0 = *(const float4*)&qs[pg][col][kc * 32 + oct * 8];
      float4 a1 = *(const float4*)&qs[pg][col][kc * 32 + oct * 8 + 4];
      union { unsigned short s[8]; bf16x8 v; } af;
      af.s[0] = f2bf(a0.x); af.s[1] = f2bf(a0.y); af.s[2] = f2bf(a0.z); af.s[3] = f2bf(a0.w);
      af.s[4] = f2bf(a1.x); af.s[5] = f2bf(a1.y); af.s[6] = f2bf(a1.z); af.s[7] = f2bf(a1.w);
#pragma unroll
      for (int ct = 0; ct < 4; ct++) {
        bf16x8 Bf = *(const bf16x8*)(hwb + (16 * ct + col) * CC + kc * 32 + oct * 8);
        ah[ct] = __builtin_amdgcn_mfma_f32_16x16x32_bf16(af.v, Bf, ah[ct], 0, 0, 0);
      }
    }
    float b1l[2], b1b[2], w2l[2], w2b[2];
#pragma unroll
    for (int ct = 0; ct < 2; ct++) {
      int mid = 16 * ct + col;
      b1l[ct] = lw1b[mid]; w2l[ct] = lw2w[mid];
      b1b[ct] = bw1b[mid]; w2b[ct] = bw2w[mid];
    }
#pragma unroll
    for (int r = 0; r < 4; r++) {
      float wp = 0.f, bp = 0.f;
#pragma unroll
      for (int ct = 0; ct < 2; ct++) {
        float zl = ah[ct][r] + b1l[ct];
        zl = (zl >= 0.f) ? zl : 0.2f * zl;
        wp += w2l[ct] * zl;
        float zb = ah[ct + 2][r] + b1b[ct];
        zb = (zb >= 0.f) ? zb : 0.2f * zb;
        bp += w2b[ct] * zb;
      }
      wp += __shfl_xor(wp, 1); wp += __shfl_xor(wp, 2);
      wp += __shfl_xor(wp, 4); wp += __shfl_xor(wp, 8);
      bp += __shfl_xor(bp, 1); bp += __shfl_xor(bp, 2);
      bp += __shfl_xor(bp, 4); bp += __shfl_xor(bp, 8);
      if (col == 0) {
        int g = b * NN + n0 + 4 * oct + r;
        wmap[g] = wp + lw2b[0];
        bmap[g] = bp + bw2b[0];
      }
    }
  }

  // ---- block reduction of partials -> coalesced global partial vectors ----
  __syncthreads();
  int blk = b * 128 + nb;
  if (t < 128) {
    float s = partK[0][t] + partK[1][t];
    pSkey[(size_t)blk * 128 + t] = s;
  } else {
    int c = t - 128;
    float s = partV[0][c] + partV[1][c];
    pSumV[(size_t)blk * 128 + c] = s;
  }
}

// ---------------- reduce: partials -> Skey / SumV (128 blocks/batch) -------
__global__ __launch_bounds__(256) void reduce_kernel(
    const float* __restrict__ pSkey, const float* __restrict__ pSumV,
    float* __restrict__ Skey, float* __restrict__ SumV) {
  int b = blockIdx.x;
  int t = threadIdx.x;
  const float* src = (t < 128) ? pSkey : pSumV;
  int c = t & 127;
  float s = 0.f;
#pragma unroll 8
  for (int nb = 0; nb < 128; nb++)
    s += src[((size_t)b * 128 + nb) * 128 + c];
  if (t < 128) Skey[b * CC + c] = s;
  else SumV[b * CC + c] = s;
}

// ---- stats: per-row c1/zd (dedup: was recomputed by all 16 ks-blocks) ------
__global__ __launch_bounds__(256) void stats_kernel(
    const unsigned short* __restrict__ qtn, const float* __restrict__ Skey,
    const float* __restrict__ nrm, const float* __restrict__ wmap,
    const float* __restrict__ bmap, float* __restrict__ c1a,
    float* __restrict__ zda) {
  int g = blockIdx.x * 256 + threadIdx.x;   // g in [0, BB*NN)
  int b = g >> 12;                          // NN = 4096; 16 blocks per batch
  __shared__ float sk[CC];
  if (threadIdx.x < CC) sk[threadIdx.x] = Skey[b * CC + threadIdx.x];
  __syncthreads();
  const unsigned short* qp = qtn + (size_t)g * CC;
  float dot = 0.f;
#pragma unroll
  for (int i = 0; i < CC; i += 8) {
    bf16x8 v = *(const bf16x8*)(qp + i);
    dot += bf2f(v[0]) * sk[i]     + bf2f(v[1]) * sk[i + 1]
         + bf2f(v[2]) * sk[i + 2] + bf2f(v[3]) * sk[i + 3]
         + bf2f(v[4]) * sk[i + 4] + bf2f(v[5]) * sk[i + 5]
         + bf2f(v[6]) * sk[i + 6] + bf2f(v[7]) * sk[i + 7];
  }
  float c1 = dot * (1.0f / NN) * wmap[g] - bmap[g];
  float nm = nrm[g];
  c1a[g] = c1;
  zda[g] = nm * fmaxf(nm - c1, 0.f);
}

// -------- qk_sparse v8: fused PV, sync slab staging, precomputed stats ------
// grid 2048: lin = mtile*64 + b*16 + ks; 128 m x 256 keys (8 iters).
__global__ __launch_bounds__(256, 2) void qk_sparse(
    const unsigned short* __restrict__ qt, const unsigned short* __restrict__ qtn,
    const float* __restrict__ c1a, const float* __restrict__ zda,
    float* __restrict__ Zacc, const unsigned short* __restrict__ vb16,
    float* __restrict__ Ypart, int* __restrict__ flags) {
  int lin = blockIdx.x;
  int mtile = lin >> 6;
  int bks = lin & 63;
  int b = bks >> 4, ks = bks & 15;
  int t = threadIdx.x, wave = t >> 6, lane = t & 63;
  int col = lane & 15, oct = lane >> 4;
  int m0 = mtile * 128 + 32 * wave;
  int bucket = b * 128 + (m0 >> 5);

  __shared__ unsigned short Bt[8][4096];                 // full 256-key slab, 64 KB
  __shared__ __align__(16) unsigned short tS[4][32][40]; // per-wave P tile

  const unsigned short* qtb  = qt  + (size_t)b * NN * CC;
  const unsigned short* qtnb = qtn + (size_t)b * NN * CC;
  const unsigned short* vbb  = vb16 + (size_t)b * CC * NN;

  bf16x8 A[2][4];
#pragma unroll
  for (int mt = 0; mt < 2; mt++)
#pragma unroll
    for (int kc = 0; kc < 4; kc++)
      A[mt][kc] = *(const bf16x8*)(qtb + (size_t)(m0 + 16 * mt + col) * CC + 32 * kc + 8 * oct);

  // precomputed per-row stats: 2 loads + the same broadcast shuffles
  float stc1[2][4], stzd[2][4];
#pragma unroll
  for (int mt = 0; mt < 2; mt++) {
    int m = m0 + 16 * mt + col;
    float c1 = c1a[(size_t)b * NN + m];
    float zd = zda[(size_t)b * NN + m];
#pragma unroll
    for (int r = 0; r < 4; r++) {
      stc1[mt][r] = __shfl(c1, 4 * oct + r);
      stzd[mt][r] = __shfl(zd, 4 * oct + r);
    }
  }

  int n0base = ks * 256;
  // stage the ENTIRE 256-key slab once: 16 independent uint4 loads/thread
  {
    int f0 = wave, f1 = wave + 4;
    size_t off0 = (size_t)(16 * (f0 >> 2) + col) * CC + (4 * (f0 & 3) + oct) * 8;
    size_t off1 = (size_t)(16 * (f1 >> 2) + col) * CC + (4 * (f1 & 3) + oct) * 8;
#pragma unroll
    for (int it = 0; it < 8; it++) {
      size_t nb0 = (size_t)(n0base + it * 32) * CC;
      uint4 r0 = *(const uint4*)(qtnb + nb0 + off0);
      uint4 r1 = *(const uint4*)(qtnb + nb0 + off1);
      *(uint4*)&Bt[it][f0 * 512 + lane * 8] = r0;
      *(uint4*)&Bt[it][f1 * 512 + lane * 8] = r1;
    }
  }
  __syncthreads();   // the ONLY block-wide barrier

  float zp[2][4];
#pragma unroll
  for (int mt = 0; mt < 2; mt++)
#pragma unroll
    for (int r = 0; r < 4; r++) zp[mt][r] = 0.f;
  // persistent PV accumulators: pvacc[mt][ct] covers (c = 16ct+4oct+r, m = 16mt+col)
  f32x4 pvacc[2][8];
#pragma unroll
  for (int mt = 0; mt < 2; mt++)
#pragma unroll
    for (int ct = 0; ct < 8; ct++) pvacc[mt][ct] = (f32x4)0.f;
  bool didwork = false;

  for (int it = 0; it < 8; it++) {
    f32x4 acc[2][2];
    acc[0][0] = (f32x4)0.f; acc[0][1] = (f32x4)0.f;
    acc[1][0] = (f32x4)0.f; acc[1][1] = (f32x4)0.f;
#pragma unroll
    for (int nt = 0; nt < 2; nt++)
#pragma unroll
      for (int kc = 0; kc < 4; kc++) {
        bf16x8 Bf = *(const bf16x8*)&Bt[it][(nt * 4 + kc) * 512 + lane * 8];
        acc[0][nt] = __builtin_amdgcn_mfma_f32_16x16x32_bf16(A[0][kc], Bf, acc[0][nt], 0, 0, 0);
        acc[1][nt] = __builtin_amdgcn_mfma_f32_16x16x32_bf16(A[1][kc], Bf, acc[1][nt], 0, 0, 0);
      }
    // cheap row-max screen: max_z_row <= max(lmax*relu(lmax-c1), 0)
    float fm = -1e30f;
#pragma unroll
    for (int mt = 0; mt < 2; mt++)
#pragma unroll
      for (int r = 0; r < 4; r++) {
        float lm = fmaxf(acc[mt][0][r], acc[mt][1][r]);
        float ub = fmaxf(lm * fmaxf(lm - stc1[mt][r], 0.f), 0.f);
        fm = fmaxf(fm, ub - stzd[mt][r]);
      }
    if (__any(fm > -18.4207f)) {
      didwork = true;
      int n0 = n0base + it * 32;
#pragma unroll
      for (int mt = 0; mt < 2; mt++)
#pragma unroll
        for (int nt = 0; nt < 2; nt++)
#pragma unroll
          for (int r = 0; r < 4; r++) {
            float l = acc[mt][nt][r];
            float s = l - stc1[mt][r];
            float z = l * fmaxf(s, 0.f);
            float e = __expf(z - stzd[mt][r]);
            zp[mt][r] += e;
            tS[wave][16 * mt + 4 * oct + r][16 * nt + col] = f2bf((s > 0.f) ? e : 0.f);
          }
      // fused PV: P (tS) is in B-fragment layout; V fragments direct from global
      bf16x8 Pa = *(const bf16x8*)&tS[wave][col][8 * oct];
      bf16x8 Pb = *(const bf16x8*)&tS[wave][16 + col][8 * oct];
#pragma unroll
      for (int ct = 0; ct < 8; ct++) {
        bf16x8 Vf = *(const bf16x8*)(vbb + (size_t)(16 * ct + col) * NN + n0 + 8 * oct);
        pvacc[0][ct] = __builtin_amdgcn_mfma_f32_16x16x32_bf16(Vf, Pa, pvacc[0][ct], 0, 0, 0);
        pvacc[1][ct] = __builtin_amdgcn_mfma_f32_16x16x32_bf16(Vf, Pb, pvacc[1][ct], 0, 0, 0);
      }
    }
  }

  if (didwork) {
#pragma unroll
    for (int mt = 0; mt < 2; mt++)
#pragma unroll
      for (int r = 0; r < 4; r++) {
        float v = zp[mt][r];
        v += __shfl_xor(v, 1); v += __shfl_xor(v, 2);
        v += __shfl_xor(v, 4); v += __shfl_xor(v, 8);
        if (col == 0)
          atomicAdd(Zacc + (size_t)b * NN + m0 + 16 * mt + 4 * oct + r, v);
      }
    // write un-normalized PV partial: Ypart chunk [32 m][128 c], single writer
    float* yp = Ypart + ((size_t)bucket * 16 + ks) * (32 * CC);
#pragma unroll
    for (int mt = 0; mt < 2; mt++)
#pragma unroll
      for (int ct = 0; ct < 8; ct++) {
        float4 o;
        o.x = pvacc[mt][ct][0]; o.y = pvacc[mt][ct][1];
        o.z = pvacc[mt][ct][2]; o.w = pvacc[mt][ct][3];
        *(float4*)(yp + (16 * mt + col) * CC + 16 * ct + 4 * oct) = o;
      }
    if (lane == 0) flags[bucket * 16 + ks] = 1;
  }
}

// ---- yfin: sum flagged chunk partials, /Z + 1e-8*SumV -> bf16 padded Yt ----
__global__ __launch_bounds__(256) void yfin_kernel(
    const float* __restrict__ Ypart, const int* __restrict__ flags,
    const float* __restrict__ Zacc, const float* __restrict__ SumV,
    unsigned short* __restrict__ Yt) {
  int bucket = blockIdx.x;
  int b = bucket >> 7;
  int m0 = (bucket & 127) * 32;
  int t = threadIdx.x;
  int mi = t >> 3, c0 = (t & 7) * 16;
  int m = m0 + mi;
  __shared__ int fl[16];
  if (t < 16) fl[t] = flags[bucket * 16 + t];
  __syncthreads();
  float rZ = 1.0f / Zacc[(size_t)b * NN + m];
  int h = m >> 6, ww = m & 63;
  const float* yb = Ypart + (size_t)bucket * 16 * (32 * CC) + mi * CC + c0;
  const float* sv = SumV + b * CC + c0;
  unsigned short* yp = Yt + ((size_t)b * YTP + (size_t)(h + 1) * 66 + (ww + 1)) * CC + c0;
  float a[16];
#pragma unroll
  for (int j = 0; j < 16; j++) a[j] = 0.f;
  for (int ks = 0; ks < 16; ks++) {
    if (!fl[ks]) continue;
    const float* ya = yb + (size_t)ks * (32 * CC);
#pragma unroll
    for (int j = 0; j < 4; j++) {
      float4 v = *(const float4*)(ya + 4 * j);
      a[4 * j] += v.x; a[4 * j + 1] += v.y; a[4 * j + 2] += v.z; a[4 * j + 3] += v.w;
    }
  }
  unsigned ov[8];
#pragma unroll
  for (int j = 0; j < 8; j++) {
    float2 s = *(const float2*)(sv + 2 * j);
    float y0 = a[2 * j] * rZ + 1e-8f * s.x;
    float y1 = a[2 * j + 1] * rZ + 1e-8f * s.y;
    ov[j] = (unsigned)f2bf(y0) | ((unsigned)f2bf(y1) << 16);
  }
  uint4 o0; o0.x = ov[0]; o0.y = ov[1]; o0.z = ov[2]; o0.w = ov[3];
  uint4 o1; o1.x = ov[4]; o1.y = ov[5]; o1.z = ov[6]; o1.w = ov[7];
  *(uint4*)yp = o0;
  *(uint4*)(yp + 8) = o1;
}

// -------- conv v2: MFMA 3x3 conv, LDS-staged halo tile, 4x finer grid -------
__global__ __launch_bounds__(256, 4) void conv_mfma(
    const unsigned short* __restrict__ Yt, const unsigned short* __restrict__ Wt,
    const float* __restrict__ x, const float* __restrict__ lb,
    float* __restrict__ out) {
  int h = blockIdx.x;
  int by = blockIdx.y;               // 16-pixel column tile
  int b = blockIdx.z;
  int t = threadIdx.x;
  int wave = t >> 6, lane = t & 63;
  int col = lane & 15, oct = lane >> 4;
  int w0 = by * 16;
  __shared__ __align__(16) unsigned short ys[54 * 128];  // 3 x 18 x 128, swizzled

  // stage halo: padded rows h..h+2, padded cols w0..w0+17, all 128 ch
  const unsigned short* Yb = Yt + (size_t)b * YTP * CC;
  for (int e = t; e < 864; e += 256) {     // 864 = 54 rows * 16 uint4
    int row = e >> 4;                      // 0..53
    int c16 = e & 15;
    int dr = row / 18, j = row - dr * 18;
    uint4 v = *(const uint4*)(Yb + ((size_t)(h + dr) * 66 + w0 + j) * CC + c16 * 8);
    int slot = row * 16 + (c16 ^ (row & 7));
    *(uint4*)(ys + slot * 8) = v;
  }
  __syncthreads();

  f32x4 acc[2];
  acc[0] = (f32x4)0.f; acc[1] = (f32x4)0.f;

#pragma unroll
  for (int tap = 0; tap < 9; tap++) {
    int dr = tap / 3, dc = tap % 3;
    int arow = dr * 18 + dc + col;         // pixel row in tile, 0..53
#pragma unroll
    for (int kc = 0; kc < 4; kc++) {
      int slot = arow * 16 + ((kc * 4 + oct) ^ (arow & 7));
      bf16x8 Af = *(const bf16x8*)(ys + slot * 8);
#pragma unroll
      for (int ct = 0; ct < 2; ct++) {
        bf16x8 Bf = *(const bf16x8*)(Wt +
            (size_t)(32 * wave + 16 * ct + col) * 1152 + tap * 128 + 32 * kc + 8 * oct);
        acc[ct] = __builtin_amdgcn_mfma_f32_16x16x32_bf16(Af, Bf, acc[ct], 0, 0, 0);
      }
    }
  }
#pragma unroll
  for (int ct = 0; ct < 2; ct++) {
    int co = 32 * wave + 16 * ct + col;
    float bv = lb[co];
    int n = h * 64 + w0 + 4 * oct;
    size_t base = ((size_t)b * CC + co) * NN + n;
    float4 xi = *(const float4*)(x + base);
    float4 o;
    float z0 = acc[ct][0] + bv; o.x = ((z0 >= 0.f) ? z0 : 0.2f * z0) + xi.x;
    float z1 = acc[ct][1] + bv; o.y = ((z1 >= 0.f) ? z1 : 0.2f * z1) + xi.y;
    float z2 = acc[ct][2] + bv; o.z = ((z2 >= 0.f) ? z2 : 0.2f * z2) + xi.z;
    float z3 = acc[ct][3] + bv; o.w = ((z3 >= 0.f) ? z3 : 0.2f * z3) + xi.w;
    *(float4*)(out + base) = o;
  }
}

extern "C" void kernel_launch(void* const* d_in, const int* in_sizes, int n_in,
                              void* d_out, int out_size, void* d_ws, size_t ws_size,
                              hipStream_t stream) {
  const float* x    = (const float*)d_in[0];
  const float* q_w  = (const float*)d_in[1];
  const float* q_b  = (const float*)d_in[2];
  const float* v_w  = (const float*)d_in[3];
  const float* v_b  = (const float*)d_in[4];
  const float* lw1w = (const float*)d_in[5];
  const float* lw1b = (const float*)d_in[6];
  const float* lw2w = (const float*)d_in[7];
  const float* lw2b = (const float*)d_in[8];
  const float* bw1w = (const float*)d_in[9];
  const float* bw1b = (const float*)d_in[10];
  const float* bw2w = (const float*)d_in[11];
  const float* bw2b = (const float*)d_in[12];
  const float* linw = (const float*)d_in[13];
  const float* linb = (const float*)d_in[14];
  float* out = (float*)d_out;

  const size_t BCN = (size_t)BB * CC * NN;  // 2,097,152
  const size_t BN  = (size_t)BB * NN;       // 16,384

  unsigned short* xtb = (unsigned short*)d_ws;         // BCN bf16
  unsigned short* qt  = xtb + BCN;                     // BCN
  unsigned short* qtn = qt + BCN;                      // BCN
  unsigned short* vb16 = qtn + BCN;                    // BCN
  unsigned short* Yt  = vb16 + BCN;                    // BB*YTP*CC
  unsigned short* qwb = Yt + (size_t)BB * YTP * CC;    // CC*CC
  unsigned short* vwb = qwb + CC * CC;                 // CC*CC
  unsigned short* hwb = vwb + CC * CC;                 // 64*CC
  unsigned short* Wt  = hwb + 64 * CC;                 // CC*1152
  float* nrmb = (float*)(Wt + (size_t)CC * 1152);      // BN
  float* wmap = nrmb + BN;                             // BN
  float* bmap = wmap + BN;                             // BN
  float* SumV = bmap + BN;                             // BB*CC
  float* Skey = SumV + (size_t)BB * CC;                // BB*CC
  float* c1a  = Skey + (size_t)BB * CC;                // BN
  float* zda  = c1a + BN;                              // BN
  float* Zacc = zda + BN;                              // BN        } zero
  int*   flags = (int*)(Zacc + BN);                    // 512*16    } region
  float* pSkey = (float*)(flags + 512 * 16);           // 512*128
  float* pSumV = pSkey + 512 * 128;                    // 512*128
  float* Ypart = pSumV + 512 * 128;                    // 512*16*4096 f32 (128MB)
  // total ≈ 16 MB bf16 bufs + 4.3 Yt + ~0.6 weights + maps + 128 MB Ypart
  //       ≈ 150 MB < 256 MiB.  Ypart needs no memset (only flagged chunks read).

  size_t zbytes = BN * sizeof(float) + 512 * 16 * sizeof(int);
  hipMemsetAsync(Zacc, 0, zbytes, stream);
  hipMemsetAsync(Yt, 0, (size_t)BB * YTP * CC * sizeof(unsigned short), stream);

  hipLaunchKernelGGL(xt_kernel, dim3(NN / 64, BB), dim3(256), 0, stream, x, xtb);
  hipLaunchKernelGGL(wrepack_kernel, dim3((188416 + 255) / 256), dim3(256), 0,
                     stream, q_w, v_w, lw1w, bw1w, linw, qwb, vwb, hwb, Wt);
  hipLaunchKernelGGL(qv_mfma, dim3(NN / 32, BB), dim3(256), 0, stream,
                     xtb, qwb, vwb, hwb, q_b, v_b, lw1b, lw2w, lw2b,
                     bw1b, bw2w, bw2b, qt, qtn, nrmb, pSkey, vb16, pSumV,
                     wmap, bmap);
  hipLaunchKernelGGL(reduce_kernel, dim3(BB), dim3(256), 0, stream,
                     pSkey, pSumV, Skey, SumV);
  hipLaunchKernelGGL(stats_kernel, dim3(BN / 256), dim3(256), 0, stream,
                     qtn, Skey, nrmb, wmap, bmap, c1a, zda);
  hipLaunchKernelGGL(qk_sparse, dim3(2048), dim3(256), 0, stream,
                     qt, qtn, c1a, zda, Zacc, vb16, Ypart, flags);
  hipLaunchKernelGGL(yfin_kernel, dim3(512), dim3(256), 0, stream,
                     Ypart, flags, Zacc, SumV, Yt);
  hipLaunchKernelGGL(conv_mfma, dim3(HH, 4, BB), dim3(256), 0, stream,
                     Yt, Wt, x, linb, out);
}

// Round 15
// 204.123 us; speedup vs baseline: 1.0906x; 1.0219x over previous
//
#include <hip/hip_runtime.h>
#include <math.h>

#define BB 4
#define CC 128
#define NN 4096
#define HH 64
#define WW 64
#define YTP 4356   // 66*66 padded pixel count

typedef __attribute__((ext_vector_type(8))) short bf16x8;
typedef __attribute__((ext_vector_type(4))) float f32x4;

__device__ inline unsigned short f2bf(float f) {
  unsigned int u = __float_as_uint(f);
  unsigned int r = (u + 0x7FFFu + ((u >> 16) & 1u)) >> 16;
  return (unsigned short)r;
}
__device__ inline float bf2f(short s) {
  union { unsigned u; float f; } x;
  x.u = ((unsigned)(unsigned short)s) << 16;
  return x.f;
}

// ---------------- wrepack: all weights -> bf16 packed ----------------
__global__ __launch_bounds__(256) void wrepack_kernel(
    const float* __restrict__ qw, const float* __restrict__ vw,
    const float* __restrict__ lw1w, const float* __restrict__ bw1w,
    const float* __restrict__ lw, unsigned short* __restrict__ qwb,
    unsigned short* __restrict__ vwb, unsigned short* __restrict__ hwb,
    unsigned short* __restrict__ Wt) {
  int idx = blockIdx.x * 256 + threadIdx.x;
  if (idx < 16384) { qwb[idx] = f2bf(qw[idx]); return; }
  idx -= 16384;
  if (idx < 16384) { vwb[idx] = f2bf(vw[idx]); return; }
  idx -= 16384;
  if (idx < 4096) { hwb[idx] = f2bf(lw1w[idx]); return; }
  idx -= 4096;
  if (idx < 4096) { hwb[4096 + idx] = f2bf(bw1w[idx]); return; }
  idx -= 4096;
  if (idx < CC * 1152) {
    int co = idx / 1152, rem = idx % 1152;
    int tap = rem >> 7, ci = rem & 127;
    Wt[idx] = f2bf(lw[(size_t)(co * CC + ci) * 9 + tap]);
  }
}

// ---- qv_mfma v3: FUSED TRANSPOSE.  Round-14 insight: xt_kernel's only
// consumer was this kernel (xtb dead otherwise) -- 64 MB of global round-
// trip + a launch to move 16 KB/block.  Fuse: block stages x[c][n] f32
// coalesced into LDS (pad+1), transposes/packs to swizzled bf16 [pixel][ch]
// (conv-proven c16^(j&7) swizzle; fragment reads 2-way = free), and all 4
// waves share the one copy (old code read X fragments 4x from global).
// Role-split retained: q-wave / v-wave per 16-pixel group, grid (128, 4).
__global__ __launch_bounds__(256) void qv_mfma(
    const float* __restrict__ x, const unsigned short* __restrict__ qwb,
    const unsigned short* __restrict__ vwb, const unsigned short* __restrict__ hwb,
    const float* __restrict__ qb, const float* __restrict__ vb,
    const float* __restrict__ lw1b, const float* __restrict__ lw2w,
    const float* __restrict__ lw2b, const float* __restrict__ bw1b,
    const float* __restrict__ bw2w, const float* __restrict__ bw2b,
    unsigned short* __restrict__ qt, unsigned short* __restrict__ qtn,
    float* __restrict__ nrm, float* __restrict__ pSkey,
    unsigned short* __restrict__ vbuf, float* __restrict__ pSumV,
    float* __restrict__ wmap, float* __restrict__ bmap) {
  int b = blockIdx.y;
  int nb = blockIdx.x;               // 128 per batch, 32 pixels each
  int t = threadIdx.x, w = t >> 6, lane = t & 63;
  int role = w & 1, pg = w >> 1;     // role 0 = q, 1 = v; pixel group 0..1
  int n0g = nb * 32;                 // block's 32 pixels
  int n0 = n0g + pg * 16;            // this wave-pair's 16 pixels
  int col = lane & 15, oct = lane >> 4;
  __shared__ float xs[CC][33];                           // f32 transpose stage
  __shared__ __align__(16) unsigned short xsb[32 * 128]; // swizzled bf16 [px][ch]
  __shared__ float qs[2][16][132];
  __shared__ float partK[2][128];
  __shared__ float partV[2][128];

  // pass 1: coalesced load of x[c][n0g..n0g+31] (128 rows x 128 B)
#pragma unroll
  for (int l = 0; l < 16; l++) {
    int e = t + 256 * l;             // 4096 elements
    int c = e >> 5, j = e & 31;
    xs[c][j] = x[((size_t)b * CC + c) * NN + n0g + j];
  }
  __syncthreads();
  // pass 2: transpose + bf16 pack into swizzled [pixel][ch] uint4 grid
#pragma unroll
  for (int l = 0; l < 2; l++) {
    int e = t + 256 * l;             // 512 items = 32 px x 16 uint4
    int j = e >> 4, c16 = e & 15;
    unsigned short u[8];
#pragma unroll
    for (int k = 0; k < 8; k++) u[k] = f2bf(xs[c16 * 8 + k][j]);
    uint4 v;
    v.x = (unsigned)u[0] | ((unsigned)u[1] << 16);
    v.y = (unsigned)u[2] | ((unsigned)u[3] << 16);
    v.z = (unsigned)u[4] | ((unsigned)u[5] << 16);
    v.w = (unsigned)u[6] | ((unsigned)u[7] << 16);
    int slot = j * 16 + (c16 ^ (j & 7));
    *(uint4*)(xsb + slot * 8) = v;
  }
  __syncthreads();

  int xrow = pg * 16 + col;          // this lane's pixel row in the tile
  if (role == 1) {
    // ---------------- v path ----------------
    f32x4 av[8];
#pragma unroll
    for (int i = 0; i < 8; i++) av[i] = (f32x4)0.f;
#pragma unroll
    for (int kc = 0; kc < 4; kc++) {
      bf16x8 Xf = *(const bf16x8*)(xsb + (xrow * 16 + ((kc * 4 + oct) ^ (xrow & 7))) * 8);
#pragma unroll
      for (int ct = 0; ct < 8; ct++) {
        bf16x8 Vf = *(const bf16x8*)(vwb + (16 * ct + col) * CC + kc * 32 + oct * 8);
        av[ct] = __builtin_amdgcn_mfma_f32_16x16x32_bf16(Vf, Xf, av[ct], 0, 0, 0);
      }
    }
    unsigned short* vbb = vbuf + (size_t)b * CC * NN;
#pragma unroll
    for (int ct = 0; ct < 8; ct++) {
#pragma unroll
      for (int r = 0; r < 4; r++) {
        int c = 16 * ct + 4 * oct + r;
        float val = av[ct][r] + vb[c];
        vbb[(size_t)c * NN + n0 + col] = f2bf(val);
        float sv = val;
        sv += __shfl_xor(sv, 1); sv += __shfl_xor(sv, 2);
        sv += __shfl_xor(sv, 4); sv += __shfl_xor(sv, 8);
        if (col == 0) partV[pg][c] = sv;
      }
    }
  } else {
    // ---------------- q path ----------------
    f32x4 aq[8];
#pragma unroll
    for (int i = 0; i < 8; i++) aq[i] = (f32x4)0.f;
#pragma unroll
    for (int kc = 0; kc < 4; kc++) {
      bf16x8 Xf = *(const bf16x8*)(xsb + (xrow * 16 + ((kc * 4 + oct) ^ (xrow & 7))) * 8);
#pragma unroll
      for (int ct = 0; ct < 8; ct++) {
        bf16x8 Qf = *(const bf16x8*)(qwb + (16 * ct + col) * CC + kc * 32 + oct * 8);
        aq[ct] = __builtin_amdgcn_mfma_f32_16x16x32_bf16(Xf, Qf, aq[ct], 0, 0, 0);
      }
    }
    // q -> LDS (fp32, biased); same-wave write->read, no block barrier needed
#pragma unroll
    for (int ct = 0; ct < 8; ct++) {
#pragma unroll
      for (int r = 0; r < 4; r++) {
        int c = 16 * ct + col;
        qs[pg][4 * oct + r][c] = aq[ct][r] + qb[c];
      }
    }
    int row = lane >> 2, cq = (lane & 3) * 32;
    float vals[32];
    float ssq = 0.f;
#pragma unroll
    for (int i = 0; i < 32; i += 4) {
      float4 v4 = *(const float4*)&qs[pg][row][cq + i];
      vals[i] = v4.x; vals[i + 1] = v4.y; vals[i + 2] = v4.z; vals[i + 3] = v4.w;
      ssq += v4.x * v4.x + v4.y * v4.y + v4.z * v4.z + v4.w * v4.w;
    }
    ssq += __shfl_xor(ssq, 1); ssq += __shfl_xor(ssq, 2);
    float nm = fmaxf(sqrtf(ssq), 1e-4f), sc = 1.0f / nm;
    int gp = b * NN + n0 + row;
    if ((lane & 3) == 0) nrm[gp] = nm;
    unsigned outq[16], outn[16];
    float sk[32];
#pragma unroll
    for (int i = 0; i < 32; i += 2) {
      unsigned short u0 = f2bf(vals[i]), u1 = f2bf(vals[i + 1]);
      unsigned short m0 = f2bf(vals[i] * sc), m1 = f2bf(vals[i + 1] * sc);
      outq[i >> 1] = (unsigned)u0 | ((unsigned)u1 << 16);
      outn[i >> 1] = (unsigned)m0 | ((unsigned)m1 << 16);
      sk[i] = bf2f((short)m0); sk[i + 1] = bf2f((short)m1);
    }
    unsigned short* qtp = qt + (size_t)gp * CC + cq;
    unsigned short* qnp = qtn + (size_t)gp * CC + cq;
#pragma unroll
    for (int k = 0; k < 4; k++) {
      uint4 v; v.x = outq[4 * k]; v.y = outq[4 * k + 1]; v.z = outq[4 * k + 2]; v.w = outq[4 * k + 3];
      *(uint4*)(qtp + 8 * k) = v;
      uint4 u; u.x = outn[4 * k]; u.y = outn[4 * k + 1]; u.z = outn[4 * k + 2]; u.w = outn[4 * k + 3];
      *(uint4*)(qnp + 8 * k) = u;
    }
#pragma unroll
    for (int i = 0; i < 32; i++) {
      float v = sk[i];
      v += __shfl_xor(v, 4); v += __shfl_xor(v, 8);
      v += __shfl_xor(v, 16); v += __shfl_xor(v, 32);
      if ((lane >> 2) == 0) partK[pg][cq + i] = v;
    }

    // ---- heads ----
    f32x4 ah[4];
#pragma unroll
    for (int i = 0; i < 4; i++) ah[i] = (f32x4)0.f;
#pragma unroll
    for (int kc = 0; kc < 4; kc++) {
      float4 a0 = *(const float4*)&qs[pg][col][kc * 32 + oct * 8];
      float4 a1 = *(const float4*)&qs[pg][col][kc * 32 + oct * 8 + 4];
      union { unsigned short s[8]; bf16x8 v; } af;
      af.s[0] = f2bf(a0.x); af.s[1] = f2bf(a0.y); af.s[2] = f2bf(a0.z); af.s[3] = f2bf(a0.w);
      af.s[4] = f2bf(a1.x); af.s[5] = f2bf(a1.y); af.s[6] = f2bf(a1.z); af.s[7] = f2bf(a1.w);
#pragma unroll
      for (int ct = 0; ct < 4; ct++) {
        bf16x8 Bf = *(const bf16x8*)(hwb + (16 * ct + col) * CC + kc * 32 + oct * 8);
        ah[ct] = __builtin_amdgcn_mfma_f32_16x16x32_bf16(af.v, Bf, ah[ct], 0, 0, 0);
      }
    }
    float b1l[2], b1b[2], w2l[2], w2b[2];
#pragma unroll
    for (int ct = 0; ct < 2; ct++) {
      int mid = 16 * ct + col;
      b1l[ct] = lw1b[mid]; w2l[ct] = lw2w[mid];
      b1b[ct] = bw1b[mid]; w2b[ct] = bw2w[mid];
    }
#pragma unroll
    for (int r = 0; r < 4; r++) {
      float wp = 0.f, bp = 0.f;
#pragma unroll
      for (int ct = 0; ct < 2; ct++) {
        float zl = ah[ct][r] + b1l[ct];
        zl = (zl >= 0.f) ? zl : 0.2f * zl;
        wp += w2l[ct] * zl;
        float zb = ah[ct + 2][r] + b1b[ct];
        zb = (zb >= 0.f) ? zb : 0.2f * zb;
        bp += w2b[ct] * zb;
      }
      wp += __shfl_xor(wp, 1); wp += __shfl_xor(wp, 2);
      wp += __shfl_xor(wp, 4); wp += __shfl_xor(wp, 8);
      bp += __shfl_xor(bp, 1); bp += __shfl_xor(bp, 2);
      bp += __shfl_xor(bp, 4); bp += __shfl_xor(bp, 8);
      if (col == 0) {
        int g = b * NN + n0 + 4 * oct + r;
        wmap[g] = wp + lw2b[0];
        bmap[g] = bp + bw2b[0];
      }
    }
  }

  // ---- block reduction of partials -> coalesced global partial vectors ----
  __syncthreads();
  int blk = b * 128 + nb;
  if (t < 128) {
    float s = partK[0][t] + partK[1][t];
    pSkey[(size_t)blk * 128 + t] = s;
  } else {
    int c = t - 128;
    float s = partV[0][c] + partV[1][c];
    pSumV[(size_t)blk * 128 + c] = s;
  }
}

// ---------------- reduce: partials -> Skey / SumV (128 blocks/batch) -------
__global__ __launch_bounds__(256) void reduce_kernel(
    const float* __restrict__ pSkey, const float* __restrict__ pSumV,
    float* __restrict__ Skey, float* __restrict__ SumV) {
  int b = blockIdx.x;
  int t = threadIdx.x;
  const float* src = (t < 128) ? pSkey : pSumV;
  int c = t & 127;
  float s = 0.f;
#pragma unroll 8
  for (int nb = 0; nb < 128; nb++)
    s += src[((size_t)b * 128 + nb) * 128 + c];
  if (t < 128) Skey[b * CC + c] = s;
  else SumV[b * CC + c] = s;
}

// ---- stats: per-row c1/zd (dedup: was recomputed by all 16 ks-blocks) ------
__global__ __launch_bounds__(256) void stats_kernel(
    const unsigned short* __restrict__ qtn, const float* __restrict__ Skey,
    const float* __restrict__ nrm, const float* __restrict__ wmap,
    const float* __restrict__ bmap, float* __restrict__ c1a,
    float* __restrict__ zda) {
  int g = blockIdx.x * 256 + threadIdx.x;   // g in [0, BB*NN)
  int b = g >> 12;                          // NN = 4096; 16 blocks per batch
  __shared__ float sk[CC];
  if (threadIdx.x < CC) sk[threadIdx.x] = Skey[b * CC + threadIdx.x];
  __syncthreads();
  const unsigned short* qp = qtn + (size_t)g * CC;
  float dot = 0.f;
#pragma unroll
  for (int i = 0; i < CC; i += 8) {
    bf16x8 v = *(const bf16x8*)(qp + i);
    dot += bf2f(v[0]) * sk[i]     + bf2f(v[1]) * sk[i + 1]
         + bf2f(v[2]) * sk[i + 2] + bf2f(v[3]) * sk[i + 3]
         + bf2f(v[4]) * sk[i + 4] + bf2f(v[5]) * sk[i + 5]
         + bf2f(v[6]) * sk[i + 6] + bf2f(v[7]) * sk[i + 7];
  }
  float c1 = dot * (1.0f / NN) * wmap[g] - bmap[g];
  float nm = nrm[g];
  c1a[g] = c1;
  zda[g] = nm * fmaxf(nm - c1, 0.f);
}

// -------- qk_sparse v8: fused PV, sync slab staging, precomputed stats ------
// grid 2048: lin = mtile*64 + b*16 + ks; 128 m x 256 keys (8 iters).
__global__ __launch_bounds__(256, 2) void qk_sparse(
    const unsigned short* __restrict__ qt, const unsigned short* __restrict__ qtn,
    const float* __restrict__ c1a, const float* __restrict__ zda,
    float* __restrict__ Zacc, const unsigned short* __restrict__ vb16,
    float* __restrict__ Ypart, int* __restrict__ flags) {
  int lin = blockIdx.x;
  int mtile = lin >> 6;
  int bks = lin & 63;
  int b = bks >> 4, ks = bks & 15;
  int t = threadIdx.x, wave = t >> 6, lane = t & 63;
  int col = lane & 15, oct = lane >> 4;
  int m0 = mtile * 128 + 32 * wave;
  int bucket = b * 128 + (m0 >> 5);

  __shared__ unsigned short Bt[8][4096];                 // full 256-key slab, 64 KB
  __shared__ __align__(16) unsigned short tS[4][32][40]; // per-wave P tile

  const unsigned short* qtb  = qt  + (size_t)b * NN * CC;
  const unsigned short* qtnb = qtn + (size_t)b * NN * CC;
  const unsigned short* vbb  = vb16 + (size_t)b * CC * NN;

  bf16x8 A[2][4];
#pragma unroll
  for (int mt = 0; mt < 2; mt++)
#pragma unroll
    for (int kc = 0; kc < 4; kc++)
      A[mt][kc] = *(const bf16x8*)(qtb + (size_t)(m0 + 16 * mt + col) * CC + 32 * kc + 8 * oct);

  // precomputed per-row stats: 2 loads + the same broadcast shuffles
  float stc1[2][4], stzd[2][4];
#pragma unroll
  for (int mt = 0; mt < 2; mt++) {
    int m = m0 + 16 * mt + col;
    float c1 = c1a[(size_t)b * NN + m];
    float zd = zda[(size_t)b * NN + m];
#pragma unroll
    for (int r = 0; r < 4; r++) {
      stc1[mt][r] = __shfl(c1, 4 * oct + r);
      stzd[mt][r] = __shfl(zd, 4 * oct + r);
    }
  }

  int n0base = ks * 256;
  // stage the ENTIRE 256-key slab once: 16 independent uint4 loads/thread
  {
    int f0 = wave, f1 = wave + 4;
    size_t off0 = (size_t)(16 * (f0 >> 2) + col) * CC + (4 * (f0 & 3) + oct) * 8;
    size_t off1 = (size_t)(16 * (f1 >> 2) + col) * CC + (4 * (f1 & 3) + oct) * 8;
#pragma unroll
    for (int it = 0; it < 8; it++) {
      size_t nb0 = (size_t)(n0base + it * 32) * CC;
      uint4 r0 = *(const uint4*)(qtnb + nb0 + off0);
      uint4 r1 = *(const uint4*)(qtnb + nb0 + off1);
      *(uint4*)&Bt[it][f0 * 512 + lane * 8] = r0;
      *(uint4*)&Bt[it][f1 * 512 + lane * 8] = r1;
    }
  }
  __syncthreads();   // the ONLY block-wide barrier

  float zp[2][4];
#pragma unroll
  for (int mt = 0; mt < 2; mt++)
#pragma unroll
    for (int r = 0; r < 4; r++) zp[mt][r] = 0.f;
  // persistent PV accumulators: pvacc[mt][ct] covers (c = 16ct+4oct+r, m = 16mt+col)
  f32x4 pvacc[2][8];
#pragma unroll
  for (int mt = 0; mt < 2; mt++)
#pragma unroll
    for (int ct = 0; ct < 8; ct++) pvacc[mt][ct] = (f32x4)0.f;
  bool didwork = false;

  for (int it = 0; it < 8; it++) {
    f32x4 acc[2][2];
    acc[0][0] = (f32x4)0.f; acc[0][1] = (f32x4)0.f;
    acc[1][0] = (f32x4)0.f; acc[1][1] = (f32x4)0.f;
#pragma unroll
    for (int nt = 0; nt < 2; nt++)
#pragma unroll
      for (int kc = 0; kc < 4; kc++) {
        bf16x8 Bf = *(const bf16x8*)&Bt[it][(nt * 4 + kc) * 512 + lane * 8];
        acc[0][nt] = __builtin_amdgcn_mfma_f32_16x16x32_bf16(A[0][kc], Bf, acc[0][nt], 0, 0, 0);
        acc[1][nt] = __builtin_amdgcn_mfma_f32_16x16x32_bf16(A[1][kc], Bf, acc[1][nt], 0, 0, 0);
      }
    // cheap row-max screen: max_z_row <= max(lmax*relu(lmax-c1), 0)
    float fm = -1e30f;
#pragma unroll
    for (int mt = 0; mt < 2; mt++)
#pragma unroll
      for (int r = 0; r < 4; r++) {
        float lm = fmaxf(acc[mt][0][r], acc[mt][1][r]);
        float ub = fmaxf(lm * fmaxf(lm - stc1[mt][r], 0.f), 0.f);
        fm = fmaxf(fm, ub - stzd[mt][r]);
      }
    if (__any(fm > -18.4207f)) {
      didwork = true;
      int n0 = n0base + it * 32;
#pragma unroll
      for (int mt = 0; mt < 2; mt++)
#pragma unroll
        for (int nt = 0; nt < 2; nt++)
#pragma unroll
          for (int r = 0; r < 4; r++) {
            float l = acc[mt][nt][r];
            float s = l - stc1[mt][r];
            float z = l * fmaxf(s, 0.f);
            float e = __expf(z - stzd[mt][r]);
            zp[mt][r] += e;
            tS[wave][16 * mt + 4 * oct + r][16 * nt + col] = f2bf((s > 0.f) ? e : 0.f);
          }
      // fused PV: P (tS) is in B-fragment layout; V fragments direct from global
      bf16x8 Pa = *(const bf16x8*)&tS[wave][col][8 * oct];
      bf16x8 Pb = *(const bf16x8*)&tS[wave][16 + col][8 * oct];
#pragma unroll
      for (int ct = 0; ct < 8; ct++) {
        bf16x8 Vf = *(const bf16x8*)(vbb + (size_t)(16 * ct + col) * NN + n0 + 8 * oct);
        pvacc[0][ct] = __builtin_amdgcn_mfma_f32_16x16x32_bf16(Vf, Pa, pvacc[0][ct], 0, 0, 0);
        pvacc[1][ct] = __builtin_amdgcn_mfma_f32_16x16x32_bf16(Vf, Pb, pvacc[1][ct], 0, 0, 0);
      }
    }
  }

  if (didwork) {
#pragma unroll
    for (int mt = 0; mt < 2; mt++)
#pragma unroll
      for (int r = 0; r < 4; r++) {
        float v = zp[mt][r];
        v += __shfl_xor(v, 1); v += __shfl_xor(v, 2);
        v += __shfl_xor(v, 4); v += __shfl_xor(v, 8);
        if (col == 0)
          atomicAdd(Zacc + (size_t)b * NN + m0 + 16 * mt + 4 * oct + r, v);
      }
    // write un-normalized PV partial: Ypart chunk [32 m][128 c], single writer
    float* yp = Ypart + ((size_t)bucket * 16 + ks) * (32 * CC);
#pragma unroll
    for (int mt = 0; mt < 2; mt++)
#pragma unroll
      for (int ct = 0; ct < 8; ct++) {
        float4 o;
        o.x = pvacc[mt][ct][0]; o.y = pvacc[mt][ct][1];
        o.z = pvacc[mt][ct][2]; o.w = pvacc[mt][ct][3];
        *(float4*)(yp + (16 * mt + col) * CC + 16 * ct + 4 * oct) = o;
      }
    if (lane == 0) flags[bucket * 16 + ks] = 1;
  }
}

// ---- yfin: sum flagged chunk partials, /Z + 1e-8*SumV -> bf16 padded Yt ----
__global__ __launch_bounds__(256) void yfin_kernel(
    const float* __restrict__ Ypart, const int* __restrict__ flags,
    const float* __restrict__ Zacc, const float* __restrict__ SumV,
    unsigned short* __restrict__ Yt) {
  int bucket = blockIdx.x;
  int b = bucket >> 7;
  int m0 = (bucket & 127) * 32;
  int t = threadIdx.x;
  int mi = t >> 3, c0 = (t & 7) * 16;
  int m = m0 + mi;
  __shared__ int fl[16];
  if (t < 16) fl[t] = flags[bucket * 16 + t];
  __syncthreads();
  float rZ = 1.0f / Zacc[(size_t)b * NN + m];
  int h = m >> 6, ww = m & 63;
  const float* yb = Ypart + (size_t)bucket * 16 * (32 * CC) + mi * CC + c0;
  const float* sv = SumV + b * CC + c0;
  unsigned short* yp = Yt + ((size_t)b * YTP + (size_t)(h + 1) * 66 + (ww + 1)) * CC + c0;
  float a[16];
#pragma unroll
  for (int j = 0; j < 16; j++) a[j] = 0.f;
  for (int ks = 0; ks < 16; ks++) {
    if (!fl[ks]) continue;
    const float* ya = yb + (size_t)ks * (32 * CC);
#pragma unroll
    for (int j = 0; j < 4; j++) {
      float4 v = *(const float4*)(ya + 4 * j);
      a[4 * j] += v.x; a[4 * j + 1] += v.y; a[4 * j + 2] += v.z; a[4 * j + 3] += v.w;
    }
  }
  unsigned ov[8];
#pragma unroll
  for (int j = 0; j < 8; j++) {
    float2 s = *(const float2*)(sv + 2 * j);
    float y0 = a[2 * j] * rZ + 1e-8f * s.x;
    float y1 = a[2 * j + 1] * rZ + 1e-8f * s.y;
    ov[j] = (unsigned)f2bf(y0) | ((unsigned)f2bf(y1) << 16);
  }
  uint4 o0; o0.x = ov[0]; o0.y = ov[1]; o0.z = ov[2]; o0.w = ov[3];
  uint4 o1; o1.x = ov[4]; o1.y = ov[5]; o1.z = ov[6]; o1.w = ov[7];
  *(uint4*)yp = o0;
  *(uint4*)(yp + 8) = o1;
}

// -------- conv v2: MFMA 3x3 conv, LDS-staged halo tile, 4x finer grid -------
__global__ __launch_bounds__(256, 4) void conv_mfma(
    const unsigned short* __restrict__ Yt, const unsigned short* __restrict__ Wt,
    const float* __restrict__ x, const float* __restrict__ lb,
    float* __restrict__ out) {
  int h = blockIdx.x;
  int by = blockIdx.y;               // 16-pixel column tile
  int b = blockIdx.z;
  int t = threadIdx.x;
  int wave = t >> 6, lane = t & 63;
  int col = lane & 15, oct = lane >> 4;
  int w0 = by * 16;
  __shared__ __align__(16) unsigned short ys[54 * 128];  // 3 x 18 x 128, swizzled

  // stage halo: padded rows h..h+2, padded cols w0..w0+17, all 128 ch
  const unsigned short* Yb = Yt + (size_t)b * YTP * CC;
  for (int e = t; e < 864; e += 256) {     // 864 = 54 rows * 16 uint4
    int row = e >> 4;                      // 0..53
    int c16 = e & 15;
    int dr = row / 18, j = row - dr * 18;
    uint4 v = *(const uint4*)(Yb + ((size_t)(h + dr) * 66 + w0 + j) * CC + c16 * 8);
    int slot = row * 16 + (c16 ^ (row & 7));
    *(uint4*)(ys + slot * 8) = v;
  }
  __syncthreads();

  f32x4 acc[2];
  acc[0] = (f32x4)0.f; acc[1] = (f32x4)0.f;

#pragma unroll
  for (int tap = 0; tap < 9; tap++) {
    int dr = tap / 3, dc = tap % 3;
    int arow = dr * 18 + dc + col;         // pixel row in tile, 0..53
#pragma unroll
    for (int kc = 0; kc < 4; kc++) {
      int slot = arow * 16 + ((kc * 4 + oct) ^ (arow & 7));
      bf16x8 Af = *(const bf16x8*)(ys + slot * 8);
#pragma unroll
      for (int ct = 0; ct < 2; ct++) {
        bf16x8 Bf = *(const bf16x8*)(Wt +
            (size_t)(32 * wave + 16 * ct + col) * 1152 + tap * 128 + 32 * kc + 8 * oct);
        acc[ct] = __builtin_amdgcn_mfma_f32_16x16x32_bf16(Af, Bf, acc[ct], 0, 0, 0);
      }
    }
  }
#pragma unroll
  for (int ct = 0; ct < 2; ct++) {
    int co = 32 * wave + 16 * ct + col;
    float bv = lb[co];
    int n = h * 64 + w0 + 4 * oct;
    size_t base = ((size_t)b * CC + co) * NN + n;
    float4 xi = *(const float4*)(x + base);
    float4 o;
    float z0 = acc[ct][0] + bv; o.x = ((z0 >= 0.f) ? z0 : 0.2f * z0) + xi.x;
    float z1 = acc[ct][1] + bv; o.y = ((z1 >= 0.f) ? z1 : 0.2f * z1) + xi.y;
    float z2 = acc[ct][2] + bv; o.z = ((z2 >= 0.f) ? z2 : 0.2f * z2) + xi.z;
    float z3 = acc[ct][3] + bv; o.w = ((z3 >= 0.f) ? z3 : 0.2f * z3) + xi.w;
    *(float4*)(out + base) = o;
  }
}

extern "C" void kernel_launch(void* const* d_in, const int* in_sizes, int n_in,
                              void* d_out, int out_size, void* d_ws, size_t ws_size,
                              hipStream_t stream) {
  const float* x    = (const float*)d_in[0];
  const float* q_w  = (const float*)d_in[1];
  const float* q_b  = (const float*)d_in[2];
  const float* v_w  = (const float*)d_in[3];
  const float* v_b  = (const float*)d_in[4];
  const float* lw1w = (const float*)d_in[5];
  const float* lw1b = (const float*)d_in[6];
  const float* lw2w = (const float*)d_in[7];
  const float* lw2b = (const float*)d_in[8];
  const float* bw1w = (const float*)d_in[9];
  const float* bw1b = (const float*)d_in[10];
  const float* bw2w = (const float*)d_in[11];
  const float* bw2b = (const float*)d_in[12];
  const float* linw = (const float*)d_in[13];
  const float* linb = (const float*)d_in[14];
  float* out = (float*)d_out;

  const size_t BCN = (size_t)BB * CC * NN;  // 2,097,152
  const size_t BN  = (size_t)BB * NN;       // 16,384

  unsigned short* xtb = (unsigned short*)d_ws;         // BCN bf16 (UNUSED; slot kept)
  unsigned short* qt  = xtb + BCN;                     // BCN
  unsigned short* qtn = qt + BCN;                      // BCN
  unsigned short* vb16 = qtn + BCN;                    // BCN
  unsigned short* Yt  = vb16 + BCN;                    // BB*YTP*CC
  unsigned short* qwb = Yt + (size_t)BB * YTP * CC;    // CC*CC
  unsigned short* vwb = qwb + CC * CC;                 // CC*CC
  unsigned short* hwb = vwb + CC * CC;                 // 64*CC
  unsigned short* Wt  = hwb + 64 * CC;                 // CC*1152
  float* nrmb = (float*)(Wt + (size_t)CC * 1152);      // BN
  float* wmap = nrmb + BN;                             // BN
  float* bmap = wmap + BN;                             // BN
  float* SumV = bmap + BN;                             // BB*CC
  float* Skey = SumV + (size_t)BB * CC;                // BB*CC
  float* c1a  = Skey + (size_t)BB * CC;                // BN
  float* zda  = c1a + BN;                              // BN
  float* Zacc = zda + BN;                              // BN        } zero
  int*   flags = (int*)(Zacc + BN);                    // 512*16    } region
  float* pSkey = (float*)(flags + 512 * 16);           // 512*128
  float* pSumV = pSkey + 512 * 128;                    // 512*128
  float* Ypart = pSumV + 512 * 128;                    // 512*16*4096 f32 (128MB)
  // total ≈ 16 MB bf16 bufs + 4.3 Yt + ~0.6 weights + maps + 128 MB Ypart
  //       ≈ 150 MB < 256 MiB.  Ypart needs no memset (only flagged chunks read).

  size_t zbytes = BN * sizeof(float) + 512 * 16 * sizeof(int);
  hipMemsetAsync(Zacc, 0, zbytes, stream);
  hipMemsetAsync(Yt, 0, (size_t)BB * YTP * CC * sizeof(unsigned short), stream);

  hipLaunchKernelGGL(wrepack_kernel, dim3((188416 + 255) / 256), dim3(256), 0,
                     stream, q_w, v_w, lw1w, bw1w, linw, qwb, vwb, hwb, Wt);
  hipLaunchKernelGGL(qv_mfma, dim3(NN / 32, BB), dim3(256), 0, stream,
                     x, qwb, vwb, hwb, q_b, v_b, lw1b, lw2w, lw2b,
                     bw1b, bw2w, bw2b, qt, qtn, nrmb, pSkey, vb16, pSumV,
                     wmap, bmap);
  hipLaunchKernelGGL(reduce_kernel, dim3(BB), dim3(256), 0, stream,
                     pSkey, pSumV, Skey, SumV);
  hipLaunchKernelGGL(stats_kernel, dim3(BN / 256), dim3(256), 0, stream,
                     qtn, Skey, nrmb, wmap, bmap, c1a, zda);
  hipLaunchKernelGGL(qk_sparse, dim3(2048), dim3(256), 0, stream,
                     qt, qtn, c1a, zda, Zacc, vb16, Ypart, flags);
  hipLaunchKernelGGL(yfin_kernel, dim3(512), dim3(256), 0, stream,
                     Ypart, flags, Zacc, SumV, Yt);
  hipLaunchKernelGGL(conv_mfma, dim3(HH, 4, BB), dim3(256), 0, stream,
                     Yt, Wt, x, linb, out);
}

// Round 16
// 203.256 us; speedup vs baseline: 1.0952x; 1.0043x over previous
//
#include <hip/hip_runtime.h>
#include <math.h>

#define BB 4
#define CC 128
#define NN 4096
#define HH 64
#define WW 64
#define YTP 4356   // 66*66 padded pixel count

typedef __attribute__((ext_vector_type(8))) short bf16x8;
typedef __attribute__((ext_vector_type(4))) float f32x4;

__device__ inline unsigned short f2bf(float f) {
  unsigned int u = __float_as_uint(f);
  unsigned int r = (u + 0x7FFFu + ((u >> 16) & 1u)) >> 16;
  return (unsigned short)r;
}
__device__ inline float bf2f(short s) {
  union { unsigned u; float f; } x;
  x.u = ((unsigned)(unsigned short)s) << 16;
  return x.f;
}

// ---------------- wrepack: all weights -> bf16 packed ----------------
__global__ __launch_bounds__(256) void wrepack_kernel(
    const float* __restrict__ qw, const float* __restrict__ vw,
    const float* __restrict__ lw1w, const float* __restrict__ bw1w,
    const float* __restrict__ lw, unsigned short* __restrict__ qwb,
    unsigned short* __restrict__ vwb, unsigned short* __restrict__ hwb,
    unsigned short* __restrict__ Wt) {
  int idx = blockIdx.x * 256 + threadIdx.x;
  if (idx < 16384) { qwb[idx] = f2bf(qw[idx]); return; }
  idx -= 16384;
  if (idx < 16384) { vwb[idx] = f2bf(vw[idx]); return; }
  idx -= 16384;
  if (idx < 4096) { hwb[idx] = f2bf(lw1w[idx]); return; }
  idx -= 4096;
  if (idx < 4096) { hwb[4096 + idx] = f2bf(bw1w[idx]); return; }
  idx -= 4096;
  if (idx < CC * 1152) {
    int co = idx / 1152, rem = idx % 1152;
    int tap = rem >> 7, ci = rem & 127;
    Wt[idx] = f2bf(lw[(size_t)(co * CC + ci) * 9 + tap]);
  }
}

// ---- qv_mfma v3: fused transpose + role-split (round-15 best) --------------
__global__ __launch_bounds__(256) void qv_mfma(
    const float* __restrict__ x, const unsigned short* __restrict__ qwb,
    const unsigned short* __restrict__ vwb, const unsigned short* __restrict__ hwb,
    const float* __restrict__ qb, const float* __restrict__ vb,
    const float* __restrict__ lw1b, const float* __restrict__ lw2w,
    const float* __restrict__ lw2b, const float* __restrict__ bw1b,
    const float* __restrict__ bw2w, const float* __restrict__ bw2b,
    unsigned short* __restrict__ qt, unsigned short* __restrict__ qtn,
    float* __restrict__ nrm, float* __restrict__ pSkey,
    unsigned short* __restrict__ vbuf, float* __restrict__ pSumV,
    float* __restrict__ wmap, float* __restrict__ bmap) {
  int b = blockIdx.y;
  int nb = blockIdx.x;               // 128 per batch, 32 pixels each
  int t = threadIdx.x, w = t >> 6, lane = t & 63;
  int role = w & 1, pg = w >> 1;     // role 0 = q, 1 = v; pixel group 0..1
  int n0g = nb * 32;                 // block's 32 pixels
  int n0 = n0g + pg * 16;            // this wave-pair's 16 pixels
  int col = lane & 15, oct = lane >> 4;
  __shared__ float xs[CC][33];                           // f32 transpose stage
  __shared__ __align__(16) unsigned short xsb[32 * 128]; // swizzled bf16 [px][ch]
  __shared__ float qs[2][16][132];
  __shared__ float partK[2][128];
  __shared__ float partV[2][128];

  // pass 1: coalesced load of x[c][n0g..n0g+31] (128 rows x 128 B)
#pragma unroll
  for (int l = 0; l < 16; l++) {
    int e = t + 256 * l;             // 4096 elements
    int c = e >> 5, j = e & 31;
    xs[c][j] = x[((size_t)b * CC + c) * NN + n0g + j];
  }
  __syncthreads();
  // pass 2: transpose + bf16 pack into swizzled [pixel][ch] uint4 grid
#pragma unroll
  for (int l = 0; l < 2; l++) {
    int e = t + 256 * l;             // 512 items = 32 px x 16 uint4
    int j = e >> 4, c16 = e & 15;
    unsigned short u[8];
#pragma unroll
    for (int k = 0; k < 8; k++) u[k] = f2bf(xs[c16 * 8 + k][j]);
    uint4 v;
    v.x = (unsigned)u[0] | ((unsigned)u[1] << 16);
    v.y = (unsigned)u[2] | ((unsigned)u[3] << 16);
    v.z = (unsigned)u[4] | ((unsigned)u[5] << 16);
    v.w = (unsigned)u[6] | ((unsigned)u[7] << 16);
    int slot = j * 16 + (c16 ^ (j & 7));
    *(uint4*)(xsb + slot * 8) = v;
  }
  __syncthreads();

  int xrow = pg * 16 + col;          // this lane's pixel row in the tile
  if (role == 1) {
    // ---------------- v path ----------------
    f32x4 av[8];
#pragma unroll
    for (int i = 0; i < 8; i++) av[i] = (f32x4)0.f;
#pragma unroll
    for (int kc = 0; kc < 4; kc++) {
      bf16x8 Xf = *(const bf16x8*)(xsb + (xrow * 16 + ((kc * 4 + oct) ^ (xrow & 7))) * 8);
#pragma unroll
      for (int ct = 0; ct < 8; ct++) {
        bf16x8 Vf = *(const bf16x8*)(vwb + (16 * ct + col) * CC + kc * 32 + oct * 8);
        av[ct] = __builtin_amdgcn_mfma_f32_16x16x32_bf16(Vf, Xf, av[ct], 0, 0, 0);
      }
    }
    unsigned short* vbb = vbuf + (size_t)b * CC * NN;
#pragma unroll
    for (int ct = 0; ct < 8; ct++) {
#pragma unroll
      for (int r = 0; r < 4; r++) {
        int c = 16 * ct + 4 * oct + r;
        float val = av[ct][r] + vb[c];
        vbb[(size_t)c * NN + n0 + col] = f2bf(val);
        float sv = val;
        sv += __shfl_xor(sv, 1); sv += __shfl_xor(sv, 2);
        sv += __shfl_xor(sv, 4); sv += __shfl_xor(sv, 8);
        if (col == 0) partV[pg][c] = sv;
      }
    }
  } else {
    // ---------------- q path ----------------
    f32x4 aq[8];
#pragma unroll
    for (int i = 0; i < 8; i++) aq[i] = (f32x4)0.f;
#pragma unroll
    for (int kc = 0; kc < 4; kc++) {
      bf16x8 Xf = *(const bf16x8*)(xsb + (xrow * 16 + ((kc * 4 + oct) ^ (xrow & 7))) * 8);
#pragma unroll
      for (int ct = 0; ct < 8; ct++) {
        bf16x8 Qf = *(const bf16x8*)(qwb + (16 * ct + col) * CC + kc * 32 + oct * 8);
        aq[ct] = __builtin_amdgcn_mfma_f32_16x16x32_bf16(Xf, Qf, aq[ct], 0, 0, 0);
      }
    }
    // q -> LDS (fp32, biased); same-wave write->read, no block barrier needed
#pragma unroll
    for (int ct = 0; ct < 8; ct++) {
#pragma unroll
      for (int r = 0; r < 4; r++) {
        int c = 16 * ct + col;
        qs[pg][4 * oct + r][c] = aq[ct][r] + qb[c];
      }
    }
    int row = lane >> 2, cq = (lane & 3) * 32;
    float vals[32];
    float ssq = 0.f;
#pragma unroll
    for (int i = 0; i < 32; i += 4) {
      float4 v4 = *(const float4*)&qs[pg][row][cq + i];
      vals[i] = v4.x; vals[i + 1] = v4.y; vals[i + 2] = v4.z; vals[i + 3] = v4.w;
      ssq += v4.x * v4.x + v4.y * v4.y + v4.z * v4.z + v4.w * v4.w;
    }
    ssq += __shfl_xor(ssq, 1); ssq += __shfl_xor(ssq, 2);
    float nm = fmaxf(sqrtf(ssq), 1e-4f), sc = 1.0f / nm;
    int gp = b * NN + n0 + row;
    if ((lane & 3) == 0) nrm[gp] = nm;
    unsigned outq[16], outn[16];
    float sk[32];
#pragma unroll
    for (int i = 0; i < 32; i += 2) {
      unsigned short u0 = f2bf(vals[i]), u1 = f2bf(vals[i + 1]);
      unsigned short m0 = f2bf(vals[i] * sc), m1 = f2bf(vals[i + 1] * sc);
      outq[i >> 1] = (unsigned)u0 | ((unsigned)u1 << 16);
      outn[i >> 1] = (unsigned)m0 | ((unsigned)m1 << 16);
      sk[i] = bf2f((short)m0); sk[i + 1] = bf2f((short)m1);
    }
    unsigned short* qtp = qt + (size_t)gp * CC + cq;
    unsigned short* qnp = qtn + (size_t)gp * CC + cq;
#pragma unroll
    for (int k = 0; k < 4; k++) {
      uint4 v; v.x = outq[4 * k]; v.y = outq[4 * k + 1]; v.z = outq[4 * k + 2]; v.w = outq[4 * k + 3];
      *(uint4*)(qtp + 8 * k) = v;
      uint4 u; u.x = outn[4 * k]; u.y = outn[4 * k + 1]; u.z = outn[4 * k + 2]; u.w = outn[4 * k + 3];
      *(uint4*)(qnp + 8 * k) = u;
    }
#pragma unroll
    for (int i = 0; i < 32; i++) {
      float v = sk[i];
      v += __shfl_xor(v, 4); v += __shfl_xor(v, 8);
      v += __shfl_xor(v, 16); v += __shfl_xor(v, 32);
      if ((lane >> 2) == 0) partK[pg][cq + i] = v;
    }

    // ---- heads ----
    f32x4 ah[4];
#pragma unroll
    for (int i = 0; i < 4; i++) ah[i] = (f32x4)0.f;
#pragma unroll
    for (int kc = 0; kc < 4; kc++) {
      float4 a0 = *(const float4*)&qs[pg][col][kc * 32 + oct * 8];
      float4 a1 = *(const float4*)&qs[pg][col][kc * 32 + oct * 8 + 4];
      union { unsigned short s[8]; bf16x8 v; } af;
      af.s[0] = f2bf(a0.x); af.s[1] = f2bf(a0.y); af.s[2] = f2bf(a0.z); af.s[3] = f2bf(a0.w);
      af.s[4] = f2bf(a1.x); af.s[5] = f2bf(a1.y); af.s[6] = f2bf(a1.z); af.s[7] = f2bf(a1.w);
#pragma unroll
      for (int ct = 0; ct < 4; ct++) {
        bf16x8 Bf = *(const bf16x8*)(hwb + (16 * ct + col) * CC + kc * 32 + oct * 8);
        ah[ct] = __builtin_amdgcn_mfma_f32_16x16x32_bf16(af.v, Bf, ah[ct], 0, 0, 0);
      }
    }
    float b1l[2], b1b[2], w2l[2], w2b[2];
#pragma unroll
    for (int ct = 0; ct < 2; ct++) {
      int mid = 16 * ct + col;
      b1l[ct] = lw1b[mid]; w2l[ct] = lw2w[mid];
      b1b[ct] = bw1b[mid]; w2b[ct] = bw2w[mid];
    }
#pragma unroll
    for (int r = 0; r < 4; r++) {
      float wp = 0.f, bp = 0.f;
#pragma unroll
      for (int ct = 0; ct < 2; ct++) {
        float zl = ah[ct][r] + b1l[ct];
        zl = (zl >= 0.f) ? zl : 0.2f * zl;
        wp += w2l[ct] * zl;
        float zb = ah[ct + 2][r] + b1b[ct];
        zb = (zb >= 0.f) ? zb : 0.2f * zb;
        bp += w2b[ct] * zb;
      }
      wp += __shfl_xor(wp, 1); wp += __shfl_xor(wp, 2);
      wp += __shfl_xor(wp, 4); wp += __shfl_xor(wp, 8);
      bp += __shfl_xor(bp, 1); bp += __shfl_xor(bp, 2);
      bp += __shfl_xor(bp, 4); bp += __shfl_xor(bp, 8);
      if (col == 0) {
        int g = b * NN + n0 + 4 * oct + r;
        wmap[g] = wp + lw2b[0];
        bmap[g] = bp + bw2b[0];
      }
    }
  }

  // ---- block reduction of partials -> coalesced global partial vectors ----
  __syncthreads();
  int blk = b * 128 + nb;
  if (t < 128) {
    float s = partK[0][t] + partK[1][t];
    pSkey[(size_t)blk * 128 + t] = s;
  } else {
    int c = t - 128;
    float s = partV[0][c] + partV[1][c];
    pSumV[(size_t)blk * 128 + c] = s;
  }
}

// ---------------- reduce: partials -> Skey / SumV (128 blocks/batch) -------
__global__ __launch_bounds__(256) void reduce_kernel(
    const float* __restrict__ pSkey, const float* __restrict__ pSumV,
    float* __restrict__ Skey, float* __restrict__ SumV) {
  int b = blockIdx.x;
  int t = threadIdx.x;
  const float* src = (t < 128) ? pSkey : pSumV;
  int c = t & 127;
  float s = 0.f;
#pragma unroll 8
  for (int nb = 0; nb < 128; nb++)
    s += src[((size_t)b * 128 + nb) * 128 + c];
  if (t < 128) Skey[b * CC + c] = s;
  else SumV[b * CC + c] = s;
}

// ---- stats: per-row c1/zd (dedup: was recomputed by all 16 ks-blocks) ------
__global__ __launch_bounds__(256) void stats_kernel(
    const unsigned short* __restrict__ qtn, const float* __restrict__ Skey,
    const float* __restrict__ nrm, const float* __restrict__ wmap,
    const float* __restrict__ bmap, float* __restrict__ c1a,
    float* __restrict__ zda) {
  int g = blockIdx.x * 256 + threadIdx.x;   // g in [0, BB*NN)
  int b = g >> 12;                          // NN = 4096; 16 blocks per batch
  __shared__ float sk[CC];
  if (threadIdx.x < CC) sk[threadIdx.x] = Skey[b * CC + threadIdx.x];
  __syncthreads();
  const unsigned short* qp = qtn + (size_t)g * CC;
  float dot = 0.f;
#pragma unroll
  for (int i = 0; i < CC; i += 8) {
    bf16x8 v = *(const bf16x8*)(qp + i);
    dot += bf2f(v[0]) * sk[i]     + bf2f(v[1]) * sk[i + 1]
         + bf2f(v[2]) * sk[i + 2] + bf2f(v[3]) * sk[i + 3]
         + bf2f(v[4]) * sk[i + 4] + bf2f(v[5]) * sk[i + 5]
         + bf2f(v[6]) * sk[i + 6] + bf2f(v[7]) * sk[i + 7];
  }
  float c1 = dot * (1.0f / NN) * wmap[g] - bmap[g];
  float nm = nrm[g];
  c1a[g] = c1;
  zda[g] = nm * fmaxf(nm - c1, 0.f);
}

// -------- qk_sparse v9: fused PV + T5 setprio around MFMA clusters ----------
// qk's ~43.5 us floor survived 6 structural variants; one untried, evidence-
// based lever remains: s_setprio (guide T5).  It pays where waves on a CU
// are at DIFFERENT phases (attn +4-7%, m191) and is null in lockstep loops
// (m190).  This kernel is barrier-free after staging with waves diverging
// into screen vs survivor-PV phases -- exactly the paying regime.
// grid 2048: lin = mtile*64 + b*16 + ks; 128 m x 256 keys (8 iters).
__global__ __launch_bounds__(256, 2) void qk_sparse(
    const unsigned short* __restrict__ qt, const unsigned short* __restrict__ qtn,
    const float* __restrict__ c1a, const float* __restrict__ zda,
    float* __restrict__ Zacc, const unsigned short* __restrict__ vb16,
    float* __restrict__ Ypart, int* __restrict__ flags) {
  int lin = blockIdx.x;
  int mtile = lin >> 6;
  int bks = lin & 63;
  int b = bks >> 4, ks = bks & 15;
  int t = threadIdx.x, wave = t >> 6, lane = t & 63;
  int col = lane & 15, oct = lane >> 4;
  int m0 = mtile * 128 + 32 * wave;
  int bucket = b * 128 + (m0 >> 5);

  __shared__ unsigned short Bt[8][4096];                 // full 256-key slab, 64 KB
  __shared__ __align__(16) unsigned short tS[4][32][40]; // per-wave P tile

  const unsigned short* qtb  = qt  + (size_t)b * NN * CC;
  const unsigned short* qtnb = qtn + (size_t)b * NN * CC;
  const unsigned short* vbb  = vb16 + (size_t)b * CC * NN;

  bf16x8 A[2][4];
#pragma unroll
  for (int mt = 0; mt < 2; mt++)
#pragma unroll
    for (int kc = 0; kc < 4; kc++)
      A[mt][kc] = *(const bf16x8*)(qtb + (size_t)(m0 + 16 * mt + col) * CC + 32 * kc + 8 * oct);

  // precomputed per-row stats: 2 loads + the same broadcast shuffles
  float stc1[2][4], stzd[2][4];
#pragma unroll
  for (int mt = 0; mt < 2; mt++) {
    int m = m0 + 16 * mt + col;
    float c1 = c1a[(size_t)b * NN + m];
    float zd = zda[(size_t)b * NN + m];
#pragma unroll
    for (int r = 0; r < 4; r++) {
      stc1[mt][r] = __shfl(c1, 4 * oct + r);
      stzd[mt][r] = __shfl(zd, 4 * oct + r);
    }
  }

  int n0base = ks * 256;
  // stage the ENTIRE 256-key slab once: 16 independent uint4 loads/thread
  {
    int f0 = wave, f1 = wave + 4;
    size_t off0 = (size_t)(16 * (f0 >> 2) + col) * CC + (4 * (f0 & 3) + oct) * 8;
    size_t off1 = (size_t)(16 * (f1 >> 2) + col) * CC + (4 * (f1 & 3) + oct) * 8;
#pragma unroll
    for (int it = 0; it < 8; it++) {
      size_t nb0 = (size_t)(n0base + it * 32) * CC;
      uint4 r0 = *(const uint4*)(qtnb + nb0 + off0);
      uint4 r1 = *(const uint4*)(qtnb + nb0 + off1);
      *(uint4*)&Bt[it][f0 * 512 + lane * 8] = r0;
      *(uint4*)&Bt[it][f1 * 512 + lane * 8] = r1;
    }
  }
  __syncthreads();   // the ONLY block-wide barrier

  float zp[2][4];
#pragma unroll
  for (int mt = 0; mt < 2; mt++)
#pragma unroll
    for (int r = 0; r < 4; r++) zp[mt][r] = 0.f;
  // persistent PV accumulators: pvacc[mt][ct] covers (c = 16ct+4oct+r, m = 16mt+col)
  f32x4 pvacc[2][8];
#pragma unroll
  for (int mt = 0; mt < 2; mt++)
#pragma unroll
    for (int ct = 0; ct < 8; ct++) pvacc[mt][ct] = (f32x4)0.f;
  bool didwork = false;

  for (int it = 0; it < 8; it++) {
    f32x4 acc[2][2];
    acc[0][0] = (f32x4)0.f; acc[0][1] = (f32x4)0.f;
    acc[1][0] = (f32x4)0.f; acc[1][1] = (f32x4)0.f;
    __builtin_amdgcn_s_setprio(1);
#pragma unroll
    for (int nt = 0; nt < 2; nt++)
#pragma unroll
      for (int kc = 0; kc < 4; kc++) {
        bf16x8 Bf = *(const bf16x8*)&Bt[it][(nt * 4 + kc) * 512 + lane * 8];
        acc[0][nt] = __builtin_amdgcn_mfma_f32_16x16x32_bf16(A[0][kc], Bf, acc[0][nt], 0, 0, 0);
        acc[1][nt] = __builtin_amdgcn_mfma_f32_16x16x32_bf16(A[1][kc], Bf, acc[1][nt], 0, 0, 0);
      }
    __builtin_amdgcn_s_setprio(0);
    // cheap row-max screen: max_z_row <= max(lmax*relu(lmax-c1), 0)
    float fm = -1e30f;
#pragma unroll
    for (int mt = 0; mt < 2; mt++)
#pragma unroll
      for (int r = 0; r < 4; r++) {
        float lm = fmaxf(acc[mt][0][r], acc[mt][1][r]);
        float ub = fmaxf(lm * fmaxf(lm - stc1[mt][r], 0.f), 0.f);
        fm = fmaxf(fm, ub - stzd[mt][r]);
      }
    if (__any(fm > -18.4207f)) {
      didwork = true;
      int n0 = n0base + it * 32;
#pragma unroll
      for (int mt = 0; mt < 2; mt++)
#pragma unroll
        for (int nt = 0; nt < 2; nt++)
#pragma unroll
          for (int r = 0; r < 4; r++) {
            float l = acc[mt][nt][r];
            float s = l - stc1[mt][r];
            float z = l * fmaxf(s, 0.f);
            float e = __expf(z - stzd[mt][r]);
            zp[mt][r] += e;
            tS[wave][16 * mt + 4 * oct + r][16 * nt + col] = f2bf((s > 0.f) ? e : 0.f);
          }
      // fused PV: P (tS) is in B-fragment layout; V fragments direct from global
      bf16x8 Pa = *(const bf16x8*)&tS[wave][col][8 * oct];
      bf16x8 Pb = *(const bf16x8*)&tS[wave][16 + col][8 * oct];
      __builtin_amdgcn_s_setprio(1);
#pragma unroll
      for (int ct = 0; ct < 8; ct++) {
        bf16x8 Vf = *(const bf16x8*)(vbb + (size_t)(16 * ct + col) * NN + n0 + 8 * oct);
        pvacc[0][ct] = __builtin_amdgcn_mfma_f32_16x16x32_bf16(Vf, Pa, pvacc[0][ct], 0, 0, 0);
        pvacc[1][ct] = __builtin_amdgcn_mfma_f32_16x16x32_bf16(Vf, Pb, pvacc[1][ct], 0, 0, 0);
      }
      __builtin_amdgcn_s_setprio(0);
    }
  }

  if (didwork) {
#pragma unroll
    for (int mt = 0; mt < 2; mt++)
#pragma unroll
      for (int r = 0; r < 4; r++) {
        float v = zp[mt][r];
        v += __shfl_xor(v, 1); v += __shfl_xor(v, 2);
        v += __shfl_xor(v, 4); v += __shfl_xor(v, 8);
        if (col == 0)
          atomicAdd(Zacc + (size_t)b * NN + m0 + 16 * mt + 4 * oct + r, v);
      }
    // write un-normalized PV partial: Ypart chunk [32 m][128 c], single writer
    float* yp = Ypart + ((size_t)bucket * 16 + ks) * (32 * CC);
#pragma unroll
    for (int mt = 0; mt < 2; mt++)
#pragma unroll
      for (int ct = 0; ct < 8; ct++) {
        float4 o;
        o.x = pvacc[mt][ct][0]; o.y = pvacc[mt][ct][1];
        o.z = pvacc[mt][ct][2]; o.w = pvacc[mt][ct][3];
        *(float4*)(yp + (16 * mt + col) * CC + 16 * ct + 4 * oct) = o;
      }
    if (lane == 0) flags[bucket * 16 + ks] = 1;
  }
}

// ---- yfin: chunk-sum + /Z + 1e-8*SumV -> bf16 Yt; also zeroes Yt border ----
// (border zeroing replaces the 4.5 MB Yt memset: interior fully written here,
// border (260 px/batch) zeroed by threads t<48 of each block, disjoint addrs)
__global__ __launch_bounds__(256) void yfin_kernel(
    const float* __restrict__ Ypart, const int* __restrict__ flags,
    const float* __restrict__ Zacc, const float* __restrict__ SumV,
    unsigned short* __restrict__ Yt) {
  int bucket = blockIdx.x;
  int b = bucket >> 7;
  int chunk = bucket & 127;
  int m0 = chunk * 32;
  int t = threadIdx.x;
  // ---- border zero: block covers pixels k = chunk*2, chunk*2+1 (+256+chunk) --
  {
    int slot = t >> 4, q4 = t & 15;
    if (slot < 3) {
      int k = (slot < 2) ? (chunk * 2 + slot) : (chunk < 4 ? 256 + chunk : -1);
      if (k >= 0 && k < 260) {
        int hh, ww;
        if (k < 66)       { hh = 0;            ww = k; }
        else if (k < 132) { hh = 65;           ww = k - 66; }
        else if (k < 196) { hh = k - 132 + 1;  ww = 0; }
        else              { hh = k - 196 + 1;  ww = 65; }
        uint4 z; z.x = 0; z.y = 0; z.z = 0; z.w = 0;
        *(uint4*)(Yt + ((size_t)b * YTP + (size_t)hh * 66 + ww) * CC + q4 * 8) = z;
      }
    }
  }
  int mi = t >> 3, c0 = (t & 7) * 16;
  int m = m0 + mi;
  __shared__ int fl[16];
  if (t < 16) fl[t] = flags[bucket * 16 + t];
  __syncthreads();
  float rZ = 1.0f / Zacc[(size_t)b * NN + m];
  int h = m >> 6, ww = m & 63;
  const float* yb = Ypart + (size_t)bucket * 16 * (32 * CC) + mi * CC + c0;
  const float* sv = SumV + b * CC + c0;
  unsigned short* yp = Yt + ((size_t)b * YTP + (size_t)(h + 1) * 66 + (ww + 1)) * CC + c0;
  float a[16];
#pragma unroll
  for (int j = 0; j < 16; j++) a[j] = 0.f;
  for (int ks = 0; ks < 16; ks++) {
    if (!fl[ks]) continue;
    const float* ya = yb + (size_t)ks * (32 * CC);
#pragma unroll
    for (int j = 0; j < 4; j++) {
      float4 v = *(const float4*)(ya + 4 * j);
      a[4 * j] += v.x; a[4 * j + 1] += v.y; a[4 * j + 2] += v.z; a[4 * j + 3] += v.w;
    }
  }
  unsigned ov[8];
#pragma unroll
  for (int j = 0; j < 8; j++) {
    float2 s = *(const float2*)(sv + 2 * j);
    float y0 = a[2 * j] * rZ + 1e-8f * s.x;
    float y1 = a[2 * j + 1] * rZ + 1e-8f * s.y;
    ov[j] = (unsigned)f2bf(y0) | ((unsigned)f2bf(y1) << 16);
  }
  uint4 o0; o0.x = ov[0]; o0.y = ov[1]; o0.z = ov[2]; o0.w = ov[3];
  uint4 o1; o1.x = ov[4]; o1.y = ov[5]; o1.z = ov[6]; o1.w = ov[7];
  *(uint4*)yp = o0;
  *(uint4*)(yp + 8) = o1;
}

// -------- conv v2: MFMA 3x3 conv, LDS-staged halo tile, 4x finer grid -------
__global__ __launch_bounds__(256, 4) void conv_mfma(
    const unsigned short* __restrict__ Yt, const unsigned short* __restrict__ Wt,
    const float* __restrict__ x, const float* __restrict__ lb,
    float* __restrict__ out) {
  int h = blockIdx.x;
  int by = blockIdx.y;               // 16-pixel column tile
  int b = blockIdx.z;
  int t = threadIdx.x;
  int wave = t >> 6, lane = t & 63;
  int col = lane & 15, oct = lane >> 4;
  int w0 = by * 16;
  __shared__ __align__(16) unsigned short ys[54 * 128];  // 3 x 18 x 128, swizzled

  // stage halo: padded rows h..h+2, padded cols w0..w0+17, all 128 ch
  const unsigned short* Yb = Yt + (size_t)b * YTP * CC;
  for (int e = t; e < 864; e += 256) {     // 864 = 54 rows * 16 uint4
    int row = e >> 4;                      // 0..53
    int c16 = e & 15;
    int dr = row / 18, j = row - dr * 18;
    uint4 v = *(const uint4*)(Yb + ((size_t)(h + dr) * 66 + w0 + j) * CC + c16 * 8);
    int slot = row * 16 + (c16 ^ (row & 7));
    *(uint4*)(ys + slot * 8) = v;
  }
  __syncthreads();

  f32x4 acc[2];
  acc[0] = (f32x4)0.f; acc[1] = (f32x4)0.f;

#pragma unroll
  for (int tap = 0; tap < 9; tap++) {
    int dr = tap / 3, dc = tap % 3;
    int arow = dr * 18 + dc + col;         // pixel row in tile, 0..53
#pragma unroll
    for (int kc = 0; kc < 4; kc++) {
      int slot = arow * 16 + ((kc * 4 + oct) ^ (arow & 7));
      bf16x8 Af = *(const bf16x8*)(ys + slot * 8);
#pragma unroll
      for (int ct = 0; ct < 2; ct++) {
        bf16x8 Bf = *(const bf16x8*)(Wt +
            (size_t)(32 * wave + 16 * ct + col) * 1152 + tap * 128 + 32 * kc + 8 * oct);
        acc[ct] = __builtin_amdgcn_mfma_f32_16x16x32_bf16(Af, Bf, acc[ct], 0, 0, 0);
      }
    }
  }
#pragma unroll
  for (int ct = 0; ct < 2; ct++) {
    int co = 32 * wave + 16 * ct + col;
    float bv = lb[co];
    int n = h * 64 + w0 + 4 * oct;
    size_t base = ((size_t)b * CC + co) * NN + n;
    float4 xi = *(const float4*)(x + base);
    float4 o;
    float z0 = acc[ct][0] + bv; o.x = ((z0 >= 0.f) ? z0 : 0.2f * z0) + xi.x;
    float z1 = acc[ct][1] + bv; o.y = ((z1 >= 0.f) ? z1 : 0.2f * z1) + xi.y;
    float z2 = acc[ct][2] + bv; o.z = ((z2 >= 0.f) ? z2 : 0.2f * z2) + xi.z;
    float z3 = acc[ct][3] + bv; o.w = ((z3 >= 0.f) ? z3 : 0.2f * z3) + xi.w;
    *(float4*)(out + base) = o;
  }
}

extern "C" void kernel_launch(void* const* d_in, const int* in_sizes, int n_in,
                              void* d_out, int out_size, void* d_ws, size_t ws_size,
                              hipStream_t stream) {
  const float* x    = (const float*)d_in[0];
  const float* q_w  = (const float*)d_in[1];
  const float* q_b  = (const float*)d_in[2];
  const float* v_w  = (const float*)d_in[3];
  const float* v_b  = (const float*)d_in[4];
  const float* lw1w = (const float*)d_in[5];
  const float* lw1b = (const float*)d_in[6];
  const float* lw2w = (const float*)d_in[7];
  const float* lw2b = (const float*)d_in[8];
  const float* bw1w = (const float*)d_in[9];
  const float* bw1b = (const float*)d_in[10];
  const float* bw2w = (const float*)d_in[11];
  const float* bw2b = (const float*)d_in[12];
  const float* linw = (const float*)d_in[13];
  const float* linb = (const float*)d_in[14];
  float* out = (float*)d_out;

  const size_t BCN = (size_t)BB * CC * NN;  // 2,097,152
  const size_t BN  = (size_t)BB * NN;       // 16,384

  unsigned short* xtb = (unsigned short*)d_ws;         // BCN bf16 (UNUSED; slot kept)
  unsigned short* qt  = xtb + BCN;                     // BCN
  unsigned short* qtn = qt + BCN;                      // BCN
  unsigned short* vb16 = qtn + BCN;                    // BCN
  unsigned short* Yt  = vb16 + BCN;                    // BB*YTP*CC
  unsigned short* qwb = Yt + (size_t)BB * YTP * CC;    // CC*CC
  unsigned short* vwb = qwb + CC * CC;                 // CC*CC
  unsigned short* hwb = vwb + CC * CC;                 // 64*CC
  unsigned short* Wt  = hwb + 64 * CC;                 // CC*1152
  float* nrmb = (float*)(Wt + (size_t)CC * 1152);      // BN
  float* wmap = nrmb + BN;                             // BN
  float* bmap = wmap + BN;                             // BN
  float* SumV = bmap + BN;                             // BB*CC
  float* Skey = SumV + (size_t)BB * CC;                // BB*CC
  float* c1a  = Skey + (size_t)BB * CC;                // BN
  float* zda  = c1a + BN;                              // BN
  float* Zacc = zda + BN;                              // BN        } zero
  int*   flags = (int*)(Zacc + BN);                    // 512*16    } region
  float* pSkey = (float*)(flags + 512 * 16);           // 512*128
  float* pSumV = pSkey + 512 * 128;                    // 512*128
  float* Ypart = pSumV + 512 * 128;                    // 512*16*4096 f32 (128MB)
  // total ≈ 16 MB bf16 bufs + 4.3 Yt + ~0.6 weights + maps + 128 MB Ypart
  //       ≈ 150 MB < 256 MiB.  Ypart needs no memset (only flagged chunks read).
  // Yt memset DROPPED: yfin writes all interior pixels + zeroes the border.

  size_t zbytes = BN * sizeof(float) + 512 * 16 * sizeof(int);
  hipMemsetAsync(Zacc, 0, zbytes, stream);

  hipLaunchKernelGGL(wrepack_kernel, dim3((188416 + 255) / 256), dim3(256), 0,
                     stream, q_w, v_w, lw1w, bw1w, linw, qwb, vwb, hwb, Wt);
  hipLaunchKernelGGL(qv_mfma, dim3(NN / 32, BB), dim3(256), 0, stream,
                     x, qwb, vwb, hwb, q_b, v_b, lw1b, lw2w, lw2b,
                     bw1b, bw2w, bw2b, qt, qtn, nrmb, pSkey, vb16, pSumV,
                     wmap, bmap);
  hipLaunchKernelGGL(reduce_kernel, dim3(BB), dim3(256), 0, stream,
                     pSkey, pSumV, Skey, SumV);
  hipLaunchKernelGGL(stats_kernel, dim3(BN / 256), dim3(256), 0, stream,
                     qtn, Skey, nrmb, wmap, bmap, c1a, zda);
  hipLaunchKernelGGL(qk_sparse, dim3(2048), dim3(256), 0, stream,
                     qt, qtn, c1a, zda, Zacc, vb16, Ypart, flags);
  hipLaunchKernelGGL(yfin_kernel, dim3(512), dim3(256), 0, stream,
                     Ypart, flags, Zacc, SumV, Yt);
  hipLaunchKernelGGL(conv_mfma, dim3(HH, 4, BB), dim3(256), 0, stream,
                     Yt, Wt, x, linb, out);
}

// Round 17
// 202.177 us; speedup vs baseline: 1.1011x; 1.0053x over previous
//
#include <hip/hip_runtime.h>
#include <math.h>

#define BB 4
#define CC 128
#define NN 4096
#define HH 64
#define WW 64
#define YTP 4356   // 66*66 padded pixel count

typedef __attribute__((ext_vector_type(8))) short bf16x8;
typedef __attribute__((ext_vector_type(4))) float f32x4;

__device__ inline unsigned short f2bf(float f) {
  unsigned int u = __float_as_uint(f);
  unsigned int r = (u + 0x7FFFu + ((u >> 16) & 1u)) >> 16;
  return (unsigned short)r;
}
__device__ inline float bf2f(short s) {
  union { unsigned u; float f; } x;
  x.u = ((unsigned)(unsigned short)s) << 16;
  return x.f;
}

// ---------------- wrepack: all weights -> bf16 packed ----------------
__global__ __launch_bounds__(256) void wrepack_kernel(
    const float* __restrict__ qw, const float* __restrict__ vw,
    const float* __restrict__ lw1w, const float* __restrict__ bw1w,
    const float* __restrict__ lw, unsigned short* __restrict__ qwb,
    unsigned short* __restrict__ vwb, unsigned short* __restrict__ hwb,
    unsigned short* __restrict__ Wt) {
  int idx = blockIdx.x * 256 + threadIdx.x;
  if (idx < 16384) { qwb[idx] = f2bf(qw[idx]); return; }
  idx -= 16384;
  if (idx < 16384) { vwb[idx] = f2bf(vw[idx]); return; }
  idx -= 16384;
  if (idx < 4096) { hwb[idx] = f2bf(lw1w[idx]); return; }
  idx -= 4096;
  if (idx < 4096) { hwb[4096 + idx] = f2bf(bw1w[idx]); return; }
  idx -= 4096;
  if (idx < CC * 1152) {
    int co = idx / 1152, rem = idx % 1152;
    int tap = rem >> 7, ci = rem & 127;
    Wt[idx] = f2bf(lw[(size_t)(co * CC + ci) * 9 + tap]);
  }
}

// ---- qv_mfma v3: fused transpose + role-split (round-15 best) --------------
__global__ __launch_bounds__(256) void qv_mfma(
    const float* __restrict__ x, const unsigned short* __restrict__ qwb,
    const unsigned short* __restrict__ vwb, const unsigned short* __restrict__ hwb,
    const float* __restrict__ qb, const float* __restrict__ vb,
    const float* __restrict__ lw1b, const float* __restrict__ lw2w,
    const float* __restrict__ lw2b, const float* __restrict__ bw1b,
    const float* __restrict__ bw2w, const float* __restrict__ bw2b,
    unsigned short* __restrict__ qt, unsigned short* __restrict__ qtn,
    float* __restrict__ nrm, float* __restrict__ pSkey,
    unsigned short* __restrict__ vbuf, float* __restrict__ pSumV,
    float* __restrict__ wmap, float* __restrict__ bmap) {
  int b = blockIdx.y;
  int nb = blockIdx.x;               // 128 per batch, 32 pixels each
  int t = threadIdx.x, w = t >> 6, lane = t & 63;
  int role = w & 1, pg = w >> 1;     // role 0 = q, 1 = v; pixel group 0..1
  int n0g = nb * 32;                 // block's 32 pixels
  int n0 = n0g + pg * 16;            // this wave-pair's 16 pixels
  int col = lane & 15, oct = lane >> 4;
  __shared__ float xs[CC][33];                           // f32 transpose stage
  __shared__ __align__(16) unsigned short xsb[32 * 128]; // swizzled bf16 [px][ch]
  __shared__ float qs[2][16][132];
  __shared__ float partK[2][128];
  __shared__ float partV[2][128];

  // pass 1: coalesced load of x[c][n0g..n0g+31] (128 rows x 128 B)
#pragma unroll
  for (int l = 0; l < 16; l++) {
    int e = t + 256 * l;             // 4096 elements
    int c = e >> 5, j = e & 31;
    xs[c][j] = x[((size_t)b * CC + c) * NN + n0g + j];
  }
  __syncthreads();
  // pass 2: transpose + bf16 pack into swizzled [pixel][ch] uint4 grid
#pragma unroll
  for (int l = 0; l < 2; l++) {
    int e = t + 256 * l;             // 512 items = 32 px x 16 uint4
    int j = e >> 4, c16 = e & 15;
    unsigned short u[8];
#pragma unroll
    for (int k = 0; k < 8; k++) u[k] = f2bf(xs[c16 * 8 + k][j]);
    uint4 v;
    v.x = (unsigned)u[0] | ((unsigned)u[1] << 16);
    v.y = (unsigned)u[2] | ((unsigned)u[3] << 16);
    v.z = (unsigned)u[4] | ((unsigned)u[5] << 16);
    v.w = (unsigned)u[6] | ((unsigned)u[7] << 16);
    int slot = j * 16 + (c16 ^ (j & 7));
    *(uint4*)(xsb + slot * 8) = v;
  }
  __syncthreads();

  int xrow = pg * 16 + col;          // this lane's pixel row in the tile
  if (role == 1) {
    // ---------------- v path ----------------
    f32x4 av[8];
#pragma unroll
    for (int i = 0; i < 8; i++) av[i] = (f32x4)0.f;
#pragma unroll
    for (int kc = 0; kc < 4; kc++) {
      bf16x8 Xf = *(const bf16x8*)(xsb + (xrow * 16 + ((kc * 4 + oct) ^ (xrow & 7))) * 8);
#pragma unroll
      for (int ct = 0; ct < 8; ct++) {
        bf16x8 Vf = *(const bf16x8*)(vwb + (16 * ct + col) * CC + kc * 32 + oct * 8);
        av[ct] = __builtin_amdgcn_mfma_f32_16x16x32_bf16(Vf, Xf, av[ct], 0, 0, 0);
      }
    }
    unsigned short* vbb = vbuf + (size_t)b * CC * NN;
#pragma unroll
    for (int ct = 0; ct < 8; ct++) {
#pragma unroll
      for (int r = 0; r < 4; r++) {
        int c = 16 * ct + 4 * oct + r;
        float val = av[ct][r] + vb[c];
        vbb[(size_t)c * NN + n0 + col] = f2bf(val);
        float sv = val;
        sv += __shfl_xor(sv, 1); sv += __shfl_xor(sv, 2);
        sv += __shfl_xor(sv, 4); sv += __shfl_xor(sv, 8);
        if (col == 0) partV[pg][c] = sv;
      }
    }
  } else {
    // ---------------- q path ----------------
    f32x4 aq[8];
#pragma unroll
    for (int i = 0; i < 8; i++) aq[i] = (f32x4)0.f;
#pragma unroll
    for (int kc = 0; kc < 4; kc++) {
      bf16x8 Xf = *(const bf16x8*)(xsb + (xrow * 16 + ((kc * 4 + oct) ^ (xrow & 7))) * 8);
#pragma unroll
      for (int ct = 0; ct < 8; ct++) {
        bf16x8 Qf = *(const bf16x8*)(qwb + (16 * ct + col) * CC + kc * 32 + oct * 8);
        aq[ct] = __builtin_amdgcn_mfma_f32_16x16x32_bf16(Xf, Qf, aq[ct], 0, 0, 0);
      }
    }
    // q -> LDS (fp32, biased); same-wave write->read, no block barrier needed
#pragma unroll
    for (int ct = 0; ct < 8; ct++) {
#pragma unroll
      for (int r = 0; r < 4; r++) {
        int c = 16 * ct + col;
        qs[pg][4 * oct + r][c] = aq[ct][r] + qb[c];
      }
    }
    int row = lane >> 2, cq = (lane & 3) * 32;
    float vals[32];
    float ssq = 0.f;
#pragma unroll
    for (int i = 0; i < 32; i += 4) {
      float4 v4 = *(const float4*)&qs[pg][row][cq + i];
      vals[i] = v4.x; vals[i + 1] = v4.y; vals[i + 2] = v4.z; vals[i + 3] = v4.w;
      ssq += v4.x * v4.x + v4.y * v4.y + v4.z * v4.z + v4.w * v4.w;
    }
    ssq += __shfl_xor(ssq, 1); ssq += __shfl_xor(ssq, 2);
    float nm = fmaxf(sqrtf(ssq), 1e-4f), sc = 1.0f / nm;
    int gp = b * NN + n0 + row;
    if ((lane & 3) == 0) nrm[gp] = nm;
    unsigned outq[16], outn[16];
    float sk[32];
#pragma unroll
    for (int i = 0; i < 32; i += 2) {
      unsigned short u0 = f2bf(vals[i]), u1 = f2bf(vals[i + 1]);
      unsigned short m0 = f2bf(vals[i] * sc), m1 = f2bf(vals[i + 1] * sc);
      outq[i >> 1] = (unsigned)u0 | ((unsigned)u1 << 16);
      outn[i >> 1] = (unsigned)m0 | ((unsigned)m1 << 16);
      sk[i] = bf2f((short)m0); sk[i + 1] = bf2f((short)m1);
    }
    unsigned short* qtp = qt + (size_t)gp * CC + cq;
    unsigned short* qnp = qtn + (size_t)gp * CC + cq;
#pragma unroll
    for (int k = 0; k < 4; k++) {
      uint4 v; v.x = outq[4 * k]; v.y = outq[4 * k + 1]; v.z = outq[4 * k + 2]; v.w = outq[4 * k + 3];
      *(uint4*)(qtp + 8 * k) = v;
      uint4 u; u.x = outn[4 * k]; u.y = outn[4 * k + 1]; u.z = outn[4 * k + 2]; u.w = outn[4 * k + 3];
      *(uint4*)(qnp + 8 * k) = u;
    }
#pragma unroll
    for (int i = 0; i < 32; i++) {
      float v = sk[i];
      v += __shfl_xor(v, 4); v += __shfl_xor(v, 8);
      v += __shfl_xor(v, 16); v += __shfl_xor(v, 32);
      if ((lane >> 2) == 0) partK[pg][cq + i] = v;
    }

    // ---- heads ----
    f32x4 ah[4];
#pragma unroll
    for (int i = 0; i < 4; i++) ah[i] = (f32x4)0.f;
#pragma unroll
    for (int kc = 0; kc < 4; kc++) {
      float4 a0 = *(const float4*)&qs[pg][col][kc * 32 + oct * 8];
      float4 a1 = *(const float4*)&qs[pg][col][kc * 32 + oct * 8 + 4];
      union { unsigned short s[8]; bf16x8 v; } af;
      af.s[0] = f2bf(a0.x); af.s[1] = f2bf(a0.y); af.s[2] = f2bf(a0.z); af.s[3] = f2bf(a0.w);
      af.s[4] = f2bf(a1.x); af.s[5] = f2bf(a1.y); af.s[6] = f2bf(a1.z); af.s[7] = f2bf(a1.w);
#pragma unroll
      for (int ct = 0; ct < 4; ct++) {
        bf16x8 Bf = *(const bf16x8*)(hwb + (16 * ct + col) * CC + kc * 32 + oct * 8);
        ah[ct] = __builtin_amdgcn_mfma_f32_16x16x32_bf16(af.v, Bf, ah[ct], 0, 0, 0);
      }
    }
    float b1l[2], b1b[2], w2l[2], w2b[2];
#pragma unroll
    for (int ct = 0; ct < 2; ct++) {
      int mid = 16 * ct + col;
      b1l[ct] = lw1b[mid]; w2l[ct] = lw2w[mid];
      b1b[ct] = bw1b[mid]; w2b[ct] = bw2w[mid];
    }
#pragma unroll
    for (int r = 0; r < 4; r++) {
      float wp = 0.f, bp = 0.f;
#pragma unroll
      for (int ct = 0; ct < 2; ct++) {
        float zl = ah[ct][r] + b1l[ct];
        zl = (zl >= 0.f) ? zl : 0.2f * zl;
        wp += w2l[ct] * zl;
        float zb = ah[ct + 2][r] + b1b[ct];
        zb = (zb >= 0.f) ? zb : 0.2f * zb;
        bp += w2b[ct] * zb;
      }
      wp += __shfl_xor(wp, 1); wp += __shfl_xor(wp, 2);
      wp += __shfl_xor(wp, 4); wp += __shfl_xor(wp, 8);
      bp += __shfl_xor(bp, 1); bp += __shfl_xor(bp, 2);
      bp += __shfl_xor(bp, 4); bp += __shfl_xor(bp, 8);
      if (col == 0) {
        int g = b * NN + n0 + 4 * oct + r;
        wmap[g] = wp + lw2b[0];
        bmap[g] = bp + bw2b[0];
      }
    }
  }

  // ---- block reduction of partials -> coalesced global partial vectors ----
  __syncthreads();
  int blk = b * 128 + nb;
  if (t < 128) {
    float s = partK[0][t] + partK[1][t];
    pSkey[(size_t)blk * 128 + t] = s;
  } else {
    int c = t - 128;
    float s = partV[0][c] + partV[1][c];
    pSumV[(size_t)blk * 128 + c] = s;
  }
}

// ---------------- reduce: partials -> Skey / SumV (128 blocks/batch) -------
__global__ __launch_bounds__(256) void reduce_kernel(
    const float* __restrict__ pSkey, const float* __restrict__ pSumV,
    float* __restrict__ Skey, float* __restrict__ SumV) {
  int b = blockIdx.x;
  int t = threadIdx.x;
  const float* src = (t < 128) ? pSkey : pSumV;
  int c = t & 127;
  float s = 0.f;
#pragma unroll 8
  for (int nb = 0; nb < 128; nb++)
    s += src[((size_t)b * 128 + nb) * 128 + c];
  if (t < 128) Skey[b * CC + c] = s;
  else SumV[b * CC + c] = s;
}

// ---- stats: per-row c1/zd (dedup: was recomputed by all 16 ks-blocks) ------
__global__ __launch_bounds__(256) void stats_kernel(
    const unsigned short* __restrict__ qtn, const float* __restrict__ Skey,
    const float* __restrict__ nrm, const float* __restrict__ wmap,
    const float* __restrict__ bmap, float* __restrict__ c1a,
    float* __restrict__ zda) {
  int g = blockIdx.x * 256 + threadIdx.x;   // g in [0, BB*NN)
  int b = g >> 12;                          // NN = 4096; 16 blocks per batch
  __shared__ float sk[CC];
  if (threadIdx.x < CC) sk[threadIdx.x] = Skey[b * CC + threadIdx.x];
  __syncthreads();
  const unsigned short* qp = qtn + (size_t)g * CC;
  float dot = 0.f;
#pragma unroll
  for (int i = 0; i < CC; i += 8) {
    bf16x8 v = *(const bf16x8*)(qp + i);
    dot += bf2f(v[0]) * sk[i]     + bf2f(v[1]) * sk[i + 1]
         + bf2f(v[2]) * sk[i + 2] + bf2f(v[3]) * sk[i + 3]
         + bf2f(v[4]) * sk[i + 4] + bf2f(v[5]) * sk[i + 5]
         + bf2f(v[6]) * sk[i + 6] + bf2f(v[7]) * sk[i + 7];
  }
  float c1 = dot * (1.0f / NN) * wmap[g] - bmap[g];
  float nm = nrm[g];
  c1a[g] = c1;
  zda[g] = nm * fmaxf(nm - c1, 0.f);
}

// -------- qk_sparse v8 (final): fused PV, sync slab staging, precomp stats --
// Round-16 falsified T5 setprio here (43.5 -> 45.3 us, m190-style null in
// this structure) -- reverted to the round-15 body, best measured (43.3 us).
// grid 2048: lin = mtile*64 + b*16 + ks; 128 m x 256 keys (8 iters).
__global__ __launch_bounds__(256, 2) void qk_sparse(
    const unsigned short* __restrict__ qt, const unsigned short* __restrict__ qtn,
    const float* __restrict__ c1a, const float* __restrict__ zda,
    float* __restrict__ Zacc, const unsigned short* __restrict__ vb16,
    float* __restrict__ Ypart, int* __restrict__ flags) {
  int lin = blockIdx.x;
  int mtile = lin >> 6;
  int bks = lin & 63;
  int b = bks >> 4, ks = bks & 15;
  int t = threadIdx.x, wave = t >> 6, lane = t & 63;
  int col = lane & 15, oct = lane >> 4;
  int m0 = mtile * 128 + 32 * wave;
  int bucket = b * 128 + (m0 >> 5);

  __shared__ unsigned short Bt[8][4096];                 // full 256-key slab, 64 KB
  __shared__ __align__(16) unsigned short tS[4][32][40]; // per-wave P tile

  const unsigned short* qtb  = qt  + (size_t)b * NN * CC;
  const unsigned short* qtnb = qtn + (size_t)b * NN * CC;
  const unsigned short* vbb  = vb16 + (size_t)b * CC * NN;

  bf16x8 A[2][4];
#pragma unroll
  for (int mt = 0; mt < 2; mt++)
#pragma unroll
    for (int kc = 0; kc < 4; kc++)
      A[mt][kc] = *(const bf16x8*)(qtb + (size_t)(m0 + 16 * mt + col) * CC + 32 * kc + 8 * oct);

  // precomputed per-row stats: 2 loads + the same broadcast shuffles
  float stc1[2][4], stzd[2][4];
#pragma unroll
  for (int mt = 0; mt < 2; mt++) {
    int m = m0 + 16 * mt + col;
    float c1 = c1a[(size_t)b * NN + m];
    float zd = zda[(size_t)b * NN + m];
#pragma unroll
    for (int r = 0; r < 4; r++) {
      stc1[mt][r] = __shfl(c1, 4 * oct + r);
      stzd[mt][r] = __shfl(zd, 4 * oct + r);
    }
  }

  int n0base = ks * 256;
  // stage the ENTIRE 256-key slab once: 16 independent uint4 loads/thread
  {
    int f0 = wave, f1 = wave + 4;
    size_t off0 = (size_t)(16 * (f0 >> 2) + col) * CC + (4 * (f0 & 3) + oct) * 8;
    size_t off1 = (size_t)(16 * (f1 >> 2) + col) * CC + (4 * (f1 & 3) + oct) * 8;
#pragma unroll
    for (int it = 0; it < 8; it++) {
      size_t nb0 = (size_t)(n0base + it * 32) * CC;
      uint4 r0 = *(const uint4*)(qtnb + nb0 + off0);
      uint4 r1 = *(const uint4*)(qtnb + nb0 + off1);
      *(uint4*)&Bt[it][f0 * 512 + lane * 8] = r0;
      *(uint4*)&Bt[it][f1 * 512 + lane * 8] = r1;
    }
  }
  __syncthreads();   // the ONLY block-wide barrier

  float zp[2][4];
#pragma unroll
  for (int mt = 0; mt < 2; mt++)
#pragma unroll
    for (int r = 0; r < 4; r++) zp[mt][r] = 0.f;
  // persistent PV accumulators: pvacc[mt][ct] covers (c = 16ct+4oct+r, m = 16mt+col)
  f32x4 pvacc[2][8];
#pragma unroll
  for (int mt = 0; mt < 2; mt++)
#pragma unroll
    for (int ct = 0; ct < 8; ct++) pvacc[mt][ct] = (f32x4)0.f;
  bool didwork = false;

  for (int it = 0; it < 8; it++) {
    f32x4 acc[2][2];
    acc[0][0] = (f32x4)0.f; acc[0][1] = (f32x4)0.f;
    acc[1][0] = (f32x4)0.f; acc[1][1] = (f32x4)0.f;
#pragma unroll
    for (int nt = 0; nt < 2; nt++)
#pragma unroll
      for (int kc = 0; kc < 4; kc++) {
        bf16x8 Bf = *(const bf16x8*)&Bt[it][(nt * 4 + kc) * 512 + lane * 8];
        acc[0][nt] = __builtin_amdgcn_mfma_f32_16x16x32_bf16(A[0][kc], Bf, acc[0][nt], 0, 0, 0);
        acc[1][nt] = __builtin_amdgcn_mfma_f32_16x16x32_bf16(A[1][kc], Bf, acc[1][nt], 0, 0, 0);
      }
    // cheap row-max screen: max_z_row <= max(lmax*relu(lmax-c1), 0)
    float fm = -1e30f;
#pragma unroll
    for (int mt = 0; mt < 2; mt++)
#pragma unroll
      for (int r = 0; r < 4; r++) {
        float lm = fmaxf(acc[mt][0][r], acc[mt][1][r]);
        float ub = fmaxf(lm * fmaxf(lm - stc1[mt][r], 0.f), 0.f);
        fm = fmaxf(fm, ub - stzd[mt][r]);
      }
    if (__any(fm > -18.4207f)) {
      didwork = true;
      int n0 = n0base + it * 32;
#pragma unroll
      for (int mt = 0; mt < 2; mt++)
#pragma unroll
        for (int nt = 0; nt < 2; nt++)
#pragma unroll
          for (int r = 0; r < 4; r++) {
            float l = acc[mt][nt][r];
            float s = l - stc1[mt][r];
            float z = l * fmaxf(s, 0.f);
            float e = __expf(z - stzd[mt][r]);
            zp[mt][r] += e;
            tS[wave][16 * mt + 4 * oct + r][16 * nt + col] = f2bf((s > 0.f) ? e : 0.f);
          }
      // fused PV: P (tS) is in B-fragment layout; V fragments direct from global
      bf16x8 Pa = *(const bf16x8*)&tS[wave][col][8 * oct];
      bf16x8 Pb = *(const bf16x8*)&tS[wave][16 + col][8 * oct];
#pragma unroll
      for (int ct = 0; ct < 8; ct++) {
        bf16x8 Vf = *(const bf16x8*)(vbb + (size_t)(16 * ct + col) * NN + n0 + 8 * oct);
        pvacc[0][ct] = __builtin_amdgcn_mfma_f32_16x16x32_bf16(Vf, Pa, pvacc[0][ct], 0, 0, 0);
        pvacc[1][ct] = __builtin_amdgcn_mfma_f32_16x16x32_bf16(Vf, Pb, pvacc[1][ct], 0, 0, 0);
      }
    }
  }

  if (didwork) {
#pragma unroll
    for (int mt = 0; mt < 2; mt++)
#pragma unroll
      for (int r = 0; r < 4; r++) {
        float v = zp[mt][r];
        v += __shfl_xor(v, 1); v += __shfl_xor(v, 2);
        v += __shfl_xor(v, 4); v += __shfl_xor(v, 8);
        if (col == 0)
          atomicAdd(Zacc + (size_t)b * NN + m0 + 16 * mt + 4 * oct + r, v);
      }
    // write un-normalized PV partial: Ypart chunk [32 m][128 c], single writer
    float* yp = Ypart + ((size_t)bucket * 16 + ks) * (32 * CC);
#pragma unroll
    for (int mt = 0; mt < 2; mt++)
#pragma unroll
      for (int ct = 0; ct < 8; ct++) {
        float4 o;
        o.x = pvacc[mt][ct][0]; o.y = pvacc[mt][ct][1];
        o.z = pvacc[mt][ct][2]; o.w = pvacc[mt][ct][3];
        *(float4*)(yp + (16 * mt + col) * CC + 16 * ct + 4 * oct) = o;
      }
    if (lane == 0) flags[bucket * 16 + ks] = 1;
  }
}

// ---- yfin: chunk-sum + /Z + 1e-8*SumV -> bf16 Yt; also zeroes Yt border ----
__global__ __launch_bounds__(256) void yfin_kernel(
    const float* __restrict__ Ypart, const int* __restrict__ flags,
    const float* __restrict__ Zacc, const float* __restrict__ SumV,
    unsigned short* __restrict__ Yt) {
  int bucket = blockIdx.x;
  int b = bucket >> 7;
  int chunk = bucket & 127;
  int m0 = chunk * 32;
  int t = threadIdx.x;
  // ---- border zero: block covers pixels k = chunk*2, chunk*2+1 (+256+chunk) --
  {
    int slot = t >> 4, q4 = t & 15;
    if (slot < 3) {
      int k = (slot < 2) ? (chunk * 2 + slot) : (chunk < 4 ? 256 + chunk : -1);
      if (k >= 0 && k < 260) {
        int hh, ww;
        if (k < 66)       { hh = 0;            ww = k; }
        else if (k < 132) { hh = 65;           ww = k - 66; }
        else if (k < 196) { hh = k - 132 + 1;  ww = 0; }
        else              { hh = k - 196 + 1;  ww = 65; }
        uint4 z; z.x = 0; z.y = 0; z.z = 0; z.w = 0;
        *(uint4*)(Yt + ((size_t)b * YTP + (size_t)hh * 66 + ww) * CC + q4 * 8) = z;
      }
    }
  }
  int mi = t >> 3, c0 = (t & 7) * 16;
  int m = m0 + mi;
  __shared__ int fl[16];
  if (t < 16) fl[t] = flags[bucket * 16 + t];
  __syncthreads();
  float rZ = 1.0f / Zacc[(size_t)b * NN + m];
  int h = m >> 6, ww = m & 63;
  const float* yb = Ypart + (size_t)bucket * 16 * (32 * CC) + mi * CC + c0;
  const float* sv = SumV + b * CC + c0;
  unsigned short* yp = Yt + ((size_t)b * YTP + (size_t)(h + 1) * 66 + (ww + 1)) * CC + c0;
  float a[16];
#pragma unroll
  for (int j = 0; j < 16; j++) a[j] = 0.f;
  for (int ks = 0; ks < 16; ks++) {
    if (!fl[ks]) continue;
    const float* ya = yb + (size_t)ks * (32 * CC);
#pragma unroll
    for (int j = 0; j < 4; j++) {
      float4 v = *(const float4*)(ya + 4 * j);
      a[4 * j] += v.x; a[4 * j + 1] += v.y; a[4 * j + 2] += v.z; a[4 * j + 3] += v.w;
    }
  }
  unsigned ov[8];
#pragma unroll
  for (int j = 0; j < 8; j++) {
    float2 s = *(const float2*)(sv + 2 * j);
    float y0 = a[2 * j] * rZ + 1e-8f * s.x;
    float y1 = a[2 * j + 1] * rZ + 1e-8f * s.y;
    ov[j] = (unsigned)f2bf(y0) | ((unsigned)f2bf(y1) << 16);
  }
  uint4 o0; o0.x = ov[0]; o0.y = ov[1]; o0.z = ov[2]; o0.w = ov[3];
  uint4 o1; o1.x = ov[4]; o1.y = ov[5]; o1.z = ov[6]; o1.w = ov[7];
  *(uint4*)yp = o0;
  *(uint4*)(yp + 8) = o1;
}

// -------- conv v2: MFMA 3x3 conv, LDS-staged halo tile, 4x finer grid -------
__global__ __launch_bounds__(256, 4) void conv_mfma(
    const unsigned short* __restrict__ Yt, const unsigned short* __restrict__ Wt,
    const float* __restrict__ x, const float* __restrict__ lb,
    float* __restrict__ out) {
  int h = blockIdx.x;
  int by = blockIdx.y;               // 16-pixel column tile
  int b = blockIdx.z;
  int t = threadIdx.x;
  int wave = t >> 6, lane = t & 63;
  int col = lane & 15, oct = lane >> 4;
  int w0 = by * 16;
  __shared__ __align__(16) unsigned short ys[54 * 128];  // 3 x 18 x 128, swizzled

  // stage halo: padded rows h..h+2, padded cols w0..w0+17, all 128 ch
  const unsigned short* Yb = Yt + (size_t)b * YTP * CC;
  for (int e = t; e < 864; e += 256) {     // 864 = 54 rows * 16 uint4
    int row = e >> 4;                      // 0..53
    int c16 = e & 15;
    int dr = row / 18, j = row - dr * 18;
    uint4 v = *(const uint4*)(Yb + ((size_t)(h + dr) * 66 + w0 + j) * CC + c16 * 8);
    int slot = row * 16 + (c16 ^ (row & 7));
    *(uint4*)(ys + slot * 8) = v;
  }
  __syncthreads();

  f32x4 acc[2];
  acc[0] = (f32x4)0.f; acc[1] = (f32x4)0.f;

#pragma unroll
  for (int tap = 0; tap < 9; tap++) {
    int dr = tap / 3, dc = tap % 3;
    int arow = dr * 18 + dc + col;         // pixel row in tile, 0..53
#pragma unroll
    for (int kc = 0; kc < 4; kc++) {
      int slot = arow * 16 + ((kc * 4 + oct) ^ (arow & 7));
      bf16x8 Af = *(const bf16x8*)(ys + slot * 8);
#pragma unroll
      for (int ct = 0; ct < 2; ct++) {
        bf16x8 Bf = *(const bf16x8*)(Wt +
            (size_t)(32 * wave + 16 * ct + col) * 1152 + tap * 128 + 32 * kc + 8 * oct);
        acc[ct] = __builtin_amdgcn_mfma_f32_16x16x32_bf16(Af, Bf, acc[ct], 0, 0, 0);
      }
    }
  }
#pragma unroll
  for (int ct = 0; ct < 2; ct++) {
    int co = 32 * wave + 16 * ct + col;
    float bv = lb[co];
    int n = h * 64 + w0 + 4 * oct;
    size_t base = ((size_t)b * CC + co) * NN + n;
    float4 xi = *(const float4*)(x + base);
    float4 o;
    float z0 = acc[ct][0] + bv; o.x = ((z0 >= 0.f) ? z0 : 0.2f * z0) + xi.x;
    float z1 = acc[ct][1] + bv; o.y = ((z1 >= 0.f) ? z1 : 0.2f * z1) + xi.y;
    float z2 = acc[ct][2] + bv; o.z = ((z2 >= 0.f) ? z2 : 0.2f * z2) + xi.z;
    float z3 = acc[ct][3] + bv; o.w = ((z3 >= 0.f) ? z3 : 0.2f * z3) + xi.w;
    *(float4*)(out + base) = o;
  }
}

extern "C" void kernel_launch(void* const* d_in, const int* in_sizes, int n_in,
                              void* d_out, int out_size, void* d_ws, size_t ws_size,
                              hipStream_t stream) {
  const float* x    = (const float*)d_in[0];
  const float* q_w  = (const float*)d_in[1];
  const float* q_b  = (const float*)d_in[2];
  const float* v_w  = (const float*)d_in[3];
  const float* v_b  = (const float*)d_in[4];
  const float* lw1w = (const float*)d_in[5];
  const float* lw1b = (const float*)d_in[6];
  const float* lw2w = (const float*)d_in[7];
  const float* lw2b = (const float*)d_in[8];
  const float* bw1w = (const float*)d_in[9];
  const float* bw1b = (const float*)d_in[10];
  const float* bw2w = (const float*)d_in[11];
  const float* bw2b = (const float*)d_in[12];
  const float* linw = (const float*)d_in[13];
  const float* linb = (const float*)d_in[14];
  float* out = (float*)d_out;

  const size_t BCN = (size_t)BB * CC * NN;  // 2,097,152
  const size_t BN  = (size_t)BB * NN;       // 16,384

  unsigned short* xtb = (unsigned short*)d_ws;         // BCN bf16 (UNUSED; slot kept)
  unsigned short* qt  = xtb + BCN;                     // BCN
  unsigned short* qtn = qt + BCN;                      // BCN
  unsigned short* vb16 = qtn + BCN;                    // BCN
  unsigned short* Yt  = vb16 + BCN;                    // BB*YTP*CC
  unsigned short* qwb = Yt + (size_t)BB * YTP * CC;    // CC*CC
  unsigned short* vwb = qwb + CC * CC;                 // CC*CC
  unsigned short* hwb = vwb + CC * CC;                 // 64*CC
  unsigned short* Wt  = hwb + 64 * CC;                 // CC*1152
  float* nrmb = (float*)(Wt + (size_t)CC * 1152);      // BN
  float* wmap = nrmb + BN;                             // BN
  float* bmap = wmap + BN;                             // BN
  float* SumV = bmap + BN;                             // BB*CC
  float* Skey = SumV + (size_t)BB * CC;                // BB*CC
  float* c1a  = Skey + (size_t)BB * CC;                // BN
  float* zda  = c1a + BN;                              // BN
  float* Zacc = zda + BN;                              // BN        } zero
  int*   flags = (int*)(Zacc + BN);                    // 512*16    } region
  float* pSkey = (float*)(flags + 512 * 16);           // 512*128
  float* pSumV = pSkey + 512 * 128;                    // 512*128
  float* Ypart = pSumV + 512 * 128;                    // 512*16*4096 f32 (128MB)
  // total ≈ 16 MB bf16 bufs + 4.3 Yt + ~0.6 weights + maps + 128 MB Ypart
  //       ≈ 150 MB < 256 MiB.  Ypart needs no memset (only flagged chunks read).
  // Yt memset DROPPED: yfin writes all interior pixels + zeroes the border.

  size_t zbytes = BN * sizeof(float) + 512 * 16 * sizeof(int);
  hipMemsetAsync(Zacc, 0, zbytes, stream);

  hipLaunchKernelGGL(wrepack_kernel, dim3((188416 + 255) / 256), dim3(256), 0,
                     stream, q_w, v_w, lw1w, bw1w, linw, qwb, vwb, hwb, Wt);
  hipLaunchKernelGGL(qv_mfma, dim3(NN / 32, BB), dim3(256), 0, stream,
                     x, qwb, vwb, hwb, q_b, v_b, lw1b, lw2w, lw2b,
                     bw1b, bw2w, bw2b, qt, qtn, nrmb, pSkey, vb16, pSumV,
                     wmap, bmap);
  hipLaunchKernelGGL(reduce_kernel, dim3(BB), dim3(256), 0, stream,
                     pSkey, pSumV, Skey, SumV);
  hipLaunchKernelGGL(stats_kernel, dim3(BN / 256), dim3(256), 0, stream,
                     qtn, Skey, nrmb, wmap, bmap, c1a, zda);
  hipLaunchKernelGGL(qk_sparse, dim3(2048), dim3(256), 0, stream,
                     qt, qtn, c1a, zda, Zacc, vb16, Ypart, flags);
  hipLaunchKernelGGL(yfin_kernel, dim3(512), dim3(256), 0, stream,
                     Ypart, flags, Zacc, SumV, Yt);
  hipLaunchKernelGGL(conv_mfma, dim3(HH, 4, BB), dim3(256), 0, stream,
                     Yt, Wt, x, linb, out);
}